// Round 3
// baseline (993.213 us; speedup 1.0000x reference)
//
#include <hip/hip_runtime.h>
#include <hip/hip_bf16.h>
#include <math.h>

#define BB 8
#define NCLS 21
#define NANCH 2048
#define TOPK_N 100

// ---------------- workspace layout (bytes) ----------------
static const size_t OFF_X1HI = 0;           // 8*8*130*258*8*2 = 34,344,960
static const size_t OFF_X1LO = 34344960;
static const size_t OFF_X2HI = 68689920;    // 8*16*66*130*8*2
static const size_t OFF_X2LO = 86261760;
static const size_t OFF_FTHI = 103833600;   // 8*32*34*66*8*2
static const size_t OFF_FTLO = 113025024;
static const size_t OFF_WT1  = 122216448;
static const size_t OFF_A2H  = 122223616;
static const size_t OFF_A2L  = 122371072;
static const size_t OFF_A3H  = 122518528;
static const size_t OFF_A3L  = 123108352;
static const size_t OFF_AHH  = 123698176;
static const size_t OFF_AHL  = 123993088;
static const size_t OFF_AP1H = 124288000;
static const size_t OFF_AP1L = 125467648;
static const size_t OFF_WTP2 = 126647296;
static const size_t OFF_BH   = 126680064;
static const size_t OFF_HOUT = 126680576;
static const size_t OFF_P1   = 130874880;
static const size_t OFF_PROTO= 147652096;
static const size_t OFF_BOXES= 149749248;
static const size_t OFF_SCORES=150011392;
static const size_t OFF_LABELS=150076928;
static const size_t OFF_ORDER= 150142464;
static const size_t OFF_SB   = 150208000;
static const size_t OFF_IOU  = 150470144;
static const size_t OFF_KEEP = 154664448;
static const size_t OFF_MAXB = 154668032;

// ---------------- output layout (float elements) ----------------
static const size_t OUT_BOXES  = 0;
static const size_t OUT_SCORES = 3200;
static const size_t OUT_LABELS = 4000;
static const size_t OUT_MASKS  = 4800;
static const size_t OUT_VALID  = 104862400;

typedef __attribute__((ext_vector_type(8))) short bf16x8;
typedef __attribute__((ext_vector_type(4))) float f32x4;

__device__ __forceinline__ unsigned encf(float f){
  unsigned u = __float_as_uint(f);
  return (u & 0x80000000u) ? ~u : (u | 0x80000000u);
}
__device__ __forceinline__ float decf(unsigned u){
  unsigned b = (u & 0x80000000u) ? (u & 0x7fffffffu) : ~u;
  return __uint_as_float(b);
}
__device__ __forceinline__ short f2bf(float f){
  __hip_bfloat16 h = __float2bfloat16(f);
  return *(short*)&h;
}
__device__ __forceinline__ float bf2f(short h){
  return __uint_as_float(((unsigned)(unsigned short)h) << 16);
}

// ---------------- halo-only zero, all 3 layers in one kernel ----------------
__global__ void halok3(short* __restrict__ x1hi, short* __restrict__ x1lo,
                       short* __restrict__ x2hi, short* __restrict__ x2lo,
                       short* __restrict__ fthi, short* __restrict__ ftlo,
                       unsigned* __restrict__ maxb){
  int i = blockIdx.x*256 + threadIdx.x;
  if (i < BB) maxb[i] = 0u;
  short *hi, *lo; int Hp, Wp, cell, bg;
  if (i < 49408){
    hi=x1hi; lo=x1lo; Hp=130; Wp=258; cell = i % 772; bg = i / 772;
  } else if (i < 99072){
    int j = i - 49408; hi=x2hi; lo=x2lo; Hp=66; Wp=130; cell = j % 388; bg = j / 388;
  } else if (i < 149248){
    int j = i - 99072; hi=fthi; lo=ftlo; Hp=34; Wp=66; cell = j % 196; bg = j / 196;
  } else return;
  int y, x;
  if (cell < Wp)        { y = 0;      x = cell; }
  else if (cell < 2*Wp) { y = Hp-1;   x = cell - Wp; }
  else { int r = cell - 2*Wp; y = 1 + (r>>1); x = (r&1) ? (Wp-1) : 0; }
  size_t ad = (((size_t)bg*Hp + y)*Wp + x)*8;
  bf16x8 z = (bf16x8){0,0,0,0,0,0,0,0};
  *(bf16x8*)(hi + ad) = z;
  *(bf16x8*)(lo + ad) = z;
}

// ---------------- weight packers (device bodies + one dispatcher) ----------------
template<int CIN,int COUT,int KK>
__device__ __forceinline__ void packw_body(int i, const float* __restrict__ w,
                                           float* __restrict__ wT){
  if (i >= CIN*KK*COUT) return;
  int co = i % COUT; int r = i / COUT;
  int ci = r / KK,  k = r % KK;
  wT[i] = w[(co*CIN + ci)*KK + k];
}

template<int CIN,int COUT>
__device__ __forceinline__ void packA_body(int i, const float* __restrict__ w,
                                           short* __restrict__ Ahi, short* __restrict__ Alo){
  constexpr int K = CIN*9;
  constexpr int KS = K/32;
  if (i >= COUT*K) return;
  int sub  = i & 7;
  int lane = (i >> 3) & 63;
  int rest = i >> 9;
  int ks = rest % KS;
  int mt = rest / KS;
  int m = mt*16 + (lane & 15);
  int k = ks*32 + (lane >> 4)*8 + sub;
  int tap = k / CIN, ci = k - tap*CIN;
  float v = w[(m*CIN + ci)*9 + tap];
  short h = f2bf(v);
  Ahi[i] = h;
  Alo[i] = f2bf(v - bf2f(h));
}

__device__ __forceinline__ void packAh_body(int i,
    const float* __restrict__ cw, const float* __restrict__ bw,
    const float* __restrict__ kw, const float* __restrict__ cb,
    const float* __restrict__ bb, const float* __restrict__ kb,
    short* __restrict__ Ahi, short* __restrict__ Alo, float* __restrict__ bh){
  if (i < 64){
    float v = 0.f;
    if (i < 21) v = cb[i]; else if (i < 25) v = bb[i-21]; else if (i < 57) v = kb[i-25];
    bh[i] = v;
  }
  if (i >= 64*2304) return;
  constexpr int KS = 72;
  int sub  = i & 7;
  int lane = (i >> 3) & 63;
  int rest = i >> 9;
  int ks = rest % KS;
  int mt = rest / KS;
  int m = mt*16 + (lane & 15);
  int k = ks*32 + (lane >> 4)*8 + sub;
  int tap = k >> 8, ci = k & 255;
  float v = 0.f;
  if (m < 21)      v = cw[(m*256 + ci)*9 + tap];
  else if (m < 25) v = bw[((m-21)*256 + ci)*9 + tap];
  else if (m < 57) v = kw[((m-25)*256 + ci)*9 + tap];
  short h = f2bf(v);
  Ahi[i] = h;
  Alo[i] = f2bf(v - bf2f(h));
}

// block ranges: [0,288) packA<64,128>; [288,1440) packA<128,256>;
// [1440,3744) packA<256,256>; [3744,4320) packAh; [4320,4327) packw<3,64,9>;
// [4327,4359) packw<256,32,1>
__global__ void packall(const float* __restrict__ w1, float* __restrict__ wT1,
                        const float* __restrict__ w2, short* __restrict__ a2h, short* __restrict__ a2l,
                        const float* __restrict__ w3, short* __restrict__ a3h, short* __restrict__ a3l,
                        const float* __restrict__ pw1, short* __restrict__ ap1h, short* __restrict__ ap1l,
                        const float* __restrict__ cw, const float* __restrict__ bw,
                        const float* __restrict__ kw, const float* __restrict__ cb,
                        const float* __restrict__ bb, const float* __restrict__ kb,
                        short* __restrict__ ahh, short* __restrict__ ahl, float* __restrict__ bh,
                        const float* __restrict__ pw2, float* __restrict__ wTp2){
  int blk = blockIdx.x, t = threadIdx.x;
  if (blk < 288)        packA_body<64,128>(blk*256+t, w2, a2h, a2l);
  else if (blk < 1440)  packA_body<128,256>((blk-288)*256+t, w3, a3h, a3l);
  else if (blk < 3744)  packA_body<256,256>((blk-1440)*256+t, pw1, ap1h, ap1l);
  else if (blk < 4320)  packAh_body((blk-3744)*256+t, cw,bw,kw,cb,bb,kb, ahh,ahl,bh);
  else if (blk < 4327)  packw_body<3,64,9>((blk-4320)*256+t, w1, wT1);
  else                  packw_body<256,32,1>((blk-4327)*256+t, pw2, wTp2);
}

// ---------------- conv1: direct fp32, epilogue -> C8HW8 padded bf16 hi/lo ----------------
__global__ __launch_bounds__(256) void conv1k(const float* __restrict__ img,
    const float* __restrict__ wT, const float* __restrict__ bias,
    short* __restrict__ x1hi, short* __restrict__ x1lo){
  const int b   = blockIdx.z;
  const int co0 = blockIdx.y * 16;
  const int g   = blockIdx.x*256 + threadIdx.x;
  const int y  = g >> 7;
  const int x0 = (g & 127) << 1;

  float acc[16][2];
#pragma unroll
  for (int c=0;c<16;c++){
    float bv = bias[co0+c];
    acc[c][0] = bv; acc[c][1] = bv;
  }
  int   off[3][5];
  float msk[3][5];
#pragma unroll
  for (int kh=0;kh<3;kh++){
    int iy = y*2 - 1 + kh;
    bool okr = (iy >= 0) && (iy < 256);
    int ro = okr ? iy*512 : 0;
#pragma unroll
    for (int t=0;t<5;t++){
      int col = x0*2 - 1 + t;
      bool ok = okr && (col >= 0) && (col < 512);
      off[kh][t] = ok ? (ro + col) : 0;
      msk[kh][t] = ok ? 1.f : 0.f;
    }
  }
  const float* inb = img + (size_t)b*3*256*512;
  for (int ci=0; ci<3; ci++){
    const float* inc = inb + (size_t)ci*256*512;
    float v[3][5];
#pragma unroll
    for (int kh=0;kh<3;kh++)
#pragma unroll
      for (int t=0;t<5;t++)
        v[kh][t] = inc[off[kh][t]] * msk[kh][t];
    const float* wp = wT + ci*9*64 + co0;
#pragma unroll
    for (int kh=0;kh<3;kh++)
#pragma unroll
    for (int kw=0;kw<3;kw++){
      const float* wq = wp + (kh*3+kw)*64;
#pragma unroll
      for (int c=0;c<16;c++){
        float wv = wq[c];
        acc[c][0] = fmaf(wv, v[kh][2*0+kw], acc[c][0]);
        acc[c][1] = fmaf(wv, v[kh][2*1+kw], acc[c][1]);
      }
    }
  }
#pragma unroll
  for (int s=0;s<2;s++){
    short hv[16] __attribute__((aligned(16)));
    short lv[16] __attribute__((aligned(16)));
#pragma unroll
    for (int c=0;c<16;c++){
      float r = fmaxf(acc[c][s], 0.f);
      short h = f2bf(r);
      hv[c] = h;
      lv[c] = f2bf(r - bf2f(h));
    }
#pragma unroll
    for (int g2=0; g2<2; g2++){
      size_t ad = (((size_t)(b*8 + (co0>>3) + g2)*130 + (y+1))*258 + (x0+s+1))*8;
      *(bf16x8*)(x1hi + ad) = *(bf16x8*)(hv + g2*8);
      *(bf16x8*)(x1lo + ad) = *(bf16x8*)(lv + g2*8);
    }
  }
}

// ---------------- cgemm_row: LDS-staged B rows (conv2/conv3) ----------------
template<int CIN,int K,int M,int MW,int NW,int S,int IPH,int IPW,int NXB,
         bool SPLIT,bool STAGELO,int EMODE,int OPH,int OPW>
__global__ __launch_bounds__(NW*64) void cgemm_row(
    const short* __restrict__ Ahi, const short* __restrict__ Alo,
    const short* __restrict__ Bhi, const short* __restrict__ Blo,
    const float* __restrict__ bias, float* __restrict__ outf,
    short* __restrict__ outhi, short* __restrict__ outlo){
  static_assert(CIN % 32 == 0, "CIN must be multiple of 32");
  constexpr int NT = 64*32;
  constexpr int KS = K/32;
  constexpr int CG = CIN/8;
  constexpr int SW  = 64*S + 2;
  constexpr int SWP = (S==2) ? (SW/2 + 1) : SW;
  constexpr int PARS = (S==2) ? 2 : 1;
  constexpr int LOOFF = CG*PARS*SWP*8;
  constexpr int BUFS = (SPLIT && STAGELO) ? 2 : 1;
  __shared__ __align__(16) short sB[BUFS*LOOFF];

  const int b    = blockIdx.z;
  const int oy   = blockIdx.x / NXB;
  const int xb   = (blockIdx.x % NXB) * 64;
  const int wave = threadIdx.x >> 6;
  const int lane = threadIdx.x & 63;
  const int lm = lane & 15, lq = lane >> 4;
  const int m0 = (blockIdx.y * NW + wave) * (MW*16);
  const int tid = threadIdx.x;

  f32x4 acc[MW][4];
#pragma unroll
  for (int i=0;i<MW;i++)
#pragma unroll
    for (int j=0;j<4;j++) acc[i][j] = (f32x4){0.f,0.f,0.f,0.f};

  const short* Ah_l = Ahi + (size_t)lane*8;
  const short* Al_l = Alo + (size_t)lane*8;
  const int mt0 = m0 >> 4;
  const size_t plane = (size_t)IPH*IPW;
  const short* Bl0 = Blo + ((size_t)b*CG + lq)*plane*8;

#pragma unroll 1
  for (int dy=0; dy<3; dy++){
    const int iy = oy*S + dy;
    __syncthreads();
    {
      const short* srch = Bhi + (((size_t)b*CG*IPH + iy)*IPW + (size_t)(xb*S))*8;
      for (int c = tid; c < CG*SW; c += NW*64){
        int g = c / SW, p = c - g*SW;
        int dst = (S==2) ? ((g*2 + (p&1))*SWP + (p>>1)) : (g*SW + p);
        *(bf16x8*)(&sB[(size_t)dst*8]) =
          *(const bf16x8*)(srch + ((size_t)g*plane + p)*8);
      }
      if constexpr (SPLIT && STAGELO){
        const short* srcl = Blo + (((size_t)b*CG*IPH + iy)*IPW + (size_t)(xb*S))*8;
        for (int c = tid; c < CG*SW; c += NW*64){
          int g = c / SW, p = c - g*SW;
          int dst = (S==2) ? ((g*2 + (p&1))*SWP + (p>>1)) : (g*SW + p);
          *(bf16x8*)(&sB[LOOFF + (size_t)dst*8]) =
            *(const bf16x8*)(srcl + ((size_t)g*plane + p)*8);
        }
      }
    }
    __syncthreads();
#pragma unroll
    for (int dx=0; dx<3; dx++){
      const int tap = dy*3 + dx;
      const int ksb = tap*(CIN/32);
      for (int kc=0; kc<CIN; kc+=32){
        const int ks = ksb + (kc>>5);
        int ra[4];
#pragma unroll
        for (int j=0;j<4;j++){
          int pc = (j*16 + lm)*S + dx;
          ra[j] = (S==2) ? ((((kc>>3) + lq)*2 + (pc&1))*SWP + (pc>>1))
                         : (((kc>>3) + lq)*SW + pc);
        }
        bf16x8 ah[MW], bh_[4];
#pragma unroll
        for (int i=0;i<MW;i++)
          ah[i] = *(const bf16x8*)(Ah_l + ((size_t)(mt0+i)*KS + ks)*512);
#pragma unroll
        for (int j=0;j<4;j++)
          bh_[j] = *(const bf16x8*)(&sB[(size_t)ra[j]*8]);
        if constexpr (SPLIT){
          bf16x8 al[MW], bl_[4];
#pragma unroll
          for (int i=0;i<MW;i++)
            al[i] = *(const bf16x8*)(Al_l + ((size_t)(mt0+i)*KS + ks)*512);
          if constexpr (STAGELO){
#pragma unroll
            for (int j=0;j<4;j++)
              bl_[j] = *(const bf16x8*)(&sB[LOOFF + (size_t)ra[j]*8]);
          } else {
#pragma unroll
            for (int j=0;j<4;j++){
              size_t pix = (size_t)iy*IPW + (size_t)((xb + j*16 + lm)*S + dx);
              bl_[j] = *(const bf16x8*)(Bl0 + ((size_t)(kc>>3)*plane + pix)*8);
            }
          }
#pragma unroll
          for (int j=0;j<4;j++)
#pragma unroll
            for (int i=0;i<MW;i++)
              acc[i][j] = __builtin_amdgcn_mfma_f32_16x16x32_bf16(ah[i], bh_[j], acc[i][j], 0,0,0);
#pragma unroll
          for (int j=0;j<4;j++)
#pragma unroll
            for (int i=0;i<MW;i++)
              acc[i][j] = __builtin_amdgcn_mfma_f32_16x16x32_bf16(ah[i], bl_[j], acc[i][j], 0,0,0);
#pragma unroll
          for (int j=0;j<4;j++)
#pragma unroll
            for (int i=0;i<MW;i++)
              acc[i][j] = __builtin_amdgcn_mfma_f32_16x16x32_bf16(al[i], bh_[j], acc[i][j], 0,0,0);
        } else {
#pragma unroll
          for (int j=0;j<4;j++)
#pragma unroll
            for (int i=0;i<MW;i++)
              acc[i][j] = __builtin_amdgcn_mfma_f32_16x16x32_bf16(ah[i], bh_[j], acc[i][j], 0,0,0);
        }
      }
    }
  }

#pragma unroll
  for (int i=0;i<MW;i++){
#pragma unroll
    for (int r=0;r<4;r++){
      const int m = m0 + i*16 + lq*4 + r;
      const float bv = bias[m];
      if constexpr (EMODE == 0){
#pragma unroll
        for (int j=0;j<4;j++){
          const int ox = xb + j*16 + lm;
          float v = fmaxf(acc[i][j][r] + bv, 0.f);
          short h = f2bf(v);
          short l = f2bf(v - bf2f(h));
          size_t ad = ((((size_t)(b*(M/8) + (m>>3))*OPH + (oy+1))*OPW + (ox+1)))*8 + (m&7);
          outhi[ad] = h;
          outlo[ad] = l;
        }
      } else {
        float* cp = outf + ((size_t)b*M + m)*NT + oy*64 + lm;
#pragma unroll
        for (int j=0;j<4;j++){
          float v = acc[i][j][r] + bv;
          if constexpr (EMODE == 2) v = fmaxf(v, 0.f);
          cp[j*16] = v;
        }
      }
    }
  }
}

// ---------------- heads + pw1 fused, x-split for occupancy ----------------
// blockIdx.x = oy*2 + xh; each block covers 32 output cols (2 j-tiles).
// Wave w: heads m-tile w (rows w*16..+16, split hi/lo: 6 MFMA/kc) +
//         pw1 m-tiles w*4..w*4+3 (rows w*64..+64, plain: 8 MFMA/kc).
// Per-accumulator k-sequence identical to the separate kernels -> bit-exact.
__global__ __launch_bounds__(256) void headspw1(
    const short* __restrict__ Ahh, const short* __restrict__ Ahl,
    const short* __restrict__ Aph,
    const short* __restrict__ Bhi, const short* __restrict__ Blo,
    const float* __restrict__ biash, const float* __restrict__ biasp,
    float* __restrict__ hout, float* __restrict__ p1){
  constexpr int KS = 72;           // 2304/32
  constexpr int CG = 32;           // 256/8
  constexpr int SW = 34;           // 32 cols + 2 halo
  constexpr int IPH = 34, IPW = 66;
  constexpr int LOOFF = CG*SW*8;   // 8704 shorts per buffer
  __shared__ __align__(16) short sB[2*LOOFF];

  const int b  = blockIdx.z;
  const int oy = blockIdx.x >> 1;
  const int xb = (blockIdx.x & 1) * 32;
  const int wave = threadIdx.x >> 6;
  const int lane = threadIdx.x & 63;
  const int lm = lane & 15, lq = lane >> 4;
  const int tid = threadIdx.x;

  f32x4 acch[2];
  f32x4 accp[4][2];
#pragma unroll
  for (int j=0;j<2;j++) acch[j] = (f32x4){0.f,0.f,0.f,0.f};
#pragma unroll
  for (int i=0;i<4;i++)
#pragma unroll
    for (int j=0;j<2;j++) accp[i][j] = (f32x4){0.f,0.f,0.f,0.f};

  const short* Ah_l = Ahh + (size_t)lane*8;
  const short* Al_l = Ahl + (size_t)lane*8;
  const short* Ap_l = Aph + (size_t)lane*8;
  const size_t plane = (size_t)IPH*IPW;

#pragma unroll 1
  for (int dy=0; dy<3; dy++){
    const int iy = oy + dy;
    __syncthreads();
    {
      const short* srch = Bhi + (((size_t)b*CG*IPH + iy)*IPW + xb)*8;
      const short* srcl = Blo + (((size_t)b*CG*IPH + iy)*IPW + xb)*8;
      for (int c = tid; c < CG*SW; c += 256){
        int g = c / SW, p = c - g*SW;
        *(bf16x8*)(&sB[(size_t)c*8]) =
          *(const bf16x8*)(srch + ((size_t)g*plane + p)*8);
        *(bf16x8*)(&sB[LOOFF + (size_t)c*8]) =
          *(const bf16x8*)(srcl + ((size_t)g*plane + p)*8);
      }
    }
    __syncthreads();
#pragma unroll
    for (int dx=0; dx<3; dx++){
      const int tap = dy*3 + dx;
      const int ksb = tap*8;
      for (int kc=0; kc<256; kc+=32){
        const int ks = ksb + (kc>>5);
        int ra[2];
#pragma unroll
        for (int j=0;j<2;j++) ra[j] = ((kc>>3) + lq)*SW + (j*16 + lm) + dx;
        bf16x8 bh_[2], bl_[2];
#pragma unroll
        for (int j=0;j<2;j++){
          bh_[j] = *(const bf16x8*)(&sB[(size_t)ra[j]*8]);
          bl_[j] = *(const bf16x8*)(&sB[LOOFF + (size_t)ra[j]*8]);
        }
        bf16x8 ah = *(const bf16x8*)(Ah_l + ((size_t)wave*KS + ks)*512);
        bf16x8 al = *(const bf16x8*)(Al_l + ((size_t)wave*KS + ks)*512);
#pragma unroll
        for (int j=0;j<2;j++)
          acch[j] = __builtin_amdgcn_mfma_f32_16x16x32_bf16(ah, bh_[j], acch[j], 0,0,0);
#pragma unroll
        for (int j=0;j<2;j++)
          acch[j] = __builtin_amdgcn_mfma_f32_16x16x32_bf16(ah, bl_[j], acch[j], 0,0,0);
#pragma unroll
        for (int j=0;j<2;j++)
          acch[j] = __builtin_amdgcn_mfma_f32_16x16x32_bf16(al, bh_[j], acch[j], 0,0,0);
#pragma unroll
        for (int i=0;i<4;i++){
          bf16x8 ap = *(const bf16x8*)(Ap_l + ((size_t)(wave*4+i)*KS + ks)*512);
#pragma unroll
          for (int j=0;j<2;j++)
            accp[i][j] = __builtin_amdgcn_mfma_f32_16x16x32_bf16(ap, bh_[j], accp[i][j], 0,0,0);
        }
      }
    }
  }

  // heads epilogue (no relu)
#pragma unroll
  for (int r=0;r<4;r++){
    const int mh = wave*16 + lq*4 + r;
    const float bv = biash[mh];
    float* cp = hout + ((size_t)b*64 + mh)*NANCH + oy*64 + xb + lm;
#pragma unroll
    for (int j=0;j<2;j++) cp[j*16] = acch[j][r] + bv;
  }
  // pw1 epilogue (relu)
#pragma unroll
  for (int i=0;i<4;i++){
#pragma unroll
    for (int r=0;r<4;r++){
      const int mp = wave*64 + i*16 + lq*4 + r;
      const float bv = biasp[mp];
      float* cp = p1 + ((size_t)b*256 + mp)*NANCH + oy*64 + xb + lm;
#pragma unroll
      for (int j=0;j<2;j++) cp[j*16] = fmaxf(accp[i][j][r] + bv, 0.f);
    }
  }
}

// ---------------- 1x1 conv 256->32 (fp32, mask path) ----------------
__global__ __launch_bounds__(256) void pw2k2(const float* __restrict__ p1,
    const float* __restrict__ wT, const float* __restrict__ bias,
    float* __restrict__ proto){
  const int b  = blockIdx.y;
  const int sp = blockIdx.x*256 + threadIdx.x;
  float acc[32];
#pragma unroll
  for (int c=0;c<32;c++) acc[c] = bias[c];
  const float* pb = p1 + (size_t)b*256*NANCH + sp;
  for (int ci=0;ci<256;ci++){
    float v = pb[(size_t)ci*NANCH];
    const float* wq = wT + ci*32;
#pragma unroll
    for (int c=0;c<32;c++) acc[c] = fmaf(v, wq[c], acc[c]);
  }
#pragma unroll
  for (int c=0;c<32;c++)
    proto[((size_t)b*32 + c)*NANCH + sp] = acc[c];
}

// ---------------- decode ----------------
__global__ void decodek(const float* __restrict__ hout,
                        float* __restrict__ boxes, float* __restrict__ scores,
                        int* __restrict__ labels, unsigned* __restrict__ maxb){
  const int b = blockIdx.y;
  const int n = blockIdx.x*blockDim.x + threadIdx.x;
  const float* cp = hout + (size_t)b*64*NANCH + n;
  float l[NCLS];
  float M = -1e30f;
#pragma unroll
  for (int c=0;c<NCLS;c++){ l[c] = cp[(size_t)c*NANCH]; M = fmaxf(M, l[c]); }
  float denom = 0.f;
#pragma unroll
  for (int c=0;c<NCLS;c++) denom += expf(l[c]-M);
  float best = -1.f; int bi = 0;
#pragma unroll
  for (int c=0;c<NCLS-1;c++){
    float e = expf(l[c]-M);
    if (e > best){ best = e; bi = c; }
  }
  scores[(size_t)b*NANCH + n] = best/denom;
  labels[(size_t)b*NANCH + n] = bi;

  float dx = cp[21*(size_t)NANCH], dy = cp[22*(size_t)NANCH];
  float dw = cp[23*(size_t)NANCH], dh = cp[24*(size_t)NANCH];
  const int yy = n >> 6, xx = n & 63;
  float cx = (xx+0.5f)*8.f, cy = (yy+0.5f)*8.f;
  float px = cx + dx*32.f, py = cy + dy*32.f;
  float pw = 32.f*expf(dw), ph = 32.f*expf(dh);
  float x1 = px - 0.5f*pw, y1 = py - 0.5f*ph;
  float x2 = px + 0.5f*pw, y2 = py + 0.5f*ph;
  float* bo = boxes + ((size_t)b*NANCH + n)*4;
  bo[0]=x1; bo[1]=y1; bo[2]=x2; bo[3]=y2;
  float mx = fmaxf(fmaxf(x1,y1), fmaxf(x2,y2));
#pragma unroll
  for (int off=32; off>0; off>>=1) mx = fmaxf(mx, __shfl_down(mx, off));
  if ((threadIdx.x & 63) == 0) atomicMax(maxb + b, encf(mx));
}

// ---------------- stable descending sort (bitonic) ----------------
__global__ void __launch_bounds__(1024) sortk(const float* __restrict__ scores,
                     const float* __restrict__ boxes, const int* __restrict__ labels,
                     const unsigned* __restrict__ maxb,
                     int* __restrict__ order, float* __restrict__ sb){
  __shared__ float sc[NANCH];
  __shared__ int   id[NANCH];
  const int b = blockIdx.x, t = threadIdx.x;
  for (int i=t;i<NANCH;i+=1024){ sc[i]=scores[(size_t)b*NANCH+i]; id[i]=i; }
  __syncthreads();
  for (int k=2;k<=NANCH;k<<=1){
    for (int j=k>>1;j>0;j>>=1){
      for (int i=t;i<NANCH;i+=1024){
        int ixj = i ^ j;
        if (ixj > i){
          float sa=sc[i], sb_=sc[ixj]; int ia=id[i], ib=id[ixj];
          bool dir = ((i & k) == 0);
          bool before_ba = (sb_ > sa) || (sb_ == sa && ib < ia);
          if (before_ba == dir){ sc[i]=sb_; sc[ixj]=sa; id[i]=ib; id[ixj]=ia; }
        }
      }
      __syncthreads();
    }
  }
  float mboff = decf(maxb[b]) + 1.0f;
  for (int r=t;r<NANCH;r+=1024){
    int o = id[r];
    order[(size_t)b*NANCH + r] = o;
    float off = (float)labels[(size_t)b*NANCH + o] * mboff;
    const float* bo = boxes + ((size_t)b*NANCH + o)*4;
    float* sp = sb + ((size_t)b*NANCH + r)*4;
    sp[0]=bo[0]+off; sp[1]=bo[1]+off; sp[2]=bo[2]+off; sp[3]=bo[3]+off;
  }
}

// ---------------- IoU>thr bitmask ----------------
__global__ void ioumask(const float* __restrict__ sb, unsigned long long* __restrict__ iou){
  const int b = blockIdx.y;
  const int gid = blockIdx.x*blockDim.x + threadIdx.x;
  const int i = gid >> 5, w = gid & 31;
  const float* base = sb + (size_t)b*NANCH*4;
  unsigned long long bits = 0ull;
  const int j0 = w << 6;
  if (j0 + 63 > i){
    float x1=base[i*4], y1=base[i*4+1], x2=base[i*4+2], y2=base[i*4+3];
    float ai = (x2-x1)*(y2-y1);
    for (int jj=0;jj<64;jj++){
      int j = j0 + jj;
      if (j > i){
        float bx1=base[j*4], by1=base[j*4+1], bx2=base[j*4+2], by2=base[j*4+3];
        float lx=fmaxf(x1,bx1), ly=fmaxf(y1,by1);
        float rx=fminf(x2,bx2), ry=fminf(y2,by2);
        float ww=fmaxf(rx-lx,0.f), hh=fmaxf(ry-ly,0.f);
        float inter = ww*hh;
        float aj = (bx2-bx1)*(by2-by1);
        float v = inter/(ai + aj - inter + 1e-9f);
        if (v > 0.5f) bits |= (1ull << jj);
      }
    }
  }
  iou[((size_t)b*NANCH + i)*32 + w] = bits;
}

// ---------------- greedy NMS skip-scan + gather (one wave per batch) ----------------
__global__ void nmsgather(const unsigned long long* __restrict__ iou,
                          const int* __restrict__ order,
                          const float* __restrict__ boxes, const float* __restrict__ scores,
                          const int* __restrict__ labels,
                          int* __restrict__ keep, float* __restrict__ out){
  const int b = blockIdx.x, lane = threadIdx.x;
  __shared__ int s_keep[TOPK_N];
  unsigned long long sup = 0ull;
  int k = 0, i = 0;
  while (k < TOPK_N){
    unsigned long long avail = (lane < 32) ? ~sup : 0ull;
    const int wi = i >> 6;
    if (lane < wi) avail = 0ull;
    else if (lane == wi) avail &= (~0ull) << (i & 63);
    unsigned long long ball = __ballot(avail != 0ull);
    if (!ball) break;
    int w0 = (int)__builtin_ctzll(ball);
    unsigned long long aw = __shfl(avail, w0);
    int b0 = (int)__builtin_ctzll(aw);
    i = (w0 << 6) + b0;
    int ov = order[(size_t)b*NANCH + i];
    if (lane == 0) s_keep[k] = ov;
    k++;
    unsigned long long row = (lane < 32) ? iou[((size_t)b*NANCH + i)*32 + lane] : 0ull;
    sup |= row;
    i++;
    if (i >= NANCH) break;
  }
  __syncthreads();
  for (int r = lane; r < TOPK_N; r += 64){
    int kv = (r < k) ? s_keep[r] : -1;
    keep[b*TOPK_N + r] = kv;
    float valid = (kv >= 0) ? 1.f : 0.f;
    int kc = (kv < 0) ? 0 : kv;
    const float* bo = boxes + ((size_t)b*NANCH + kc)*4;
#pragma unroll
    for (int c=0;c<4;c++) out[OUT_BOXES + ((size_t)b*TOPK_N + r)*4 + c] = bo[c]*valid;
    out[OUT_SCORES + b*TOPK_N + r] = scores[(size_t)b*NANCH + kc]*valid;
    out[OUT_LABELS + b*TOPK_N + r] = (kv >= 0) ? (float)labels[(size_t)b*NANCH + kc] : 0.f;
    out[OUT_VALID  + b*TOPK_N + r] = valid;
  }
}

// ---------------- fused mask logits + sigmoid + bilinear resize + threshold ----------------
__global__ __launch_bounds__(256) void maskresize(const int* __restrict__ keep,
    const float* __restrict__ hout, const float* __restrict__ proto,
    float* __restrict__ out){
  const int b = blockIdx.y, r = blockIdx.x;
  float* obase = out + OUT_MASKS + ((size_t)b*TOPK_N + r)*131072;
  int ki = keep[b*TOPK_N + r];
  if (ki < 0){
    float4 z = make_float4(0.f,0.f,0.f,0.f);
    for (int idx = threadIdx.x; idx < 32768; idx += 256)
      ((float4*)obase)[idx] = z;
    return;
  }
  __shared__ float cf[32];
  __shared__ float sm[NANCH];
  if (threadIdx.x < 32)
    cf[threadIdx.x] = hout[((size_t)b*64 + 25 + threadIdx.x)*NANCH + ki];
  __syncthreads();
  for (int s = threadIdx.x; s < NANCH; s += 256){
    float acc = 0.f;
#pragma unroll
    for (int p=0;p<32;p++) acc = fmaf(cf[p], proto[((size_t)b*32 + p)*NANCH + s], acc);
    sm[s] = 1.f/(1.f + expf(-acc));
  }
  __syncthreads();
  for (int pid = threadIdx.x; pid < 32768; pid += 256){
    const int y  = pid >> 7;
    const int x4 = (pid & 127) << 2;
    float sy = (y + 0.5f)*0.125f - 0.5f;
    sy = fminf(fmaxf(sy, 0.f), 31.f);
    int y0 = (int)floorf(sy);
    int y1 = min(y0+1, 31);
    float wy = sy - (float)y0;
    const float* r0 = sm + y0*64;
    const float* r1 = sm + y1*64;
    float res[4];
#pragma unroll
    for (int kk=0;kk<4;kk++){
      int x = x4 + kk;
      float sx = (x + 0.5f)*0.125f - 0.5f;
      sx = fminf(fmaxf(sx, 0.f), 63.f);
      int x0 = (int)floorf(sx);
      int x1 = min(x0+1, 63);
      float wx = sx - (float)x0;
      float t0 = r0[x0]*(1.f-wy) + r1[x0]*wy;
      float t1 = r0[x1]*(1.f-wy) + r1[x1]*wy;
      float v  = t0*(1.f-wx) + t1*wx;
      res[kk] = (v > 0.5f) ? 1.f : 0.f;
    }
    *(float4*)(obase + y*512 + x4) = make_float4(res[0], res[1], res[2], res[3]);
  }
}

extern "C" void kernel_launch(void* const* d_in, const int* in_sizes, int n_in,
                              void* d_out, int out_size, void* d_ws, size_t ws_size,
                              hipStream_t stream) {
  const float* images=(const float*)d_in[0];
  const float* w1=(const float*)d_in[1];  const float* b1=(const float*)d_in[2];
  const float* w2=(const float*)d_in[3];  const float* b2=(const float*)d_in[4];
  const float* w3=(const float*)d_in[5];  const float* b3=(const float*)d_in[6];
  const float* pw1=(const float*)d_in[7]; const float* pb1=(const float*)d_in[8];
  const float* pw2=(const float*)d_in[9]; const float* pb2=(const float*)d_in[10];
  const float* cw=(const float*)d_in[11]; const float* cb=(const float*)d_in[12];
  const float* bw=(const float*)d_in[13]; const float* bb=(const float*)d_in[14];
  const float* kw=(const float*)d_in[15]; const float* kb=(const float*)d_in[16];
  float* out = (float*)d_out;
  char* ws = (char*)d_ws;

  short* x1hi = (short*)(ws + OFF_X1HI);
  short* x1lo = (short*)(ws + OFF_X1LO);
  short* x2hi = (short*)(ws + OFF_X2HI);
  short* x2lo = (short*)(ws + OFF_X2LO);
  short* fthi = (short*)(ws + OFF_FTHI);
  short* ftlo = (short*)(ws + OFF_FTLO);
  float* wT1  = (float*)(ws + OFF_WT1);
  short* a2h  = (short*)(ws + OFF_A2H);
  short* a2l  = (short*)(ws + OFF_A2L);
  short* a3h  = (short*)(ws + OFF_A3H);
  short* a3l  = (short*)(ws + OFF_A3L);
  short* ahh  = (short*)(ws + OFF_AHH);
  short* ahl  = (short*)(ws + OFF_AHL);
  short* ap1h = (short*)(ws + OFF_AP1H);
  short* ap1l = (short*)(ws + OFF_AP1L);
  float* wTp2 = (float*)(ws + OFF_WTP2);
  float* bh   = (float*)(ws + OFF_BH);
  float* hout = (float*)(ws + OFF_HOUT);
  float* p1   = (float*)(ws + OFF_P1);
  float* proto= (float*)(ws + OFF_PROTO);
  float* boxes= (float*)(ws + OFF_BOXES);
  float* scores=(float*)(ws + OFF_SCORES);
  int*   labels=(int*)  (ws + OFF_LABELS);
  int*   order =(int*)  (ws + OFF_ORDER);
  float* sb   = (float*)(ws + OFF_SB);
  unsigned long long* iou = (unsigned long long*)(ws + OFF_IOU);
  int*   keep = (int*)  (ws + OFF_KEEP);
  unsigned* maxb = (unsigned*)(ws + OFF_MAXB);

  // halo zero (all 3 layers) + maxb init
  halok3<<<dim3(583), 256, 0, stream>>>(x1hi, x1lo, x2hi, x2lo, fthi, ftlo, maxb);

  // all weight packing in one dispatch
  packall<<<dim3(4359), 256, 0, stream>>>(w1, wT1, w2, a2h, a2l, w3, a3h, a3l,
                                          pw1, ap1h, ap1l, cw, bw, kw, cb, bb, kb,
                                          ahh, ahl, bh, pw2, wTp2);

  // conv1: direct fp32 -> x1 C8HW8 padded hi/lo
  conv1k<<<dim3(64,4,BB), 256, 0, stream>>>(images, wT1, b1, x1hi, x1lo);

  // conv2: split-bf16, hi+lo LDS-staged half-rows (parity layout), S=2
  cgemm_row<64,576,128,2,4,2,130,258,2,true,true,0,66,130>
      <<<dim3(128,1,BB), 256, 0, stream>>>(a2h, a2l, x1hi, x1lo, b2, nullptr, x2hi, x2lo);

  // conv3: split-bf16, hi+lo LDS-staged rows (parity layout), S=2; NW=8 single y-tile
  cgemm_row<128,1152,256,2,8,2,66,130,1,true,true,0,34,66>
      <<<dim3(32,1,BB), 512, 0, stream>>>(a3h, a3l, x2hi, x2lo, b3, nullptr, fthi, ftlo);

  // heads + pw1 fused, x-split: 512 blocks (2/CU, 8 waves/CU)
  headspw1<<<dim3(64,1,BB), 256, 0, stream>>>(ahh, ahl, ap1h, fthi, ftlo,
                                              bh, pb1, hout, p1);

  pw2k2<<<dim3(8,BB), 256, 0, stream>>>(p1, wTp2, pb2, proto);

  // decode + NMS
  decodek<<<dim3(8,BB), 256, 0, stream>>>(hout, boxes, scores, labels, maxb);
  sortk<<<dim3(BB), 1024, 0, stream>>>(scores, boxes, labels, maxb, order, sb);
  ioumask<<<dim3(256,BB), 256, 0, stream>>>(sb, iou);
  nmsgather<<<dim3(BB), 64, 0, stream>>>(iou, order, boxes, scores, labels, keep, out);

  // fused masks
  maskresize<<<dim3(TOPK_N,BB), 256, 0, stream>>>(keep, hout, proto, out);
}

// Round 4
// 970.411 us; speedup vs baseline: 1.0235x; 1.0235x over previous
//
#include <hip/hip_runtime.h>
#include <hip/hip_bf16.h>
#include <math.h>

#define BB 8
#define NCLS 21
#define NANCH 2048
#define TOPK_N 100

// ---------------- workspace layout (bytes) ----------------
static const size_t OFF_X1HI = 0;           // 8*8*130*258*8*2 = 34,344,960
static const size_t OFF_X1LO = 34344960;
static const size_t OFF_X2HI = 68689920;    // 8*16*66*130*8*2
static const size_t OFF_X2LO = 86261760;
static const size_t OFF_FTHI = 103833600;   // 8*32*34*66*8*2
static const size_t OFF_FTLO = 113025024;
static const size_t OFF_WT1  = 122216448;
static const size_t OFF_A2H  = 122223616;
static const size_t OFF_A2L  = 122371072;
static const size_t OFF_A3H  = 122518528;
static const size_t OFF_A3L  = 123108352;
static const size_t OFF_AHH  = 123698176;
static const size_t OFF_AHL  = 123993088;
static const size_t OFF_AP1H = 124288000;
static const size_t OFF_AP1L = 125467648;
static const size_t OFF_WTP2 = 126647296;
static const size_t OFF_BH   = 126680064;
static const size_t OFF_HOUT = 126680576;
static const size_t OFF_P1   = 130874880;
static const size_t OFF_PROTO= 147652096;
static const size_t OFF_BOXES= 149749248;
static const size_t OFF_SCORES=150011392;
static const size_t OFF_LABELS=150076928;
static const size_t OFF_ORDER= 150142464;
static const size_t OFF_SB   = 150208000;
static const size_t OFF_IOU  = 150470144;
static const size_t OFF_KEEP = 154664448;
static const size_t OFF_MAXB = 154668032;

// ---------------- output layout (float elements) ----------------
static const size_t OUT_BOXES  = 0;
static const size_t OUT_SCORES = 3200;
static const size_t OUT_LABELS = 4000;
static const size_t OUT_MASKS  = 4800;
static const size_t OUT_VALID  = 104862400;

typedef __attribute__((ext_vector_type(8))) short bf16x8;
typedef __attribute__((ext_vector_type(4))) float f32x4;

__device__ __forceinline__ unsigned encf(float f){
  unsigned u = __float_as_uint(f);
  return (u & 0x80000000u) ? ~u : (u | 0x80000000u);
}
__device__ __forceinline__ float decf(unsigned u){
  unsigned b = (u & 0x80000000u) ? (u & 0x7fffffffu) : ~u;
  return __uint_as_float(b);
}
__device__ __forceinline__ short f2bf(float f){
  __hip_bfloat16 h = __float2bfloat16(f);
  return *(short*)&h;
}
__device__ __forceinline__ float bf2f(short h){
  return __uint_as_float(((unsigned)(unsigned short)h) << 16);
}

// ---------------- halo-only zero, all 3 layers in one kernel ----------------
__global__ void halok3(short* __restrict__ x1hi, short* __restrict__ x1lo,
                       short* __restrict__ x2hi, short* __restrict__ x2lo,
                       short* __restrict__ fthi, short* __restrict__ ftlo,
                       unsigned* __restrict__ maxb){
  int i = blockIdx.x*256 + threadIdx.x;
  if (i < BB) maxb[i] = 0u;
  short *hi, *lo; int Hp, Wp, cell, bg;
  if (i < 49408){
    hi=x1hi; lo=x1lo; Hp=130; Wp=258; cell = i % 772; bg = i / 772;
  } else if (i < 99072){
    int j = i - 49408; hi=x2hi; lo=x2lo; Hp=66; Wp=130; cell = j % 388; bg = j / 388;
  } else if (i < 149248){
    int j = i - 99072; hi=fthi; lo=ftlo; Hp=34; Wp=66; cell = j % 196; bg = j / 196;
  } else return;
  int y, x;
  if (cell < Wp)        { y = 0;      x = cell; }
  else if (cell < 2*Wp) { y = Hp-1;   x = cell - Wp; }
  else { int r = cell - 2*Wp; y = 1 + (r>>1); x = (r&1) ? (Wp-1) : 0; }
  size_t ad = (((size_t)bg*Hp + y)*Wp + x)*8;
  bf16x8 z = (bf16x8){0,0,0,0,0,0,0,0};
  *(bf16x8*)(hi + ad) = z;
  *(bf16x8*)(lo + ad) = z;
}

// ---------------- weight packers (device bodies + one dispatcher) ----------------
template<int CIN,int COUT,int KK>
__device__ __forceinline__ void packw_body(int i, const float* __restrict__ w,
                                           float* __restrict__ wT){
  if (i >= CIN*KK*COUT) return;
  int co = i % COUT; int r = i / COUT;
  int ci = r / KK,  k = r % KK;
  wT[i] = w[(co*CIN + ci)*KK + k];
}

template<int CIN,int COUT>
__device__ __forceinline__ void packA_body(int i, const float* __restrict__ w,
                                           short* __restrict__ Ahi, short* __restrict__ Alo){
  constexpr int K = CIN*9;
  constexpr int KS = K/32;
  if (i >= COUT*K) return;
  int sub  = i & 7;
  int lane = (i >> 3) & 63;
  int rest = i >> 9;
  int ks = rest % KS;
  int mt = rest / KS;
  int m = mt*16 + (lane & 15);
  int k = ks*32 + (lane >> 4)*8 + sub;
  int tap = k / CIN, ci = k - tap*CIN;
  float v = w[(m*CIN + ci)*9 + tap];
  short h = f2bf(v);
  Ahi[i] = h;
  Alo[i] = f2bf(v - bf2f(h));
}

__device__ __forceinline__ void packAh_body(int i,
    const float* __restrict__ cw, const float* __restrict__ bw,
    const float* __restrict__ kw, const float* __restrict__ cb,
    const float* __restrict__ bb, const float* __restrict__ kb,
    short* __restrict__ Ahi, short* __restrict__ Alo, float* __restrict__ bh){
  if (i < 64){
    float v = 0.f;
    if (i < 21) v = cb[i]; else if (i < 25) v = bb[i-21]; else if (i < 57) v = kb[i-25];
    bh[i] = v;
  }
  if (i >= 64*2304) return;
  constexpr int KS = 72;
  int sub  = i & 7;
  int lane = (i >> 3) & 63;
  int rest = i >> 9;
  int ks = rest % KS;
  int mt = rest / KS;
  int m = mt*16 + (lane & 15);
  int k = ks*32 + (lane >> 4)*8 + sub;
  int tap = k >> 8, ci = k & 255;
  float v = 0.f;
  if (m < 21)      v = cw[(m*256 + ci)*9 + tap];
  else if (m < 25) v = bw[((m-21)*256 + ci)*9 + tap];
  else if (m < 57) v = kw[((m-25)*256 + ci)*9 + tap];
  short h = f2bf(v);
  Ahi[i] = h;
  Alo[i] = f2bf(v - bf2f(h));
}

// block ranges: [0,288) packA<64,128>; [288,1440) packA<128,256>;
// [1440,3744) packA<256,256>; [3744,4320) packAh; [4320,4327) packw<3,64,9>;
// [4327,4359) packw<256,32,1>
__global__ void packall(const float* __restrict__ w1, float* __restrict__ wT1,
                        const float* __restrict__ w2, short* __restrict__ a2h, short* __restrict__ a2l,
                        const float* __restrict__ w3, short* __restrict__ a3h, short* __restrict__ a3l,
                        const float* __restrict__ pw1, short* __restrict__ ap1h, short* __restrict__ ap1l,
                        const float* __restrict__ cw, const float* __restrict__ bw,
                        const float* __restrict__ kw, const float* __restrict__ cb,
                        const float* __restrict__ bb, const float* __restrict__ kb,
                        short* __restrict__ ahh, short* __restrict__ ahl, float* __restrict__ bh,
                        const float* __restrict__ pw2, float* __restrict__ wTp2){
  int blk = blockIdx.x, t = threadIdx.x;
  if (blk < 288)        packA_body<64,128>(blk*256+t, w2, a2h, a2l);
  else if (blk < 1440)  packA_body<128,256>((blk-288)*256+t, w3, a3h, a3l);
  else if (blk < 3744)  packA_body<256,256>((blk-1440)*256+t, pw1, ap1h, ap1l);
  else if (blk < 4320)  packAh_body((blk-3744)*256+t, cw,bw,kw,cb,bb,kb, ahh,ahl,bh);
  else if (blk < 4327)  packw_body<3,64,9>((blk-4320)*256+t, w1, wT1);
  else                  packw_body<256,32,1>((blk-4327)*256+t, pw2, wTp2);
}

// ---------------- conv1: direct fp32, epilogue -> C8HW8 padded bf16 hi/lo ----------------
__global__ __launch_bounds__(256) void conv1k(const float* __restrict__ img,
    const float* __restrict__ wT, const float* __restrict__ bias,
    short* __restrict__ x1hi, short* __restrict__ x1lo){
  const int b   = blockIdx.z;
  const int co0 = blockIdx.y * 16;
  const int g   = blockIdx.x*256 + threadIdx.x;
  const int y  = g >> 7;
  const int x0 = (g & 127) << 1;

  float acc[16][2];
#pragma unroll
  for (int c=0;c<16;c++){
    float bv = bias[co0+c];
    acc[c][0] = bv; acc[c][1] = bv;
  }
  int   off[3][5];
  float msk[3][5];
#pragma unroll
  for (int kh=0;kh<3;kh++){
    int iy = y*2 - 1 + kh;
    bool okr = (iy >= 0) && (iy < 256);
    int ro = okr ? iy*512 : 0;
#pragma unroll
    for (int t=0;t<5;t++){
      int col = x0*2 - 1 + t;
      bool ok = okr && (col >= 0) && (col < 512);
      off[kh][t] = ok ? (ro + col) : 0;
      msk[kh][t] = ok ? 1.f : 0.f;
    }
  }
  const float* inb = img + (size_t)b*3*256*512;
  for (int ci=0; ci<3; ci++){
    const float* inc = inb + (size_t)ci*256*512;
    float v[3][5];
#pragma unroll
    for (int kh=0;kh<3;kh++)
#pragma unroll
      for (int t=0;t<5;t++)
        v[kh][t] = inc[off[kh][t]] * msk[kh][t];
    const float* wp = wT + ci*9*64 + co0;
#pragma unroll
    for (int kh=0;kh<3;kh++)
#pragma unroll
    for (int kw=0;kw<3;kw++){
      const float* wq = wp + (kh*3+kw)*64;
#pragma unroll
      for (int c=0;c<16;c++){
        float wv = wq[c];
        acc[c][0] = fmaf(wv, v[kh][2*0+kw], acc[c][0]);
        acc[c][1] = fmaf(wv, v[kh][2*1+kw], acc[c][1]);
      }
    }
  }
#pragma unroll
  for (int s=0;s<2;s++){
    short hv[16] __attribute__((aligned(16)));
    short lv[16] __attribute__((aligned(16)));
#pragma unroll
    for (int c=0;c<16;c++){
      float r = fmaxf(acc[c][s], 0.f);
      short h = f2bf(r);
      hv[c] = h;
      lv[c] = f2bf(r - bf2f(h));
    }
#pragma unroll
    for (int g2=0; g2<2; g2++){
      size_t ad = (((size_t)(b*8 + (co0>>3) + g2)*130 + (y+1))*258 + (x0+s+1))*8;
      *(bf16x8*)(x1hi + ad) = *(bf16x8*)(hv + g2*8);
      *(bf16x8*)(x1lo + ad) = *(bf16x8*)(lv + g2*8);
    }
  }
}

// ---------------- cgemm_row: LDS-staged B rows (conv2/conv3/pw1) ----------------
template<int CIN,int K,int M,int MW,int NW,int S,int IPH,int IPW,int NXB,
         bool SPLIT,bool STAGELO,int EMODE,int OPH,int OPW>
__global__ __launch_bounds__(NW*64) void cgemm_row(
    const short* __restrict__ Ahi, const short* __restrict__ Alo,
    const short* __restrict__ Bhi, const short* __restrict__ Blo,
    const float* __restrict__ bias, float* __restrict__ outf,
    short* __restrict__ outhi, short* __restrict__ outlo){
  static_assert(CIN % 32 == 0, "CIN must be multiple of 32");
  constexpr int NT = 64*32;
  constexpr int KS = K/32;
  constexpr int CG = CIN/8;
  constexpr int SW  = 64*S + 2;
  constexpr int SWP = (S==2) ? (SW/2 + 1) : SW;
  constexpr int PARS = (S==2) ? 2 : 1;
  constexpr int LOOFF = CG*PARS*SWP*8;
  constexpr int BUFS = (SPLIT && STAGELO) ? 2 : 1;
  __shared__ __align__(16) short sB[BUFS*LOOFF];

  const int b    = blockIdx.z;
  const int oy   = blockIdx.x / NXB;
  const int xb   = (blockIdx.x % NXB) * 64;
  const int wave = threadIdx.x >> 6;
  const int lane = threadIdx.x & 63;
  const int lm = lane & 15, lq = lane >> 4;
  const int m0 = (blockIdx.y * NW + wave) * (MW*16);
  const int tid = threadIdx.x;

  f32x4 acc[MW][4];
#pragma unroll
  for (int i=0;i<MW;i++)
#pragma unroll
    for (int j=0;j<4;j++) acc[i][j] = (f32x4){0.f,0.f,0.f,0.f};

  const short* Ah_l = Ahi + (size_t)lane*8;
  const short* Al_l = Alo + (size_t)lane*8;
  const int mt0 = m0 >> 4;
  const size_t plane = (size_t)IPH*IPW;
  const short* Bl0 = Blo + ((size_t)b*CG + lq)*plane*8;

#pragma unroll 1
  for (int dy=0; dy<3; dy++){
    const int iy = oy*S + dy;
    __syncthreads();
    {
      const short* srch = Bhi + (((size_t)b*CG*IPH + iy)*IPW + (size_t)(xb*S))*8;
      for (int c = tid; c < CG*SW; c += NW*64){
        int g = c / SW, p = c - g*SW;
        int dst = (S==2) ? ((g*2 + (p&1))*SWP + (p>>1)) : (g*SW + p);
        *(bf16x8*)(&sB[(size_t)dst*8]) =
          *(const bf16x8*)(srch + ((size_t)g*plane + p)*8);
      }
      if constexpr (SPLIT && STAGELO){
        const short* srcl = Blo + (((size_t)b*CG*IPH + iy)*IPW + (size_t)(xb*S))*8;
        for (int c = tid; c < CG*SW; c += NW*64){
          int g = c / SW, p = c - g*SW;
          int dst = (S==2) ? ((g*2 + (p&1))*SWP + (p>>1)) : (g*SW + p);
          *(bf16x8*)(&sB[LOOFF + (size_t)dst*8]) =
            *(const bf16x8*)(srcl + ((size_t)g*plane + p)*8);
        }
      }
    }
    __syncthreads();
#pragma unroll
    for (int dx=0; dx<3; dx++){
      const int tap = dy*3 + dx;
      const int ksb = tap*(CIN/32);
      for (int kc=0; kc<CIN; kc+=32){
        const int ks = ksb + (kc>>5);
        int ra[4];
#pragma unroll
        for (int j=0;j<4;j++){
          int pc = (j*16 + lm)*S + dx;
          ra[j] = (S==2) ? ((((kc>>3) + lq)*2 + (pc&1))*SWP + (pc>>1))
                         : (((kc>>3) + lq)*SW + pc);
        }
        bf16x8 ah[MW], bh_[4];
#pragma unroll
        for (int i=0;i<MW;i++)
          ah[i] = *(const bf16x8*)(Ah_l + ((size_t)(mt0+i)*KS + ks)*512);
#pragma unroll
        for (int j=0;j<4;j++)
          bh_[j] = *(const bf16x8*)(&sB[(size_t)ra[j]*8]);
        if constexpr (SPLIT){
          bf16x8 al[MW], bl_[4];
#pragma unroll
          for (int i=0;i<MW;i++)
            al[i] = *(const bf16x8*)(Al_l + ((size_t)(mt0+i)*KS + ks)*512);
          if constexpr (STAGELO){
#pragma unroll
            for (int j=0;j<4;j++)
              bl_[j] = *(const bf16x8*)(&sB[LOOFF + (size_t)ra[j]*8]);
          } else {
#pragma unroll
            for (int j=0;j<4;j++){
              size_t pix = (size_t)iy*IPW + (size_t)((xb + j*16 + lm)*S + dx);
              bl_[j] = *(const bf16x8*)(Bl0 + ((size_t)(kc>>3)*plane + pix)*8);
            }
          }
#pragma unroll
          for (int j=0;j<4;j++)
#pragma unroll
            for (int i=0;i<MW;i++)
              acc[i][j] = __builtin_amdgcn_mfma_f32_16x16x32_bf16(ah[i], bh_[j], acc[i][j], 0,0,0);
#pragma unroll
          for (int j=0;j<4;j++)
#pragma unroll
            for (int i=0;i<MW;i++)
              acc[i][j] = __builtin_amdgcn_mfma_f32_16x16x32_bf16(ah[i], bl_[j], acc[i][j], 0,0,0);
#pragma unroll
          for (int j=0;j<4;j++)
#pragma unroll
            for (int i=0;i<MW;i++)
              acc[i][j] = __builtin_amdgcn_mfma_f32_16x16x32_bf16(al[i], bh_[j], acc[i][j], 0,0,0);
        } else {
#pragma unroll
          for (int j=0;j<4;j++)
#pragma unroll
            for (int i=0;i<MW;i++)
              acc[i][j] = __builtin_amdgcn_mfma_f32_16x16x32_bf16(ah[i], bh_[j], acc[i][j], 0,0,0);
        }
      }
    }
  }

#pragma unroll
  for (int i=0;i<MW;i++){
#pragma unroll
    for (int r=0;r<4;r++){
      const int m = m0 + i*16 + lq*4 + r;
      const float bv = bias[m];
      if constexpr (EMODE == 0){
#pragma unroll
        for (int j=0;j<4;j++){
          const int ox = xb + j*16 + lm;
          float v = fmaxf(acc[i][j][r] + bv, 0.f);
          short h = f2bf(v);
          short l = f2bf(v - bf2f(h));
          size_t ad = ((((size_t)(b*(M/8) + (m>>3))*OPH + (oy+1))*OPW + (ox+1)))*8 + (m&7);
          outhi[ad] = h;
          outlo[ad] = l;
        }
      } else {
        float* cp = outf + ((size_t)b*M + m)*NT + oy*64 + lm;
#pragma unroll
        for (int j=0;j<4;j++){
          float v = acc[i][j][r] + bv;
          if constexpr (EMODE == 2) v = fmaxf(v, 0.f);
          cp[j*16] = v;
        }
      }
    }
  }
}

// ---------------- heads GEMM + fused decode ----------------
// R1's heads structure (CIN=256,K=2304,M=64,MW=1,NW=4,S=1, split, staged lo).
// Epilogue: write hout (bit-identical) AND stage acc+bias into LDS f32, then
// threads 0..63 run the exact decodek sequence for this block's 64 anchors.
__global__ __launch_bounds__(256) void headsdec(
    const short* __restrict__ Ahi, const short* __restrict__ Alo,
    const short* __restrict__ Bhi, const short* __restrict__ Blo,
    const float* __restrict__ bias, float* __restrict__ hout,
    float* __restrict__ boxes, float* __restrict__ scores,
    int* __restrict__ labels, unsigned* __restrict__ maxb){
  constexpr int KS = 72;           // 2304/32
  constexpr int CG = 32;           // 256/8
  constexpr int SW = 66;
  constexpr int IPH = 34, IPW = 66;
  constexpr int LOOFF = CG*SW*8;   // 16896 shorts per buffer
  __shared__ __align__(16) short sB[2*LOOFF];   // 67.5 KB; reused for decode stage

  const int b  = blockIdx.z;
  const int oy = blockIdx.x;
  const int wave = threadIdx.x >> 6;
  const int lane = threadIdx.x & 63;
  const int lm = lane & 15, lq = lane >> 4;
  const int tid = threadIdx.x;

  f32x4 acc[4];
#pragma unroll
  for (int j=0;j<4;j++) acc[j] = (f32x4){0.f,0.f,0.f,0.f};

  const short* Ah_l = Ahi + (size_t)lane*8;
  const short* Al_l = Alo + (size_t)lane*8;
  const size_t plane = (size_t)IPH*IPW;

#pragma unroll 1
  for (int dy=0; dy<3; dy++){
    const int iy = oy + dy;
    __syncthreads();
    {
      const short* srch = Bhi + ((size_t)b*CG*IPH + iy)*IPW*8;
      const short* srcl = Blo + ((size_t)b*CG*IPH + iy)*IPW*8;
      for (int c = tid; c < CG*SW; c += 256){
        int g = c / SW, p = c - g*SW;
        *(bf16x8*)(&sB[(size_t)c*8]) =
          *(const bf16x8*)(srch + ((size_t)g*plane + p)*8);
        *(bf16x8*)(&sB[LOOFF + (size_t)c*8]) =
          *(const bf16x8*)(srcl + ((size_t)g*plane + p)*8);
      }
    }
    __syncthreads();
#pragma unroll
    for (int dx=0; dx<3; dx++){
      const int tap = dy*3 + dx;
      const int ksb = tap*8;
      for (int kc=0; kc<256; kc+=32){
        const int ks = ksb + (kc>>5);
        int ra[4];
#pragma unroll
        for (int j=0;j<4;j++) ra[j] = ((kc>>3) + lq)*SW + (j*16 + lm) + dx;
        bf16x8 bh_[4], bl_[4];
#pragma unroll
        for (int j=0;j<4;j++){
          bh_[j] = *(const bf16x8*)(&sB[(size_t)ra[j]*8]);
          bl_[j] = *(const bf16x8*)(&sB[LOOFF + (size_t)ra[j]*8]);
        }
        bf16x8 ah = *(const bf16x8*)(Ah_l + ((size_t)wave*KS + ks)*512);
        bf16x8 al = *(const bf16x8*)(Al_l + ((size_t)wave*KS + ks)*512);
#pragma unroll
        for (int j=0;j<4;j++)
          acc[j] = __builtin_amdgcn_mfma_f32_16x16x32_bf16(ah, bh_[j], acc[j], 0,0,0);
#pragma unroll
        for (int j=0;j<4;j++)
          acc[j] = __builtin_amdgcn_mfma_f32_16x16x32_bf16(ah, bl_[j], acc[j], 0,0,0);
#pragma unroll
        for (int j=0;j<4;j++)
          acc[j] = __builtin_amdgcn_mfma_f32_16x16x32_bf16(al, bh_[j], acc[j], 0,0,0);
      }
    }
  }

  // epilogue: hout write + LDS f32 stage [64 rows][68 stride]
  __syncthreads();                  // all k-loop LDS reads done before reuse
  float* sF = (float*)sB;
#pragma unroll
  for (int r=0;r<4;r++){
    const int m = wave*16 + lq*4 + r;
    const float bv = bias[m];
    float* cp = hout + ((size_t)b*64 + m)*NANCH + oy*64 + lm;
#pragma unroll
    for (int j=0;j<4;j++){
      float v = acc[j][r] + bv;
      cp[j*16] = v;
      sF[m*68 + j*16 + lm] = v;
    }
  }
  __syncthreads();

  // decode (exact decodek sequence) for anchors n = oy*64 + 0..63
  if (tid < 64){
    const int n = oy*64 + tid;
    float l[NCLS];
    float M = -1e30f;
#pragma unroll
    for (int c=0;c<NCLS;c++){ l[c] = sF[c*68 + tid]; M = fmaxf(M, l[c]); }
    float denom = 0.f;
#pragma unroll
    for (int c=0;c<NCLS;c++) denom += expf(l[c]-M);
    float best = -1.f; int bi = 0;
#pragma unroll
    for (int c=0;c<NCLS-1;c++){
      float e = expf(l[c]-M);
      if (e > best){ best = e; bi = c; }
    }
    scores[(size_t)b*NANCH + n] = best/denom;
    labels[(size_t)b*NANCH + n] = bi;

    float dxv = sF[21*68 + tid], dyv = sF[22*68 + tid];
    float dwv = sF[23*68 + tid], dhv = sF[24*68 + tid];
    const int yy = n >> 6, xx = n & 63;
    float cx = (xx+0.5f)*8.f, cy = (yy+0.5f)*8.f;
    float px = cx + dxv*32.f, py = cy + dyv*32.f;
    float pw = 32.f*expf(dwv), ph = 32.f*expf(dhv);
    float x1 = px - 0.5f*pw, y1 = py - 0.5f*ph;
    float x2 = px + 0.5f*pw, y2 = py + 0.5f*ph;
    float* bo = boxes + ((size_t)b*NANCH + n)*4;
    bo[0]=x1; bo[1]=y1; bo[2]=x2; bo[3]=y2;
    float mx = fmaxf(fmaxf(x1,y1), fmaxf(x2,y2));
#pragma unroll
    for (int off=32; off>0; off>>=1) mx = fmaxf(mx, __shfl_down(mx, off));
    if (tid == 0) atomicMax(maxb + b, encf(mx));
  }
}

// ---------------- 1x1 conv 256->32 (fp32, mask path) ----------------
__global__ __launch_bounds__(256) void pw2k2(const float* __restrict__ p1,
    const float* __restrict__ wT, const float* __restrict__ bias,
    float* __restrict__ proto){
  const int b  = blockIdx.y;
  const int sp = blockIdx.x*256 + threadIdx.x;
  float acc[32];
#pragma unroll
  for (int c=0;c<32;c++) acc[c] = bias[c];
  const float* pb = p1 + (size_t)b*256*NANCH + sp;
  for (int ci=0;ci<256;ci++){
    float v = pb[(size_t)ci*NANCH];
    const float* wq = wT + ci*32;
#pragma unroll
    for (int c=0;c<32;c++) acc[c] = fmaf(v, wq[c], acc[c]);
  }
#pragma unroll
  for (int c=0;c<32;c++)
    proto[((size_t)b*32 + c)*NANCH + sp] = acc[c];
}

// ---------------- stable descending sort (bitonic) ----------------
__global__ void __launch_bounds__(1024) sortk(const float* __restrict__ scores,
                     const float* __restrict__ boxes, const int* __restrict__ labels,
                     const unsigned* __restrict__ maxb,
                     int* __restrict__ order, float* __restrict__ sb){
  __shared__ float sc[NANCH];
  __shared__ int   id[NANCH];
  const int b = blockIdx.x, t = threadIdx.x;
  for (int i=t;i<NANCH;i+=1024){ sc[i]=scores[(size_t)b*NANCH+i]; id[i]=i; }
  __syncthreads();
  for (int k=2;k<=NANCH;k<<=1){
    for (int j=k>>1;j>0;j>>=1){
      for (int i=t;i<NANCH;i+=1024){
        int ixj = i ^ j;
        if (ixj > i){
          float sa=sc[i], sb_=sc[ixj]; int ia=id[i], ib=id[ixj];
          bool dir = ((i & k) == 0);
          bool before_ba = (sb_ > sa) || (sb_ == sa && ib < ia);
          if (before_ba == dir){ sc[i]=sb_; sc[ixj]=sa; id[i]=ib; id[ixj]=ia; }
        }
      }
      __syncthreads();
    }
  }
  float mboff = decf(maxb[b]) + 1.0f;
  for (int r=t;r<NANCH;r+=1024){
    int o = id[r];
    order[(size_t)b*NANCH + r] = o;
    float off = (float)labels[(size_t)b*NANCH + o] * mboff;
    const float* bo = boxes + ((size_t)b*NANCH + o)*4;
    float* sp = sb + ((size_t)b*NANCH + r)*4;
    sp[0]=bo[0]+off; sp[1]=bo[1]+off; sp[2]=bo[2]+off; sp[3]=bo[3]+off;
  }
}

// ---------------- IoU>thr bitmask ----------------
__global__ void ioumask(const float* __restrict__ sb, unsigned long long* __restrict__ iou){
  const int b = blockIdx.y;
  const int gid = blockIdx.x*blockDim.x + threadIdx.x;
  const int i = gid >> 5, w = gid & 31;
  const float* base = sb + (size_t)b*NANCH*4;
  unsigned long long bits = 0ull;
  const int j0 = w << 6;
  if (j0 + 63 > i){
    float x1=base[i*4], y1=base[i*4+1], x2=base[i*4+2], y2=base[i*4+3];
    float ai = (x2-x1)*(y2-y1);
    for (int jj=0;jj<64;jj++){
      int j = j0 + jj;
      if (j > i){
        float bx1=base[j*4], by1=base[j*4+1], bx2=base[j*4+2], by2=base[j*4+3];
        float lx=fmaxf(x1,bx1), ly=fmaxf(y1,by1);
        float rx=fminf(x2,bx2), ry=fminf(y2,by2);
        float ww=fmaxf(rx-lx,0.f), hh=fmaxf(ry-ly,0.f);
        float inter = ww*hh;
        float aj = (bx2-bx1)*(by2-by1);
        float v = inter/(ai + aj - inter + 1e-9f);
        if (v > 0.5f) bits |= (1ull << jj);
      }
    }
  }
  iou[((size_t)b*NANCH + i)*32 + w] = bits;
}

// ---------------- greedy NMS skip-scan + gather (one wave per batch) ----------------
__global__ void nmsgather(const unsigned long long* __restrict__ iou,
                          const int* __restrict__ order,
                          const float* __restrict__ boxes, const float* __restrict__ scores,
                          const int* __restrict__ labels,
                          int* __restrict__ keep, float* __restrict__ out){
  const int b = blockIdx.x, lane = threadIdx.x;
  __shared__ int s_keep[TOPK_N];
  unsigned long long sup = 0ull;
  int k = 0, i = 0;
  while (k < TOPK_N){
    unsigned long long avail = (lane < 32) ? ~sup : 0ull;
    const int wi = i >> 6;
    if (lane < wi) avail = 0ull;
    else if (lane == wi) avail &= (~0ull) << (i & 63);
    unsigned long long ball = __ballot(avail != 0ull);
    if (!ball) break;
    int w0 = (int)__builtin_ctzll(ball);
    unsigned long long aw = __shfl(avail, w0);
    int b0 = (int)__builtin_ctzll(aw);
    i = (w0 << 6) + b0;
    int ov = order[(size_t)b*NANCH + i];
    if (lane == 0) s_keep[k] = ov;
    k++;
    unsigned long long row = (lane < 32) ? iou[((size_t)b*NANCH + i)*32 + lane] : 0ull;
    sup |= row;
    i++;
    if (i >= NANCH) break;
  }
  __syncthreads();
  for (int r = lane; r < TOPK_N; r += 64){
    int kv = (r < k) ? s_keep[r] : -1;
    keep[b*TOPK_N + r] = kv;
    float valid = (kv >= 0) ? 1.f : 0.f;
    int kc = (kv < 0) ? 0 : kv;
    const float* bo = boxes + ((size_t)b*NANCH + kc)*4;
#pragma unroll
    for (int c=0;c<4;c++) out[OUT_BOXES + ((size_t)b*TOPK_N + r)*4 + c] = bo[c]*valid;
    out[OUT_SCORES + b*TOPK_N + r] = scores[(size_t)b*NANCH + kc]*valid;
    out[OUT_LABELS + b*TOPK_N + r] = (kv >= 0) ? (float)labels[(size_t)b*NANCH + kc] : 0.f;
    out[OUT_VALID  + b*TOPK_N + r] = valid;
  }
}

// ---------------- fused mask logits + sigmoid + bilinear resize + threshold ----------------
__global__ __launch_bounds__(256) void maskresize(const int* __restrict__ keep,
    const float* __restrict__ hout, const float* __restrict__ proto,
    float* __restrict__ out){
  const int b = blockIdx.y, r = blockIdx.x;
  float* obase = out + OUT_MASKS + ((size_t)b*TOPK_N + r)*131072;
  int ki = keep[b*TOPK_N + r];
  if (ki < 0){
    float4 z = make_float4(0.f,0.f,0.f,0.f);
    for (int idx = threadIdx.x; idx < 32768; idx += 256)
      ((float4*)obase)[idx] = z;
    return;
  }
  __shared__ float cf[32];
  __shared__ float sm[NANCH];
  if (threadIdx.x < 32)
    cf[threadIdx.x] = hout[((size_t)b*64 + 25 + threadIdx.x)*NANCH + ki];
  __syncthreads();
  for (int s = threadIdx.x; s < NANCH; s += 256){
    float acc = 0.f;
#pragma unroll
    for (int p=0;p<32;p++) acc = fmaf(cf[p], proto[((size_t)b*32 + p)*NANCH + s], acc);
    sm[s] = 1.f/(1.f + expf(-acc));
  }
  __syncthreads();
  for (int pid = threadIdx.x; pid < 32768; pid += 256){
    const int y  = pid >> 7;
    const int x4 = (pid & 127) << 2;
    float sy = (y + 0.5f)*0.125f - 0.5f;
    sy = fminf(fmaxf(sy, 0.f), 31.f);
    int y0 = (int)floorf(sy);
    int y1 = min(y0+1, 31);
    float wy = sy - (float)y0;
    const float* r0 = sm + y0*64;
    const float* r1 = sm + y1*64;
    float res[4];
#pragma unroll
    for (int kk=0;kk<4;kk++){
      int x = x4 + kk;
      float sx = (x + 0.5f)*0.125f - 0.5f;
      sx = fminf(fmaxf(sx, 0.f), 63.f);
      int x0 = (int)floorf(sx);
      int x1 = min(x0+1, 63);
      float wx = sx - (float)x0;
      float t0 = r0[x0]*(1.f-wy) + r1[x0]*wy;
      float t1 = r0[x1]*(1.f-wy) + r1[x1]*wy;
      float v  = t0*(1.f-wx) + t1*wx;
      res[kk] = (v > 0.5f) ? 1.f : 0.f;
    }
    *(float4*)(obase + y*512 + x4) = make_float4(res[0], res[1], res[2], res[3]);
  }
}

extern "C" void kernel_launch(void* const* d_in, const int* in_sizes, int n_in,
                              void* d_out, int out_size, void* d_ws, size_t ws_size,
                              hipStream_t stream) {
  const float* images=(const float*)d_in[0];
  const float* w1=(const float*)d_in[1];  const float* b1=(const float*)d_in[2];
  const float* w2=(const float*)d_in[3];  const float* b2=(const float*)d_in[4];
  const float* w3=(const float*)d_in[5];  const float* b3=(const float*)d_in[6];
  const float* pw1=(const float*)d_in[7]; const float* pb1=(const float*)d_in[8];
  const float* pw2=(const float*)d_in[9]; const float* pb2=(const float*)d_in[10];
  const float* cw=(const float*)d_in[11]; const float* cb=(const float*)d_in[12];
  const float* bw=(const float*)d_in[13]; const float* bb=(const float*)d_in[14];
  const float* kw=(const float*)d_in[15]; const float* kb=(const float*)d_in[16];
  float* out = (float*)d_out;
  char* ws = (char*)d_ws;

  short* x1hi = (short*)(ws + OFF_X1HI);
  short* x1lo = (short*)(ws + OFF_X1LO);
  short* x2hi = (short*)(ws + OFF_X2HI);
  short* x2lo = (short*)(ws + OFF_X2LO);
  short* fthi = (short*)(ws + OFF_FTHI);
  short* ftlo = (short*)(ws + OFF_FTLO);
  float* wT1  = (float*)(ws + OFF_WT1);
  short* a2h  = (short*)(ws + OFF_A2H);
  short* a2l  = (short*)(ws + OFF_A2L);
  short* a3h  = (short*)(ws + OFF_A3H);
  short* a3l  = (short*)(ws + OFF_A3L);
  short* ahh  = (short*)(ws + OFF_AHH);
  short* ahl  = (short*)(ws + OFF_AHL);
  short* ap1h = (short*)(ws + OFF_AP1H);
  short* ap1l = (short*)(ws + OFF_AP1L);
  float* wTp2 = (float*)(ws + OFF_WTP2);
  float* bh   = (float*)(ws + OFF_BH);
  float* hout = (float*)(ws + OFF_HOUT);
  float* p1   = (float*)(ws + OFF_P1);
  float* proto= (float*)(ws + OFF_PROTO);
  float* boxes= (float*)(ws + OFF_BOXES);
  float* scores=(float*)(ws + OFF_SCORES);
  int*   labels=(int*)  (ws + OFF_LABELS);
  int*   order =(int*)  (ws + OFF_ORDER);
  float* sb   = (float*)(ws + OFF_SB);
  unsigned long long* iou = (unsigned long long*)(ws + OFF_IOU);
  int*   keep = (int*)  (ws + OFF_KEEP);
  unsigned* maxb = (unsigned*)(ws + OFF_MAXB);

  // halo zero (all 3 layers) + maxb init
  halok3<<<dim3(583), 256, 0, stream>>>(x1hi, x1lo, x2hi, x2lo, fthi, ftlo, maxb);

  // all weight packing in one dispatch
  packall<<<dim3(4359), 256, 0, stream>>>(w1, wT1, w2, a2h, a2l, w3, a3h, a3l,
                                          pw1, ap1h, ap1l, cw, bw, kw, cb, bb, kb,
                                          ahh, ahl, bh, pw2, wTp2);

  // conv1: direct fp32 -> x1 C8HW8 padded hi/lo
  conv1k<<<dim3(64,4,BB), 256, 0, stream>>>(images, wT1, b1, x1hi, x1lo);

  // conv2: split-bf16, hi+lo LDS-staged half-rows (parity layout), S=2  [R1 config]
  cgemm_row<64,576,128,2,4,2,130,258,2,true,true,0,66,130>
      <<<dim3(128,1,BB), 256, 0, stream>>>(a2h, a2l, x1hi, x1lo, b2, nullptr, x2hi, x2lo);

  // conv3: split-bf16, hi+lo LDS-staged rows (parity layout), S=2  [R1 config]
  cgemm_row<128,1152,256,2,4,2,66,130,1,true,true,0,34,66>
      <<<dim3(32,2,BB), 256, 0, stream>>>(a3h, a3l, x2hi, x2lo, b3, nullptr, fthi, ftlo);

  // heads (R1 config) + fused decode
  headsdec<<<dim3(32,1,BB), 256, 0, stream>>>(ahh, ahl, fthi, ftlo, bh, hout,
                                              boxes, scores, labels, maxb);

  // pw1 (mask path): plain bf16, hi-B LDS-staged rows  [R1 config]
  cgemm_row<256,2304,256,2,4,1,34,66,1,false,false,2,1,1>
      <<<dim3(32,2,BB), 256, 0, stream>>>(ap1h, ap1l, fthi, fthi, pb1, p1, nullptr, nullptr);

  pw2k2<<<dim3(8,BB), 256, 0, stream>>>(p1, wTp2, pb2, proto);

  // NMS chain
  sortk<<<dim3(BB), 1024, 0, stream>>>(scores, boxes, labels, maxb, order, sb);
  ioumask<<<dim3(256,BB), 256, 0, stream>>>(sb, iou);
  nmsgather<<<dim3(BB), 64, 0, stream>>>(iou, order, boxes, scores, labels, keep, out);

  // fused masks
  maskresize<<<dim3(TOPK_N,BB), 256, 0, stream>>>(keep, hout, proto, out);
}

// Round 5
// 953.406 us; speedup vs baseline: 1.0418x; 1.0178x over previous
//
#include <hip/hip_runtime.h>
#include <hip/hip_bf16.h>
#include <math.h>

#define BB 8
#define NCLS 21
#define NANCH 2048
#define TOPK_N 100

// ---------------- workspace layout (bytes) ----------------
static const size_t OFF_X1HI = 0;           // 8*8*130*258*8*2 = 34,344,960
static const size_t OFF_X1LO = 34344960;
static const size_t OFF_X2HI = 68689920;    // 8*16*66*130*8*2
static const size_t OFF_X2LO = 86261760;
static const size_t OFF_FTHI = 103833600;   // 8*32*34*66*8*2
static const size_t OFF_FTLO = 113025024;
static const size_t OFF_WT1  = 122216448;
static const size_t OFF_A2H  = 122223616;
static const size_t OFF_A2L  = 122371072;
static const size_t OFF_A3H  = 122518528;
static const size_t OFF_A3L  = 123108352;
static const size_t OFF_AHH  = 123698176;
static const size_t OFF_AHL  = 123993088;
static const size_t OFF_AP1H = 124288000;
static const size_t OFF_AP1L = 125467648;
static const size_t OFF_WTP2 = 126647296;
static const size_t OFF_BH   = 126680064;
static const size_t OFF_HOUT = 126680576;
static const size_t OFF_P1   = 130874880;
static const size_t OFF_PROTO= 147652096;
static const size_t OFF_BOXES= 149749248;
static const size_t OFF_SCORES=150011392;
static const size_t OFF_LABELS=150076928;
static const size_t OFF_ORDER= 150142464;
static const size_t OFF_SB   = 150208000;
static const size_t OFF_IOU  = 150470144;
static const size_t OFF_KEEP = 154664448;
static const size_t OFF_MAXB = 154668032;

// ---------------- output layout (float elements) ----------------
static const size_t OUT_BOXES  = 0;
static const size_t OUT_SCORES = 3200;
static const size_t OUT_LABELS = 4000;
static const size_t OUT_MASKS  = 4800;
static const size_t OUT_VALID  = 104862400;

typedef __attribute__((ext_vector_type(8))) short bf16x8;
typedef __attribute__((ext_vector_type(4))) float f32x4;

__device__ __forceinline__ unsigned encf(float f){
  unsigned u = __float_as_uint(f);
  return (u & 0x80000000u) ? ~u : (u | 0x80000000u);
}
__device__ __forceinline__ float decf(unsigned u){
  unsigned b = (u & 0x80000000u) ? (u & 0x7fffffffu) : ~u;
  return __uint_as_float(b);
}
__device__ __forceinline__ short f2bf(float f){
  __hip_bfloat16 h = __float2bfloat16(f);
  return *(short*)&h;
}
__device__ __forceinline__ float bf2f(short h){
  return __uint_as_float(((unsigned)(unsigned short)h) << 16);
}

// ---------------- halo-only zero, all 3 layers in one kernel ----------------
__global__ void halok3(short* __restrict__ x1hi, short* __restrict__ x1lo,
                       short* __restrict__ x2hi, short* __restrict__ x2lo,
                       short* __restrict__ fthi, short* __restrict__ ftlo,
                       unsigned* __restrict__ maxb){
  int i = blockIdx.x*256 + threadIdx.x;
  if (i < BB) maxb[i] = 0u;
  short *hi, *lo; int Hp, Wp, cell, bg;
  if (i < 49408){
    hi=x1hi; lo=x1lo; Hp=130; Wp=258; cell = i % 772; bg = i / 772;
  } else if (i < 99072){
    int j = i - 49408; hi=x2hi; lo=x2lo; Hp=66; Wp=130; cell = j % 388; bg = j / 388;
  } else if (i < 149248){
    int j = i - 99072; hi=fthi; lo=ftlo; Hp=34; Wp=66; cell = j % 196; bg = j / 196;
  } else return;
  int y, x;
  if (cell < Wp)        { y = 0;      x = cell; }
  else if (cell < 2*Wp) { y = Hp-1;   x = cell - Wp; }
  else { int r = cell - 2*Wp; y = 1 + (r>>1); x = (r&1) ? (Wp-1) : 0; }
  size_t ad = (((size_t)bg*Hp + y)*Wp + x)*8;
  bf16x8 z = (bf16x8){0,0,0,0,0,0,0,0};
  *(bf16x8*)(hi + ad) = z;
  *(bf16x8*)(lo + ad) = z;
}

// ---------------- weight packers (device bodies + one dispatcher) ----------------
template<int CIN,int COUT,int KK>
__device__ __forceinline__ void packw_body(int i, const float* __restrict__ w,
                                           float* __restrict__ wT){
  if (i >= CIN*KK*COUT) return;
  int co = i % COUT; int r = i / COUT;
  int ci = r / KK,  k = r % KK;
  wT[i] = w[(co*CIN + ci)*KK + k];
}

template<int CIN,int COUT>
__device__ __forceinline__ void packA_body(int i, const float* __restrict__ w,
                                           short* __restrict__ Ahi, short* __restrict__ Alo){
  constexpr int K = CIN*9;
  constexpr int KS = K/32;
  if (i >= COUT*K) return;
  int sub  = i & 7;
  int lane = (i >> 3) & 63;
  int rest = i >> 9;
  int ks = rest % KS;
  int mt = rest / KS;
  int m = mt*16 + (lane & 15);
  int k = ks*32 + (lane >> 4)*8 + sub;
  int tap = k / CIN, ci = k - tap*CIN;
  float v = w[(m*CIN + ci)*9 + tap];
  short h = f2bf(v);
  Ahi[i] = h;
  Alo[i] = f2bf(v - bf2f(h));
}

__device__ __forceinline__ void packAh_body(int i,
    const float* __restrict__ cw, const float* __restrict__ bw,
    const float* __restrict__ kw, const float* __restrict__ cb,
    const float* __restrict__ bb, const float* __restrict__ kb,
    short* __restrict__ Ahi, short* __restrict__ Alo, float* __restrict__ bh){
  if (i < 64){
    float v = 0.f;
    if (i < 21) v = cb[i]; else if (i < 25) v = bb[i-21]; else if (i < 57) v = kb[i-25];
    bh[i] = v;
  }
  if (i >= 64*2304) return;
  constexpr int KS = 72;
  int sub  = i & 7;
  int lane = (i >> 3) & 63;
  int rest = i >> 9;
  int ks = rest % KS;
  int mt = rest / KS;
  int m = mt*16 + (lane & 15);
  int k = ks*32 + (lane >> 4)*8 + sub;
  int tap = k >> 8, ci = k & 255;
  float v = 0.f;
  if (m < 21)      v = cw[(m*256 + ci)*9 + tap];
  else if (m < 25) v = bw[((m-21)*256 + ci)*9 + tap];
  else if (m < 57) v = kw[((m-25)*256 + ci)*9 + tap];
  short h = f2bf(v);
  Ahi[i] = h;
  Alo[i] = f2bf(v - bf2f(h));
}

// block ranges: [0,288) packA<64,128>; [288,1440) packA<128,256>;
// [1440,3744) packA<256,256>; [3744,4320) packAh; [4320,4327) packw<3,64,9>;
// [4327,4359) packw<256,32,1>
__global__ void packall(const float* __restrict__ w1, float* __restrict__ wT1,
                        const float* __restrict__ w2, short* __restrict__ a2h, short* __restrict__ a2l,
                        const float* __restrict__ w3, short* __restrict__ a3h, short* __restrict__ a3l,
                        const float* __restrict__ pw1, short* __restrict__ ap1h, short* __restrict__ ap1l,
                        const float* __restrict__ cw, const float* __restrict__ bw,
                        const float* __restrict__ kw, const float* __restrict__ cb,
                        const float* __restrict__ bb, const float* __restrict__ kb,
                        short* __restrict__ ahh, short* __restrict__ ahl, float* __restrict__ bh,
                        const float* __restrict__ pw2, float* __restrict__ wTp2){
  int blk = blockIdx.x, t = threadIdx.x;
  if (blk < 288)        packA_body<64,128>(blk*256+t, w2, a2h, a2l);
  else if (blk < 1440)  packA_body<128,256>((blk-288)*256+t, w3, a3h, a3l);
  else if (blk < 3744)  packA_body<256,256>((blk-1440)*256+t, pw1, ap1h, ap1l);
  else if (blk < 4320)  packAh_body((blk-3744)*256+t, cw,bw,kw,cb,bb,kb, ahh,ahl,bh);
  else if (blk < 4327)  packw_body<3,64,9>((blk-4320)*256+t, w1, wT1);
  else                  packw_body<256,32,1>((blk-4327)*256+t, pw2, wTp2);
}

// ---------------- conv1: direct fp32, epilogue -> C8HW8 padded bf16 hi/lo ----------------
__global__ __launch_bounds__(256) void conv1k(const float* __restrict__ img,
    const float* __restrict__ wT, const float* __restrict__ bias,
    short* __restrict__ x1hi, short* __restrict__ x1lo){
  const int b   = blockIdx.z;
  const int co0 = blockIdx.y * 16;
  const int g   = blockIdx.x*256 + threadIdx.x;
  const int y  = g >> 7;
  const int x0 = (g & 127) << 1;

  float acc[16][2];
#pragma unroll
  for (int c=0;c<16;c++){
    float bv = bias[co0+c];
    acc[c][0] = bv; acc[c][1] = bv;
  }
  int   off[3][5];
  float msk[3][5];
#pragma unroll
  for (int kh=0;kh<3;kh++){
    int iy = y*2 - 1 + kh;
    bool okr = (iy >= 0) && (iy < 256);
    int ro = okr ? iy*512 : 0;
#pragma unroll
    for (int t=0;t<5;t++){
      int col = x0*2 - 1 + t;
      bool ok = okr && (col >= 0) && (col < 512);
      off[kh][t] = ok ? (ro + col) : 0;
      msk[kh][t] = ok ? 1.f : 0.f;
    }
  }
  const float* inb = img + (size_t)b*3*256*512;
  for (int ci=0; ci<3; ci++){
    const float* inc = inb + (size_t)ci*256*512;
    float v[3][5];
#pragma unroll
    for (int kh=0;kh<3;kh++)
#pragma unroll
      for (int t=0;t<5;t++)
        v[kh][t] = inc[off[kh][t]] * msk[kh][t];
    const float* wp = wT + ci*9*64 + co0;
#pragma unroll
    for (int kh=0;kh<3;kh++)
#pragma unroll
    for (int kw=0;kw<3;kw++){
      const float* wq = wp + (kh*3+kw)*64;
#pragma unroll
      for (int c=0;c<16;c++){
        float wv = wq[c];
        acc[c][0] = fmaf(wv, v[kh][2*0+kw], acc[c][0]);
        acc[c][1] = fmaf(wv, v[kh][2*1+kw], acc[c][1]);
      }
    }
  }
#pragma unroll
  for (int s=0;s<2;s++){
    short hv[16] __attribute__((aligned(16)));
    short lv[16] __attribute__((aligned(16)));
#pragma unroll
    for (int c=0;c<16;c++){
      float r = fmaxf(acc[c][s], 0.f);
      short h = f2bf(r);
      hv[c] = h;
      lv[c] = f2bf(r - bf2f(h));
    }
#pragma unroll
    for (int g2=0; g2<2; g2++){
      size_t ad = (((size_t)(b*8 + (co0>>3) + g2)*130 + (y+1))*258 + (x0+s+1))*8;
      *(bf16x8*)(x1hi + ad) = *(bf16x8*)(hv + g2*8);
      *(bf16x8*)(x1lo + ad) = *(bf16x8*)(lv + g2*8);
    }
  }
}

// ---------------- cgemm_row: LDS-staged B rows ----------------
// STAGEREG: T14 async-STAGE split — issue global loads for dy+1 into registers
// BEFORE compute(dy) (latency hides under MFMA), ds_write AFTER the post-compute
// barrier. Same addresses/values/MFMA order -> bit-identical to STAGEREG=false.
template<int CIN,int K,int M,int MW,int NW,int S,int IPH,int IPW,int NXB,
         bool SPLIT,bool STAGELO,bool STAGEREG,int EMODE,int OPH,int OPW>
__global__ __launch_bounds__(NW*64) void cgemm_row(
    const short* __restrict__ Ahi, const short* __restrict__ Alo,
    const short* __restrict__ Bhi, const short* __restrict__ Blo,
    const float* __restrict__ bias, float* __restrict__ outf,
    short* __restrict__ outhi, short* __restrict__ outlo){
  static_assert(CIN % 32 == 0, "CIN must be multiple of 32");
  constexpr int NT = 64*32;
  constexpr int KS = K/32;
  constexpr int CG = CIN/8;
  constexpr int SW  = 64*S + 2;
  constexpr int SWP = (S==2) ? (SW/2 + 1) : SW;
  constexpr int PARS = (S==2) ? 2 : 1;
  constexpr int LOOFF = CG*PARS*SWP*8;
  constexpr int BUFS = (SPLIT && STAGELO) ? 2 : 1;
  constexpr int NTH = NW*64;
  constexpr int NLD = (CG*SW + NTH - 1)/NTH;
  __shared__ __align__(16) short sB[BUFS*LOOFF];

  const int b    = blockIdx.z;
  const int oy   = blockIdx.x / NXB;
  const int xb   = (blockIdx.x % NXB) * 64;
  const int wave = threadIdx.x >> 6;
  const int lane = threadIdx.x & 63;
  const int lm = lane & 15, lq = lane >> 4;
  const int m0 = (blockIdx.y * NW + wave) * (MW*16);
  const int tid = threadIdx.x;

  f32x4 acc[MW][4];
#pragma unroll
  for (int i=0;i<MW;i++)
#pragma unroll
    for (int j=0;j<4;j++) acc[i][j] = (f32x4){0.f,0.f,0.f,0.f};

  const short* Ah_l = Ahi + (size_t)lane*8;
  const short* Al_l = Alo + (size_t)lane*8;
  const int mt0 = m0 >> 4;
  const size_t plane = (size_t)IPH*IPW;
  const short* Bl0 = Blo + ((size_t)b*CG + lq)*plane*8;

  bf16x8 rh[STAGEREG ? NLD : 1];
  bf16x8 rl[(STAGEREG && SPLIT && STAGELO) ? NLD : 1];

  auto LOADS = [&](int iyv){
    const short* srch = Bhi + (((size_t)b*CG*IPH + iyv)*IPW + (size_t)(xb*S))*8;
#pragma unroll
    for (int t=0;t<NLD;t++){
      int c = tid + t*NTH;
      if (c < CG*SW){
        int g = c / SW, p = c - g*SW;
        rh[t] = *(const bf16x8*)(srch + ((size_t)g*plane + p)*8);
      }
    }
    if constexpr (SPLIT && STAGELO){
      const short* srcl = Blo + (((size_t)b*CG*IPH + iyv)*IPW + (size_t)(xb*S))*8;
#pragma unroll
      for (int t=0;t<NLD;t++){
        int c = tid + t*NTH;
        if (c < CG*SW){
          int g = c / SW, p = c - g*SW;
          rl[t] = *(const bf16x8*)(srcl + ((size_t)g*plane + p)*8);
        }
      }
    }
  };
  auto WRITES = [&](){
#pragma unroll
    for (int t=0;t<NLD;t++){
      int c = tid + t*NTH;
      if (c < CG*SW){
        int g = c / SW, p = c - g*SW;
        int dst = (S==2) ? ((g*2 + (p&1))*SWP + (p>>1)) : (g*SW + p);
        *(bf16x8*)(&sB[(size_t)dst*8]) = rh[t];
        if constexpr (SPLIT && STAGELO)
          *(bf16x8*)(&sB[LOOFF + (size_t)dst*8]) = rl[t];
      }
    }
  };

  if constexpr (STAGEREG){
    LOADS(oy*S);
    WRITES();
    __syncthreads();
  }

#pragma unroll 1
  for (int dy=0; dy<3; dy++){
    const int iy = oy*S + dy;
    if constexpr (STAGEREG){
      if (dy < 2) LOADS(oy*S + dy + 1);     // in flight during compute
    } else {
      __syncthreads();
      {
        const short* srch = Bhi + (((size_t)b*CG*IPH + iy)*IPW + (size_t)(xb*S))*8;
        for (int c = tid; c < CG*SW; c += NTH){
          int g = c / SW, p = c - g*SW;
          int dst = (S==2) ? ((g*2 + (p&1))*SWP + (p>>1)) : (g*SW + p);
          *(bf16x8*)(&sB[(size_t)dst*8]) =
            *(const bf16x8*)(srch + ((size_t)g*plane + p)*8);
        }
        if constexpr (SPLIT && STAGELO){
          const short* srcl = Blo + (((size_t)b*CG*IPH + iy)*IPW + (size_t)(xb*S))*8;
          for (int c = tid; c < CG*SW; c += NTH){
            int g = c / SW, p = c - g*SW;
            int dst = (S==2) ? ((g*2 + (p&1))*SWP + (p>>1)) : (g*SW + p);
            *(bf16x8*)(&sB[LOOFF + (size_t)dst*8]) =
              *(const bf16x8*)(srcl + ((size_t)g*plane + p)*8);
          }
        }
      }
      __syncthreads();
    }
#pragma unroll
    for (int dx=0; dx<3; dx++){
      const int tap = dy*3 + dx;
      const int ksb = tap*(CIN/32);
#pragma unroll
      for (int kc=0; kc<CIN; kc+=32){
        const int ks = ksb + (kc>>5);
        int ra[4];
#pragma unroll
        for (int j=0;j<4;j++){
          int pc = (j*16 + lm)*S + dx;
          ra[j] = (S==2) ? ((((kc>>3) + lq)*2 + (pc&1))*SWP + (pc>>1))
                         : (((kc>>3) + lq)*SW + pc);
        }
        bf16x8 ah[MW], bh_[4];
#pragma unroll
        for (int i=0;i<MW;i++)
          ah[i] = *(const bf16x8*)(Ah_l + ((size_t)(mt0+i)*KS + ks)*512);
#pragma unroll
        for (int j=0;j<4;j++)
          bh_[j] = *(const bf16x8*)(&sB[(size_t)ra[j]*8]);
        if constexpr (SPLIT){
          bf16x8 al[MW], bl_[4];
#pragma unroll
          for (int i=0;i<MW;i++)
            al[i] = *(const bf16x8*)(Al_l + ((size_t)(mt0+i)*KS + ks)*512);
          if constexpr (STAGELO){
#pragma unroll
            for (int j=0;j<4;j++)
              bl_[j] = *(const bf16x8*)(&sB[LOOFF + (size_t)ra[j]*8]);
          } else {
#pragma unroll
            for (int j=0;j<4;j++){
              size_t pix = (size_t)iy*IPW + (size_t)((xb + j*16 + lm)*S + dx);
              bl_[j] = *(const bf16x8*)(Bl0 + ((size_t)(kc>>3)*plane + pix)*8);
            }
          }
#pragma unroll
          for (int j=0;j<4;j++)
#pragma unroll
            for (int i=0;i<MW;i++)
              acc[i][j] = __builtin_amdgcn_mfma_f32_16x16x32_bf16(ah[i], bh_[j], acc[i][j], 0,0,0);
#pragma unroll
          for (int j=0;j<4;j++)
#pragma unroll
            for (int i=0;i<MW;i++)
              acc[i][j] = __builtin_amdgcn_mfma_f32_16x16x32_bf16(ah[i], bl_[j], acc[i][j], 0,0,0);
#pragma unroll
          for (int j=0;j<4;j++)
#pragma unroll
            for (int i=0;i<MW;i++)
              acc[i][j] = __builtin_amdgcn_mfma_f32_16x16x32_bf16(al[i], bh_[j], acc[i][j], 0,0,0);
        } else {
#pragma unroll
          for (int j=0;j<4;j++)
#pragma unroll
            for (int i=0;i<MW;i++)
              acc[i][j] = __builtin_amdgcn_mfma_f32_16x16x32_bf16(ah[i], bh_[j], acc[i][j], 0,0,0);
        }
      }
    }
    if constexpr (STAGEREG){
      if (dy < 2){
        __syncthreads();      // all reads of sB done
        WRITES();             // data already arrived (hidden under compute)
        __syncthreads();      // staged for next dy
      }
    }
  }

#pragma unroll
  for (int i=0;i<MW;i++){
#pragma unroll
    for (int r=0;r<4;r++){
      const int m = m0 + i*16 + lq*4 + r;
      const float bv = bias[m];
      if constexpr (EMODE == 0){
#pragma unroll
        for (int j=0;j<4;j++){
          const int ox = xb + j*16 + lm;
          float v = fmaxf(acc[i][j][r] + bv, 0.f);
          short h = f2bf(v);
          short l = f2bf(v - bf2f(h));
          size_t ad = ((((size_t)(b*(M/8) + (m>>3))*OPH + (oy+1))*OPW + (ox+1)))*8 + (m&7);
          outhi[ad] = h;
          outlo[ad] = l;
        }
      } else {
        float* cp = outf + ((size_t)b*M + m)*NT + oy*64 + lm;
#pragma unroll
        for (int j=0;j<4;j++){
          float v = acc[i][j][r] + bv;
          if constexpr (EMODE == 2) v = fmaxf(v, 0.f);
          cp[j*16] = v;
        }
      }
    }
  }
}

// ---------------- heads GEMM + fused decode (T14 reg-staged pipeline) ----------------
__global__ __launch_bounds__(256) void headsdec(
    const short* __restrict__ Ahi, const short* __restrict__ Alo,
    const short* __restrict__ Bhi, const short* __restrict__ Blo,
    const float* __restrict__ bias, float* __restrict__ hout,
    float* __restrict__ boxes, float* __restrict__ scores,
    int* __restrict__ labels, unsigned* __restrict__ maxb){
  constexpr int KS = 72;           // 2304/32
  constexpr int CG = 32;           // 256/8
  constexpr int SW = 66;
  constexpr int IPH = 34, IPW = 66;
  constexpr int LOOFF = CG*SW*8;   // 16896 shorts per buffer
  constexpr int NLD = (CG*SW + 255)/256;   // 9
  __shared__ __align__(16) short sB[2*LOOFF];   // 67.5 KB; reused for decode stage

  const int b  = blockIdx.z;
  const int oy = blockIdx.x;
  const int wave = threadIdx.x >> 6;
  const int lane = threadIdx.x & 63;
  const int lm = lane & 15, lq = lane >> 4;
  const int tid = threadIdx.x;

  f32x4 acc[4];
#pragma unroll
  for (int j=0;j<4;j++) acc[j] = (f32x4){0.f,0.f,0.f,0.f};

  const short* Ah_l = Ahi + (size_t)lane*8;
  const short* Al_l = Alo + (size_t)lane*8;
  const size_t plane = (size_t)IPH*IPW;

  bf16x8 rh[NLD], rl[NLD];
  auto HLOADS = [&](int iyv){
    const short* srch = Bhi + ((size_t)b*CG*IPH + iyv)*IPW*8;
    const short* srcl = Blo + ((size_t)b*CG*IPH + iyv)*IPW*8;
#pragma unroll
    for (int t=0;t<NLD;t++){
      int c = tid + t*256;
      if (c < CG*SW){
        int g = c / SW, p = c - g*SW;
        rh[t] = *(const bf16x8*)(srch + ((size_t)g*plane + p)*8);
        rl[t] = *(const bf16x8*)(srcl + ((size_t)g*plane + p)*8);
      }
    }
  };
  auto HWRITES = [&](){
#pragma unroll
    for (int t=0;t<NLD;t++){
      int c = tid + t*256;
      if (c < CG*SW){
        *(bf16x8*)(&sB[(size_t)c*8]) = rh[t];
        *(bf16x8*)(&sB[LOOFF + (size_t)c*8]) = rl[t];
      }
    }
  };

  HLOADS(oy);
  HWRITES();
  __syncthreads();

#pragma unroll 1
  for (int dy=0; dy<3; dy++){
    if (dy < 2) HLOADS(oy + dy + 1);
#pragma unroll
    for (int dx=0; dx<3; dx++){
      const int tap = dy*3 + dx;
      const int ksb = tap*8;
#pragma unroll
      for (int kc=0; kc<256; kc+=32){
        const int ks = ksb + (kc>>5);
        int ra[4];
#pragma unroll
        for (int j=0;j<4;j++) ra[j] = ((kc>>3) + lq)*SW + (j*16 + lm) + dx;
        bf16x8 bh_[4], bl_[4];
#pragma unroll
        for (int j=0;j<4;j++){
          bh_[j] = *(const bf16x8*)(&sB[(size_t)ra[j]*8]);
          bl_[j] = *(const bf16x8*)(&sB[LOOFF + (size_t)ra[j]*8]);
        }
        bf16x8 ah = *(const bf16x8*)(Ah_l + ((size_t)wave*KS + ks)*512);
        bf16x8 al = *(const bf16x8*)(Al_l + ((size_t)wave*KS + ks)*512);
#pragma unroll
        for (int j=0;j<4;j++)
          acc[j] = __builtin_amdgcn_mfma_f32_16x16x32_bf16(ah, bh_[j], acc[j], 0,0,0);
#pragma unroll
        for (int j=0;j<4;j++)
          acc[j] = __builtin_amdgcn_mfma_f32_16x16x32_bf16(ah, bl_[j], acc[j], 0,0,0);
#pragma unroll
        for (int j=0;j<4;j++)
          acc[j] = __builtin_amdgcn_mfma_f32_16x16x32_bf16(al, bh_[j], acc[j], 0,0,0);
      }
    }
    if (dy < 2){
      __syncthreads();
      HWRITES();
      __syncthreads();
    }
  }

  // epilogue: hout write + LDS f32 stage [64 rows][68 stride]
  __syncthreads();                  // all k-loop LDS reads done before reuse
  float* sF = (float*)sB;
#pragma unroll
  for (int r=0;r<4;r++){
    const int m = wave*16 + lq*4 + r;
    const float bv = bias[m];
    float* cp = hout + ((size_t)b*64 + m)*NANCH + oy*64 + lm;
#pragma unroll
    for (int j=0;j<4;j++){
      float v = acc[j][r] + bv;
      cp[j*16] = v;
      sF[m*68 + j*16 + lm] = v;
    }
  }
  __syncthreads();

  // decode (exact decodek sequence) for anchors n = oy*64 + 0..63
  if (tid < 64){
    const int n = oy*64 + tid;
    float l[NCLS];
    float M = -1e30f;
#pragma unroll
    for (int c=0;c<NCLS;c++){ l[c] = sF[c*68 + tid]; M = fmaxf(M, l[c]); }
    float denom = 0.f;
#pragma unroll
    for (int c=0;c<NCLS;c++) denom += expf(l[c]-M);
    float best = -1.f; int bi = 0;
#pragma unroll
    for (int c=0;c<NCLS-1;c++){
      float e = expf(l[c]-M);
      if (e > best){ best = e; bi = c; }
    }
    scores[(size_t)b*NANCH + n] = best/denom;
    labels[(size_t)b*NANCH + n] = bi;

    float dxv = sF[21*68 + tid], dyv = sF[22*68 + tid];
    float dwv = sF[23*68 + tid], dhv = sF[24*68 + tid];
    const int yy = n >> 6, xx = n & 63;
    float cx = (xx+0.5f)*8.f, cy = (yy+0.5f)*8.f;
    float px = cx + dxv*32.f, py = cy + dyv*32.f;
    float pw = 32.f*expf(dwv), ph = 32.f*expf(dhv);
    float x1 = px - 0.5f*pw, y1 = py - 0.5f*ph;
    float x2 = px + 0.5f*pw, y2 = py + 0.5f*ph;
    float* bo = boxes + ((size_t)b*NANCH + n)*4;
    bo[0]=x1; bo[1]=y1; bo[2]=x2; bo[3]=y2;
    float mx = fmaxf(fmaxf(x1,y1), fmaxf(x2,y2));
#pragma unroll
    for (int off=32; off>0; off>>=1) mx = fmaxf(mx, __shfl_down(mx, off));
    if (tid == 0) atomicMax(maxb + b, encf(mx));
  }
}

// ---------------- 1x1 conv 256->32 (fp32, mask path) ----------------
__global__ __launch_bounds__(256) void pw2k2(const float* __restrict__ p1,
    const float* __restrict__ wT, const float* __restrict__ bias,
    float* __restrict__ proto){
  const int b  = blockIdx.y;
  const int sp = blockIdx.x*256 + threadIdx.x;
  float acc[32];
#pragma unroll
  for (int c=0;c<32;c++) acc[c] = bias[c];
  const float* pb = p1 + (size_t)b*256*NANCH + sp;
  for (int ci=0;ci<256;ci++){
    float v = pb[(size_t)ci*NANCH];
    const float* wq = wT + ci*32;
#pragma unroll
    for (int c=0;c<32;c++) acc[c] = fmaf(v, wq[c], acc[c]);
  }
#pragma unroll
  for (int c=0;c<32;c++)
    proto[((size_t)b*32 + c)*NANCH + sp] = acc[c];
}

// ---------------- stable descending sort (bitonic) ----------------
__global__ void __launch_bounds__(1024) sortk(const float* __restrict__ scores,
                     const float* __restrict__ boxes, const int* __restrict__ labels,
                     const unsigned* __restrict__ maxb,
                     int* __restrict__ order, float* __restrict__ sb){
  __shared__ float sc[NANCH];
  __shared__ int   id[NANCH];
  const int b = blockIdx.x, t = threadIdx.x;
  for (int i=t;i<NANCH;i+=1024){ sc[i]=scores[(size_t)b*NANCH+i]; id[i]=i; }
  __syncthreads();
  for (int k=2;k<=NANCH;k<<=1){
    for (int j=k>>1;j>0;j>>=1){
      for (int i=t;i<NANCH;i+=1024){
        int ixj = i ^ j;
        if (ixj > i){
          float sa=sc[i], sb_=sc[ixj]; int ia=id[i], ib=id[ixj];
          bool dir = ((i & k) == 0);
          bool before_ba = (sb_ > sa) || (sb_ == sa && ib < ia);
          if (before_ba == dir){ sc[i]=sb_; sc[ixj]=sa; id[i]=ib; id[ixj]=ia; }
        }
      }
      __syncthreads();
    }
  }
  float mboff = decf(maxb[b]) + 1.0f;
  for (int r=t;r<NANCH;r+=1024){
    int o = id[r];
    order[(size_t)b*NANCH + r] = o;
    float off = (float)labels[(size_t)b*NANCH + o] * mboff;
    const float* bo = boxes + ((size_t)b*NANCH + o)*4;
    float* sp = sb + ((size_t)b*NANCH + r)*4;
    sp[0]=bo[0]+off; sp[1]=bo[1]+off; sp[2]=bo[2]+off; sp[3]=bo[3]+off;
  }
}

// ---------------- IoU>thr bitmask ----------------
__global__ void ioumask(const float* __restrict__ sb, unsigned long long* __restrict__ iou){
  const int b = blockIdx.y;
  const int gid = blockIdx.x*blockDim.x + threadIdx.x;
  const int i = gid >> 5, w = gid & 31;
  const float* base = sb + (size_t)b*NANCH*4;
  unsigned long long bits = 0ull;
  const int j0 = w << 6;
  if (j0 + 63 > i){
    float x1=base[i*4], y1=base[i*4+1], x2=base[i*4+2], y2=base[i*4+3];
    float ai = (x2-x1)*(y2-y1);
    for (int jj=0;jj<64;jj++){
      int j = j0 + jj;
      if (j > i){
        float bx1=base[j*4], by1=base[j*4+1], bx2=base[j*4+2], by2=base[j*4+3];
        float lx=fmaxf(x1,bx1), ly=fmaxf(y1,by1);
        float rx=fminf(x2,bx2), ry=fminf(y2,by2);
        float ww=fmaxf(rx-lx,0.f), hh=fmaxf(ry-ly,0.f);
        float inter = ww*hh;
        float aj = (bx2-bx1)*(by2-by1);
        float v = inter/(ai + aj - inter + 1e-9f);
        if (v > 0.5f) bits |= (1ull << jj);
      }
    }
  }
  iou[((size_t)b*NANCH + i)*32 + w] = bits;
}

// ---------------- greedy NMS skip-scan + gather (one wave per batch) ----------------
__global__ void nmsgather(const unsigned long long* __restrict__ iou,
                          const int* __restrict__ order,
                          const float* __restrict__ boxes, const float* __restrict__ scores,
                          const int* __restrict__ labels,
                          int* __restrict__ keep, float* __restrict__ out){
  const int b = blockIdx.x, lane = threadIdx.x;
  __shared__ int s_keep[TOPK_N];
  unsigned long long sup = 0ull;
  int k = 0, i = 0;
  while (k < TOPK_N){
    unsigned long long avail = (lane < 32) ? ~sup : 0ull;
    const int wi = i >> 6;
    if (lane < wi) avail = 0ull;
    else if (lane == wi) avail &= (~0ull) << (i & 63);
    unsigned long long ball = __ballot(avail != 0ull);
    if (!ball) break;
    int w0 = (int)__builtin_ctzll(ball);
    unsigned long long aw = __shfl(avail, w0);
    int b0 = (int)__builtin_ctzll(aw);
    i = (w0 << 6) + b0;
    int ov = order[(size_t)b*NANCH + i];
    if (lane == 0) s_keep[k] = ov;
    k++;
    unsigned long long row = (lane < 32) ? iou[((size_t)b*NANCH + i)*32 + lane] : 0ull;
    sup |= row;
    i++;
    if (i >= NANCH) break;
  }
  __syncthreads();
  for (int r = lane; r < TOPK_N; r += 64){
    int kv = (r < k) ? s_keep[r] : -1;
    keep[b*TOPK_N + r] = kv;
    float valid = (kv >= 0) ? 1.f : 0.f;
    int kc = (kv < 0) ? 0 : kv;
    const float* bo = boxes + ((size_t)b*NANCH + kc)*4;
#pragma unroll
    for (int c=0;c<4;c++) out[OUT_BOXES + ((size_t)b*TOPK_N + r)*4 + c] = bo[c]*valid;
    out[OUT_SCORES + b*TOPK_N + r] = scores[(size_t)b*NANCH + kc]*valid;
    out[OUT_LABELS + b*TOPK_N + r] = (kv >= 0) ? (float)labels[(size_t)b*NANCH + kc] : 0.f;
    out[OUT_VALID  + b*TOPK_N + r] = valid;
  }
}

// ---------------- fused mask logits + sigmoid + bilinear resize + threshold ----------------
__global__ __launch_bounds__(256) void maskresize(const int* __restrict__ keep,
    const float* __restrict__ hout, const float* __restrict__ proto,
    float* __restrict__ out){
  const int b = blockIdx.y, r = blockIdx.x;
  float* obase = out + OUT_MASKS + ((size_t)b*TOPK_N + r)*131072;
  int ki = keep[b*TOPK_N + r];
  if (ki < 0){
    float4 z = make_float4(0.f,0.f,0.f,0.f);
    for (int idx = threadIdx.x; idx < 32768; idx += 256)
      ((float4*)obase)[idx] = z;
    return;
  }
  __shared__ float cf[32];
  __shared__ float sm[NANCH];
  if (threadIdx.x < 32)
    cf[threadIdx.x] = hout[((size_t)b*64 + 25 + threadIdx.x)*NANCH + ki];
  __syncthreads();
  for (int s = threadIdx.x; s < NANCH; s += 256){
    float acc = 0.f;
#pragma unroll
    for (int p=0;p<32;p++) acc = fmaf(cf[p], proto[((size_t)b*32 + p)*NANCH + s], acc);
    sm[s] = 1.f/(1.f + expf(-acc));
  }
  __syncthreads();
  for (int pid = threadIdx.x; pid < 32768; pid += 256){
    const int y  = pid >> 7;
    const int x4 = (pid & 127) << 2;
    float sy = (y + 0.5f)*0.125f - 0.5f;
    sy = fminf(fmaxf(sy, 0.f), 31.f);
    int y0 = (int)floorf(sy);
    int y1 = min(y0+1, 31);
    float wy = sy - (float)y0;
    const float* r0 = sm + y0*64;
    const float* r1 = sm + y1*64;
    float res[4];
#pragma unroll
    for (int kk=0;kk<4;kk++){
      int x = x4 + kk;
      float sx = (x + 0.5f)*0.125f - 0.5f;
      sx = fminf(fmaxf(sx, 0.f), 63.f);
      int x0 = (int)floorf(sx);
      int x1 = min(x0+1, 63);
      float wx = sx - (float)x0;
      float t0 = r0[x0]*(1.f-wy) + r1[x0]*wy;
      float t1 = r0[x1]*(1.f-wy) + r1[x1]*wy;
      float v  = t0*(1.f-wx) + t1*wx;
      res[kk] = (v > 0.5f) ? 1.f : 0.f;
    }
    *(float4*)(obase + y*512 + x4) = make_float4(res[0], res[1], res[2], res[3]);
  }
}

extern "C" void kernel_launch(void* const* d_in, const int* in_sizes, int n_in,
                              void* d_out, int out_size, void* d_ws, size_t ws_size,
                              hipStream_t stream) {
  const float* images=(const float*)d_in[0];
  const float* w1=(const float*)d_in[1];  const float* b1=(const float*)d_in[2];
  const float* w2=(const float*)d_in[3];  const float* b2=(const float*)d_in[4];
  const float* w3=(const float*)d_in[5];  const float* b3=(const float*)d_in[6];
  const float* pw1=(const float*)d_in[7]; const float* pb1=(const float*)d_in[8];
  const float* pw2=(const float*)d_in[9]; const float* pb2=(const float*)d_in[10];
  const float* cw=(const float*)d_in[11]; const float* cb=(const float*)d_in[12];
  const float* bw=(const float*)d_in[13]; const float* bb=(const float*)d_in[14];
  const float* kw=(const float*)d_in[15]; const float* kb=(const float*)d_in[16];
  float* out = (float*)d_out;
  char* ws = (char*)d_ws;

  short* x1hi = (short*)(ws + OFF_X1HI);
  short* x1lo = (short*)(ws + OFF_X1LO);
  short* x2hi = (short*)(ws + OFF_X2HI);
  short* x2lo = (short*)(ws + OFF_X2LO);
  short* fthi = (short*)(ws + OFF_FTHI);
  short* ftlo = (short*)(ws + OFF_FTLO);
  float* wT1  = (float*)(ws + OFF_WT1);
  short* a2h  = (short*)(ws + OFF_A2H);
  short* a2l  = (short*)(ws + OFF_A2L);
  short* a3h  = (short*)(ws + OFF_A3H);
  short* a3l  = (short*)(ws + OFF_A3L);
  short* ahh  = (short*)(ws + OFF_AHH);
  short* ahl  = (short*)(ws + OFF_AHL);
  short* ap1h = (short*)(ws + OFF_AP1H);
  short* ap1l = (short*)(ws + OFF_AP1L);
  float* wTp2 = (float*)(ws + OFF_WTP2);
  float* bh   = (float*)(ws + OFF_BH);
  float* hout = (float*)(ws + OFF_HOUT);
  float* p1   = (float*)(ws + OFF_P1);
  float* proto= (float*)(ws + OFF_PROTO);
  float* boxes= (float*)(ws + OFF_BOXES);
  float* scores=(float*)(ws + OFF_SCORES);
  int*   labels=(int*)  (ws + OFF_LABELS);
  int*   order =(int*)  (ws + OFF_ORDER);
  float* sb   = (float*)(ws + OFF_SB);
  unsigned long long* iou = (unsigned long long*)(ws + OFF_IOU);
  int*   keep = (int*)  (ws + OFF_KEEP);
  unsigned* maxb = (unsigned*)(ws + OFF_MAXB);

  // halo zero (all 3 layers) + maxb init
  halok3<<<dim3(583), 256, 0, stream>>>(x1hi, x1lo, x2hi, x2lo, fthi, ftlo, maxb);

  // all weight packing in one dispatch
  packall<<<dim3(4359), 256, 0, stream>>>(w1, wT1, w2, a2h, a2l, w3, a3h, a3l,
                                          pw1, ap1h, ap1l, cw, bw, kw, cb, bb, kb,
                                          ahh, ahl, bh, pw2, wTp2);

  // conv1: direct fp32 -> x1 C8HW8 padded hi/lo
  conv1k<<<dim3(64,4,BB), 256, 0, stream>>>(images, wT1, b1, x1hi, x1lo);

  // conv2: split-bf16, LDS-staged (4 blocks/CU — cross-block overlap, no reg-stage)
  cgemm_row<64,576,128,2,4,2,130,258,2,true,true,false,0,66,130>
      <<<dim3(128,1,BB), 256, 0, stream>>>(a2h, a2l, x1hi, x1lo, b2, nullptr, x2hi, x2lo);

  // conv3: split-bf16, T14 reg-staged pipeline (2 blocks/CU, LDS-capped)
  cgemm_row<128,1152,256,2,4,2,66,130,1,true,true,true,0,34,66>
      <<<dim3(32,2,BB), 256, 0, stream>>>(a3h, a3l, x2hi, x2lo, b3, nullptr, fthi, ftlo);

  // heads + fused decode, T14 reg-staged pipeline (1 block/CU)
  headsdec<<<dim3(32,1,BB), 256, 0, stream>>>(ahh, ahl, fthi, ftlo, bh, hout,
                                              boxes, scores, labels, maxb);

  // pw1 (mask path): plain bf16, T14 reg-staged pipeline (2 blocks/CU)
  cgemm_row<256,2304,256,2,4,1,34,66,1,false,false,true,2,1,1>
      <<<dim3(32,2,BB), 256, 0, stream>>>(ap1h, ap1l, fthi, fthi, pb1, p1, nullptr, nullptr);

  pw2k2<<<dim3(8,BB), 256, 0, stream>>>(p1, wTp2, pb2, proto);

  // NMS chain
  sortk<<<dim3(BB), 1024, 0, stream>>>(scores, boxes, labels, maxb, order, sb);
  ioumask<<<dim3(256,BB), 256, 0, stream>>>(sb, iou);
  nmsgather<<<dim3(BB), 64, 0, stream>>>(iou, order, boxes, scores, labels, keep, out);

  // fused masks
  maskresize<<<dim3(TOPK_N,BB), 256, 0, stream>>>(keep, hout, proto, out);
}

// Round 6
// 889.402 us; speedup vs baseline: 1.1167x; 1.0720x over previous
//
#include <hip/hip_runtime.h>
#include <hip/hip_bf16.h>
#include <math.h>

#define BB 8
#define NCLS 21
#define NANCH 2048
#define TOPK_N 100

// ---------------- workspace layout (bytes) ----------------
static const size_t OFF_X1HI = 0;           // 8*8*130*258*8*2 = 34,344,960
static const size_t OFF_X1LO = 34344960;
static const size_t OFF_X2HI = 68689920;    // 8*16*66*130*8*2
static const size_t OFF_X2LO = 86261760;
static const size_t OFF_FTHI = 103833600;   // 8*32*34*66*8*2
static const size_t OFF_FTLO = 113025024;
static const size_t OFF_WT1  = 122216448;   // (unused now; layout kept)
static const size_t OFF_A2H  = 122223616;
static const size_t OFF_A2L  = 122371072;
static const size_t OFF_A3H  = 122518528;
static const size_t OFF_A3L  = 123108352;
static const size_t OFF_AHH  = 123698176;
static const size_t OFF_AHL  = 123993088;
static const size_t OFF_AP1H = 124288000;
static const size_t OFF_AP1L = 125467648;
static const size_t OFF_WTP2 = 126647296;
static const size_t OFF_BH   = 126680064;
static const size_t OFF_HOUT = 126680576;
static const size_t OFF_P1   = 130874880;
static const size_t OFF_PROTO= 147652096;
static const size_t OFF_BOXES= 149749248;
static const size_t OFF_SCORES=150011392;
static const size_t OFF_LABELS=150076928;
static const size_t OFF_ORDER= 150142464;
static const size_t OFF_SB   = 150208000;
static const size_t OFF_IOU  = 150470144;
static const size_t OFF_KEEP = 154664448;
static const size_t OFF_MAXB = 154668032;

// ---------------- output layout (float elements) ----------------
static const size_t OUT_BOXES  = 0;
static const size_t OUT_SCORES = 3200;
static const size_t OUT_LABELS = 4000;
static const size_t OUT_MASKS  = 4800;
static const size_t OUT_VALID  = 104862400;

typedef __attribute__((ext_vector_type(8))) short bf16x8;
typedef __attribute__((ext_vector_type(4))) float f32x4;

__device__ __forceinline__ unsigned encf(float f){
  unsigned u = __float_as_uint(f);
  return (u & 0x80000000u) ? ~u : (u | 0x80000000u);
}
__device__ __forceinline__ float decf(unsigned u){
  unsigned b = (u & 0x80000000u) ? (u & 0x7fffffffu) : ~u;
  return __uint_as_float(b);
}
__device__ __forceinline__ short f2bf(float f){
  __hip_bfloat16 h = __float2bfloat16(f);
  return *(short*)&h;
}
__device__ __forceinline__ float bf2f(short h){
  return __uint_as_float(((unsigned)(unsigned short)h) << 16);
}

// ---------------- pack device bodies ----------------
template<int CIN,int COUT,int KK>
__device__ __forceinline__ void packw_body(int i, const float* __restrict__ w,
                                           float* __restrict__ wT){
  if (i >= CIN*KK*COUT) return;
  int co = i % COUT; int r = i / COUT;
  int ci = r / KK,  k = r % KK;
  wT[i] = w[(co*CIN + ci)*KK + k];
}

template<int CIN,int COUT>
__device__ __forceinline__ void packA_body(int i, const float* __restrict__ w,
                                           short* __restrict__ Ahi, short* __restrict__ Alo){
  constexpr int K = CIN*9;
  constexpr int KS = K/32;
  if (i >= COUT*K) return;
  int sub  = i & 7;
  int lane = (i >> 3) & 63;
  int rest = i >> 9;
  int ks = rest % KS;
  int mt = rest / KS;
  int m = mt*16 + (lane & 15);
  int k = ks*32 + (lane >> 4)*8 + sub;
  int tap = k / CIN, ci = k - tap*CIN;
  float v = w[(m*CIN + ci)*9 + tap];
  short h = f2bf(v);
  Ahi[i] = h;
  Alo[i] = f2bf(v - bf2f(h));
}

__device__ __forceinline__ void packAh_body(int i,
    const float* __restrict__ cw, const float* __restrict__ bw,
    const float* __restrict__ kw, const float* __restrict__ cb,
    const float* __restrict__ bb, const float* __restrict__ kb,
    short* __restrict__ Ahi, short* __restrict__ Alo, float* __restrict__ bh){
  if (i < 64){
    float v = 0.f;
    if (i < 21) v = cb[i]; else if (i < 25) v = bb[i-21]; else if (i < 57) v = kb[i-25];
    bh[i] = v;
  }
  if (i >= 64*2304) return;
  constexpr int KS = 72;
  int sub  = i & 7;
  int lane = (i >> 3) & 63;
  int rest = i >> 9;
  int ks = rest % KS;
  int mt = rest / KS;
  int m = mt*16 + (lane & 15);
  int k = ks*32 + (lane >> 4)*8 + sub;
  int tap = k >> 8, ci = k & 255;
  float v = 0.f;
  if (m < 21)      v = cw[(m*256 + ci)*9 + tap];
  else if (m < 25) v = bw[((m-21)*256 + ci)*9 + tap];
  else if (m < 57) v = kw[((m-25)*256 + ci)*9 + tap];
  short h = f2bf(v);
  Ahi[i] = h;
  Alo[i] = f2bf(v - bf2f(h));
}

// ---------------- megaprep: halo-zero + all packing + conv1 in one dispatch ----------------
// block ranges: [0,583) halo; [583,4935) packs; [4935,6983) conv1 (self-transposes w1)
__global__ __launch_bounds__(256) void megaprep(
    const float* __restrict__ images, const float* __restrict__ w1, const float* __restrict__ b1,
    const float* __restrict__ w2, short* __restrict__ a2h, short* __restrict__ a2l,
    const float* __restrict__ w3, short* __restrict__ a3h, short* __restrict__ a3l,
    const float* __restrict__ pw1, short* __restrict__ ap1h, short* __restrict__ ap1l,
    const float* __restrict__ cw, const float* __restrict__ bw, const float* __restrict__ kw,
    const float* __restrict__ cb, const float* __restrict__ bb, const float* __restrict__ kb,
    short* __restrict__ ahh, short* __restrict__ ahl, float* __restrict__ bh,
    const float* __restrict__ pw2, float* __restrict__ wTp2,
    short* __restrict__ x1hi, short* __restrict__ x1lo,
    short* __restrict__ x2hi, short* __restrict__ x2lo,
    short* __restrict__ fthi, short* __restrict__ ftlo,
    unsigned* __restrict__ maxb){
  __shared__ float sw[27*64];
  const int blk = blockIdx.x, tid = threadIdx.x;

  if (blk < 583){
    // ---- halo zero role (identical to halok3) ----
    int i = blk*256 + tid;
    if (i < BB) maxb[i] = 0u;
    short *hi, *lo; int Hp, Wp, cell, bg;
    if (i < 49408){
      hi=x1hi; lo=x1lo; Hp=130; Wp=258; cell = i % 772; bg = i / 772;
    } else if (i < 99072){
      int j = i - 49408; hi=x2hi; lo=x2lo; Hp=66; Wp=130; cell = j % 388; bg = j / 388;
    } else if (i < 149248){
      int j = i - 99072; hi=fthi; lo=ftlo; Hp=34; Wp=66; cell = j % 196; bg = j / 196;
    } else return;
    int y, x;
    if (cell < Wp)        { y = 0;      x = cell; }
    else if (cell < 2*Wp) { y = Hp-1;   x = cell - Wp; }
    else { int r = cell - 2*Wp; y = 1 + (r>>1); x = (r&1) ? (Wp-1) : 0; }
    size_t ad = (((size_t)bg*Hp + y)*Wp + x)*8;
    bf16x8 z = (bf16x8){0,0,0,0,0,0,0,0};
    *(bf16x8*)(hi + ad) = z;
    *(bf16x8*)(lo + ad) = z;
    return;
  }
  if (blk < 4935){
    // ---- pack role ----
    int lb = blk - 583;
    if (lb < 288)        packA_body<64,128>(lb*256+tid, w2, a2h, a2l);
    else if (lb < 1440)  packA_body<128,256>((lb-288)*256+tid, w3, a3h, a3l);
    else if (lb < 3744)  packA_body<256,256>((lb-1440)*256+tid, pw1, ap1h, ap1l);
    else if (lb < 4320)  packAh_body((lb-3744)*256+tid, cw,bw,kw,cb,bb,kb, ahh,ahl,bh);
    else                 packw_body<256,32,1>((lb-4320)*256+tid, pw2, wTp2);
    return;
  }

  // ---- conv1 role: cblk in [0,2048), original grid (64,4,8) ----
  const int cblk = blk - 4935;
  const int bxc = cblk & 63;
  const int co0 = ((cblk >> 6) & 3) * 16;
  const int b   = cblk >> 8;
  // self-transpose w1 into LDS: sw[(ci*9+k)*64+co] = w1[co*27 + ci*9+k]
  for (int idx = tid; idx < 1728; idx += 256){
    int r = idx >> 6, co = idx & 63;
    sw[idx] = w1[co*27 + r];
  }
  __syncthreads();

  const int g  = bxc*256 + tid;
  const int y  = g >> 7;
  const int x0 = (g & 127) << 1;

  float acc[16][2];
#pragma unroll
  for (int c=0;c<16;c++){
    float bv = b1[co0+c];
    acc[c][0] = bv; acc[c][1] = bv;
  }
  int   off[3][5];
  float msk[3][5];
#pragma unroll
  for (int kh=0;kh<3;kh++){
    int iy = y*2 - 1 + kh;
    bool okr = (iy >= 0) && (iy < 256);
    int ro = okr ? iy*512 : 0;
#pragma unroll
    for (int t=0;t<5;t++){
      int col = x0*2 - 1 + t;
      bool ok = okr && (col >= 0) && (col < 512);
      off[kh][t] = ok ? (ro + col) : 0;
      msk[kh][t] = ok ? 1.f : 0.f;
    }
  }
  const float* inb = images + (size_t)b*3*256*512;
  for (int ci=0; ci<3; ci++){
    const float* inc = inb + (size_t)ci*256*512;
    float v[3][5];
#pragma unroll
    for (int kh=0;kh<3;kh++)
#pragma unroll
      for (int t=0;t<5;t++)
        v[kh][t] = inc[off[kh][t]] * msk[kh][t];
    const float* wp = sw + ci*9*64 + co0;
#pragma unroll
    for (int kh=0;kh<3;kh++)
#pragma unroll
    for (int kw2=0;kw2<3;kw2++){
      const float* wq = wp + (kh*3+kw2)*64;
#pragma unroll
      for (int c=0;c<16;c++){
        float wv = wq[c];
        acc[c][0] = fmaf(wv, v[kh][2*0+kw2], acc[c][0]);
        acc[c][1] = fmaf(wv, v[kh][2*1+kw2], acc[c][1]);
      }
    }
  }
#pragma unroll
  for (int s=0;s<2;s++){
    short hv[16] __attribute__((aligned(16)));
    short lv[16] __attribute__((aligned(16)));
#pragma unroll
    for (int c=0;c<16;c++){
      float r = fmaxf(acc[c][s], 0.f);
      short h = f2bf(r);
      hv[c] = h;
      lv[c] = f2bf(r - bf2f(h));
    }
#pragma unroll
    for (int g2=0; g2<2; g2++){
      size_t ad = (((size_t)(b*8 + (co0>>3) + g2)*130 + (y+1))*258 + (x0+s+1))*8;
      *(bf16x8*)(x1hi + ad) = *(bf16x8*)(hv + g2*8);
      *(bf16x8*)(x1lo + ad) = *(bf16x8*)(lv + g2*8);
    }
  }
}

// ---------------- cgemm_row body (T14 reg-staged option), shared-mem passed in ----------------
template<int CIN,int K,int M,int MW,int NW,int S,int IPH,int IPW,int NXB,
         bool SPLIT,bool STAGELO,bool STAGEREG,int EMODE,int OPH,int OPW>
__device__ __forceinline__ void cgemm_row_body(
    short* sB, int bxi, int byi, int bzi,
    const short* __restrict__ Ahi, const short* __restrict__ Alo,
    const short* __restrict__ Bhi, const short* __restrict__ Blo,
    const float* __restrict__ bias, float* __restrict__ outf,
    short* __restrict__ outhi, short* __restrict__ outlo){
  static_assert(CIN % 32 == 0, "CIN must be multiple of 32");
  constexpr int NT = 64*32;
  constexpr int KS = K/32;
  constexpr int CG = CIN/8;
  constexpr int SW  = 64*S + 2;
  constexpr int SWP = (S==2) ? (SW/2 + 1) : SW;
  constexpr int LOOFF = CG*((S==2)?2:1)*SWP*8;
  constexpr int NTH = NW*64;
  constexpr int NLD = (CG*SW + NTH - 1)/NTH;

  const int b    = bzi;
  const int oy   = bxi / NXB;
  const int xb   = (bxi % NXB) * 64;
  const int wave = threadIdx.x >> 6;
  const int lane = threadIdx.x & 63;
  const int lm = lane & 15, lq = lane >> 4;
  const int m0 = (byi * NW + wave) * (MW*16);
  const int tid = threadIdx.x;

  f32x4 acc[MW][4];
#pragma unroll
  for (int i=0;i<MW;i++)
#pragma unroll
    for (int j=0;j<4;j++) acc[i][j] = (f32x4){0.f,0.f,0.f,0.f};

  const short* Ah_l = Ahi + (size_t)lane*8;
  const short* Al_l = Alo + (size_t)lane*8;
  const int mt0 = m0 >> 4;
  const size_t plane = (size_t)IPH*IPW;
  const short* Bl0 = Blo + ((size_t)b*CG + lq)*plane*8;

  bf16x8 rh[STAGEREG ? NLD : 1];
  bf16x8 rl[(STAGEREG && SPLIT && STAGELO) ? NLD : 1];

  auto LOADS = [&](int iyv){
    const short* srch = Bhi + (((size_t)b*CG*IPH + iyv)*IPW + (size_t)(xb*S))*8;
#pragma unroll
    for (int t=0;t<NLD;t++){
      int c = tid + t*NTH;
      if (c < CG*SW){
        int g = c / SW, p = c - g*SW;
        rh[t] = *(const bf16x8*)(srch + ((size_t)g*plane + p)*8);
      }
    }
    if constexpr (SPLIT && STAGELO){
      const short* srcl = Blo + (((size_t)b*CG*IPH + iyv)*IPW + (size_t)(xb*S))*8;
#pragma unroll
      for (int t=0;t<NLD;t++){
        int c = tid + t*NTH;
        if (c < CG*SW){
          int g = c / SW, p = c - g*SW;
          rl[t] = *(const bf16x8*)(srcl + ((size_t)g*plane + p)*8);
        }
      }
    }
  };
  auto WRITES = [&](){
#pragma unroll
    for (int t=0;t<NLD;t++){
      int c = tid + t*NTH;
      if (c < CG*SW){
        int g = c / SW, p = c - g*SW;
        int dst = (S==2) ? ((g*2 + (p&1))*SWP + (p>>1)) : (g*SW + p);
        *(bf16x8*)(&sB[(size_t)dst*8]) = rh[t];
        if constexpr (SPLIT && STAGELO)
          *(bf16x8*)(&sB[LOOFF + (size_t)dst*8]) = rl[t];
      }
    }
  };

  if constexpr (STAGEREG){
    LOADS(oy*S);
    WRITES();
    __syncthreads();
  }

#pragma unroll 1
  for (int dy=0; dy<3; dy++){
    const int iy = oy*S + dy;
    if constexpr (STAGEREG){
      if (dy < 2) LOADS(oy*S + dy + 1);     // in flight during compute
    } else {
      __syncthreads();
      {
        const short* srch = Bhi + (((size_t)b*CG*IPH + iy)*IPW + (size_t)(xb*S))*8;
        for (int c = tid; c < CG*SW; c += NTH){
          int g = c / SW, p = c - g*SW;
          int dst = (S==2) ? ((g*2 + (p&1))*SWP + (p>>1)) : (g*SW + p);
          *(bf16x8*)(&sB[(size_t)dst*8]) =
            *(const bf16x8*)(srch + ((size_t)g*plane + p)*8);
        }
        if constexpr (SPLIT && STAGELO){
          const short* srcl = Blo + (((size_t)b*CG*IPH + iy)*IPW + (size_t)(xb*S))*8;
          for (int c = tid; c < CG*SW; c += NTH){
            int g = c / SW, p = c - g*SW;
            int dst = (S==2) ? ((g*2 + (p&1))*SWP + (p>>1)) : (g*SW + p);
            *(bf16x8*)(&sB[LOOFF + (size_t)dst*8]) =
              *(const bf16x8*)(srcl + ((size_t)g*plane + p)*8);
          }
        }
      }
      __syncthreads();
    }
#pragma unroll
    for (int dx=0; dx<3; dx++){
      const int tap = dy*3 + dx;
      const int ksb = tap*(CIN/32);
#pragma unroll
      for (int kc=0; kc<CIN; kc+=32){
        const int ks = ksb + (kc>>5);
        int ra[4];
#pragma unroll
        for (int j=0;j<4;j++){
          int pc = (j*16 + lm)*S + dx;
          ra[j] = (S==2) ? ((((kc>>3) + lq)*2 + (pc&1))*SWP + (pc>>1))
                         : (((kc>>3) + lq)*SW + pc);
        }
        bf16x8 ah[MW], bh_[4];
#pragma unroll
        for (int i=0;i<MW;i++)
          ah[i] = *(const bf16x8*)(Ah_l + ((size_t)(mt0+i)*KS + ks)*512);
#pragma unroll
        for (int j=0;j<4;j++)
          bh_[j] = *(const bf16x8*)(&sB[(size_t)ra[j]*8]);
        if constexpr (SPLIT){
          bf16x8 al[MW], bl_[4];
#pragma unroll
          for (int i=0;i<MW;i++)
            al[i] = *(const bf16x8*)(Al_l + ((size_t)(mt0+i)*KS + ks)*512);
          if constexpr (STAGELO){
#pragma unroll
            for (int j=0;j<4;j++)
              bl_[j] = *(const bf16x8*)(&sB[LOOFF + (size_t)ra[j]*8]);
          } else {
#pragma unroll
            for (int j=0;j<4;j++){
              size_t pix = (size_t)iy*IPW + (size_t)((xb + j*16 + lm)*S + dx);
              bl_[j] = *(const bf16x8*)(Bl0 + ((size_t)(kc>>3)*plane + pix)*8);
            }
          }
#pragma unroll
          for (int j=0;j<4;j++)
#pragma unroll
            for (int i=0;i<MW;i++)
              acc[i][j] = __builtin_amdgcn_mfma_f32_16x16x32_bf16(ah[i], bh_[j], acc[i][j], 0,0,0);
#pragma unroll
          for (int j=0;j<4;j++)
#pragma unroll
            for (int i=0;i<MW;i++)
              acc[i][j] = __builtin_amdgcn_mfma_f32_16x16x32_bf16(ah[i], bl_[j], acc[i][j], 0,0,0);
#pragma unroll
          for (int j=0;j<4;j++)
#pragma unroll
            for (int i=0;i<MW;i++)
              acc[i][j] = __builtin_amdgcn_mfma_f32_16x16x32_bf16(al[i], bh_[j], acc[i][j], 0,0,0);
        } else {
#pragma unroll
          for (int j=0;j<4;j++)
#pragma unroll
            for (int i=0;i<MW;i++)
              acc[i][j] = __builtin_amdgcn_mfma_f32_16x16x32_bf16(ah[i], bh_[j], acc[i][j], 0,0,0);
        }
      }
    }
    if constexpr (STAGEREG){
      if (dy < 2){
        __syncthreads();      // all reads of sB done
        WRITES();             // data already arrived (hidden under compute)
        __syncthreads();      // staged for next dy
      }
    }
  }

#pragma unroll
  for (int i=0;i<MW;i++){
#pragma unroll
    for (int r=0;r<4;r++){
      const int m = m0 + i*16 + lq*4 + r;
      const float bv = bias[m];
      if constexpr (EMODE == 0){
#pragma unroll
        for (int j=0;j<4;j++){
          const int ox = xb + j*16 + lm;
          float v = fmaxf(acc[i][j][r] + bv, 0.f);
          short h = f2bf(v);
          short l = f2bf(v - bf2f(h));
          size_t ad = ((((size_t)(b*(M/8) + (m>>3))*OPH + (oy+1))*OPW + (ox+1)))*8 + (m&7);
          outhi[ad] = h;
          outlo[ad] = l;
        }
      } else {
        float* cp = outf + ((size_t)b*M + m)*NT + oy*64 + lm;
#pragma unroll
        for (int j=0;j<4;j++){
          float v = acc[i][j][r] + bv;
          if constexpr (EMODE == 2) v = fmaxf(v, 0.f);
          cp[j*16] = v;
        }
      }
    }
  }
}

template<int CIN,int K,int M,int MW,int NW,int S,int IPH,int IPW,int NXB,
         bool SPLIT,bool STAGELO,bool STAGEREG,int EMODE,int OPH,int OPW>
__global__ __launch_bounds__(NW*64) void cgemm_row(
    const short* __restrict__ Ahi, const short* __restrict__ Alo,
    const short* __restrict__ Bhi, const short* __restrict__ Blo,
    const float* __restrict__ bias, float* __restrict__ outf,
    short* __restrict__ outhi, short* __restrict__ outlo){
  constexpr int CG = CIN/8;
  constexpr int SW  = 64*S + 2;
  constexpr int SWP = (S==2) ? (SW/2 + 1) : SW;
  constexpr int LOOFF = CG*((S==2)?2:1)*SWP*8;
  constexpr int BUFS = (SPLIT && STAGELO) ? 2 : 1;
  __shared__ __align__(16) short sB[BUFS*LOOFF];
  cgemm_row_body<CIN,K,M,MW,NW,S,IPH,IPW,NXB,SPLIT,STAGELO,STAGEREG,EMODE,OPH,OPW>(
      sB, blockIdx.x, blockIdx.y, blockIdx.z,
      Ahi, Alo, Bhi, Blo, bias, outf, outhi, outlo);
}

// ---------------- headsdec body (T14 reg-staged + fused decode) ----------------
__device__ __forceinline__ void headsdec_body(
    short* sB, int oy, int b,
    const short* __restrict__ Ahi, const short* __restrict__ Alo,
    const short* __restrict__ Bhi, const short* __restrict__ Blo,
    const float* __restrict__ bias, float* __restrict__ hout,
    float* __restrict__ boxes, float* __restrict__ scores,
    int* __restrict__ labels, unsigned* __restrict__ maxb){
  constexpr int KS = 72;           // 2304/32
  constexpr int CG = 32;           // 256/8
  constexpr int SW = 66;
  constexpr int IPH = 34, IPW = 66;
  constexpr int LOOFF = CG*SW*8;   // 16896 shorts per buffer
  constexpr int NLD = (CG*SW + 255)/256;   // 9

  const int wave = threadIdx.x >> 6;
  const int lane = threadIdx.x & 63;
  const int lm = lane & 15, lq = lane >> 4;
  const int tid = threadIdx.x;

  f32x4 acc[4];
#pragma unroll
  for (int j=0;j<4;j++) acc[j] = (f32x4){0.f,0.f,0.f,0.f};

  const short* Ah_l = Ahi + (size_t)lane*8;
  const short* Al_l = Alo + (size_t)lane*8;
  const size_t plane = (size_t)IPH*IPW;

  bf16x8 rh[NLD], rl[NLD];
  auto HLOADS = [&](int iyv){
    const short* srch = Bhi + ((size_t)b*CG*IPH + iyv)*IPW*8;
    const short* srcl = Blo + ((size_t)b*CG*IPH + iyv)*IPW*8;
#pragma unroll
    for (int t=0;t<NLD;t++){
      int c = tid + t*256;
      if (c < CG*SW){
        int g = c / SW, p = c - g*SW;
        rh[t] = *(const bf16x8*)(srch + ((size_t)g*plane + p)*8);
        rl[t] = *(const bf16x8*)(srcl + ((size_t)g*plane + p)*8);
      }
    }
  };
  auto HWRITES = [&](){
#pragma unroll
    for (int t=0;t<NLD;t++){
      int c = tid + t*256;
      if (c < CG*SW){
        *(bf16x8*)(&sB[(size_t)c*8]) = rh[t];
        *(bf16x8*)(&sB[LOOFF + (size_t)c*8]) = rl[t];
      }
    }
  };

  HLOADS(oy);
  HWRITES();
  __syncthreads();

#pragma unroll 1
  for (int dy=0; dy<3; dy++){
    if (dy < 2) HLOADS(oy + dy + 1);
#pragma unroll
    for (int dx=0; dx<3; dx++){
      const int tap = dy*3 + dx;
      const int ksb = tap*8;
#pragma unroll
      for (int kc=0; kc<256; kc+=32){
        const int ks = ksb + (kc>>5);
        int ra[4];
#pragma unroll
        for (int j=0;j<4;j++) ra[j] = ((kc>>3) + lq)*SW + (j*16 + lm) + dx;
        bf16x8 bh_[4], bl_[4];
#pragma unroll
        for (int j=0;j<4;j++){
          bh_[j] = *(const bf16x8*)(&sB[(size_t)ra[j]*8]);
          bl_[j] = *(const bf16x8*)(&sB[LOOFF + (size_t)ra[j]*8]);
        }
        bf16x8 ah = *(const bf16x8*)(Ah_l + ((size_t)wave*KS + ks)*512);
        bf16x8 al = *(const bf16x8*)(Al_l + ((size_t)wave*KS + ks)*512);
#pragma unroll
        for (int j=0;j<4;j++)
          acc[j] = __builtin_amdgcn_mfma_f32_16x16x32_bf16(ah, bh_[j], acc[j], 0,0,0);
#pragma unroll
        for (int j=0;j<4;j++)
          acc[j] = __builtin_amdgcn_mfma_f32_16x16x32_bf16(ah, bl_[j], acc[j], 0,0,0);
#pragma unroll
        for (int j=0;j<4;j++)
          acc[j] = __builtin_amdgcn_mfma_f32_16x16x32_bf16(al, bh_[j], acc[j], 0,0,0);
      }
    }
    if (dy < 2){
      __syncthreads();
      HWRITES();
      __syncthreads();
    }
  }

  // epilogue: hout write + LDS f32 stage [64 rows][68 stride]
  __syncthreads();                  // all k-loop LDS reads done before reuse
  float* sF = (float*)sB;
#pragma unroll
  for (int r=0;r<4;r++){
    const int m = wave*16 + lq*4 + r;
    const float bv = bias[m];
    float* cp = hout + ((size_t)b*64 + m)*NANCH + oy*64 + lm;
#pragma unroll
    for (int j=0;j<4;j++){
      float v = acc[j][r] + bv;
      cp[j*16] = v;
      sF[m*68 + j*16 + lm] = v;
    }
  }
  __syncthreads();

  // decode (exact decodek sequence) for anchors n = oy*64 + 0..63
  if (tid < 64){
    const int n = oy*64 + tid;
    float l[NCLS];
    float M = -1e30f;
#pragma unroll
    for (int c=0;c<NCLS;c++){ l[c] = sF[c*68 + tid]; M = fmaxf(M, l[c]); }
    float denom = 0.f;
#pragma unroll
    for (int c=0;c<NCLS;c++) denom += expf(l[c]-M);
    float best = -1.f; int bi = 0;
#pragma unroll
    for (int c=0;c<NCLS-1;c++){
      float e = expf(l[c]-M);
      if (e > best){ best = e; bi = c; }
    }
    scores[(size_t)b*NANCH + n] = best/denom;
    labels[(size_t)b*NANCH + n] = bi;

    float dxv = sF[21*68 + tid], dyv = sF[22*68 + tid];
    float dwv = sF[23*68 + tid], dhv = sF[24*68 + tid];
    const int yy = n >> 6, xx = n & 63;
    float cx = (xx+0.5f)*8.f, cy = (yy+0.5f)*8.f;
    float px = cx + dxv*32.f, py = cy + dyv*32.f;
    float pw = 32.f*expf(dwv), ph = 32.f*expf(dhv);
    float x1 = px - 0.5f*pw, y1 = py - 0.5f*ph;
    float x2 = px + 0.5f*pw, y2 = py + 0.5f*ph;
    float* bo = boxes + ((size_t)b*NANCH + n)*4;
    bo[0]=x1; bo[1]=y1; bo[2]=x2; bo[3]=y2;
    float mx = fmaxf(fmaxf(x1,y1), fmaxf(x2,y2));
#pragma unroll
    for (int off=32; off>0; off>>=1) mx = fmaxf(mx, __shfl_down(mx, off));
    if (tid == 0) atomicMax(maxb + b, encf(mx));
  }
}

// ---------------- heads + pw1 co-dispatch (separate blocks, identical per-role code) ----------------
// grid (96,1,BB): bx<32 -> headsdec(oy=bx); bx>=32 -> pw1 cgemm_row(oy=(bx-32)&31, my=(bx-32)>>5)
__global__ __launch_bounds__(256) void headpw1k(
    const short* __restrict__ ahh, const short* __restrict__ ahl,
    const short* __restrict__ ap1h,
    const short* __restrict__ fthi, const short* __restrict__ ftlo,
    const float* __restrict__ bh, const float* __restrict__ pb1,
    float* __restrict__ hout, float* __restrict__ p1,
    float* __restrict__ boxes, float* __restrict__ scores,
    int* __restrict__ labels, unsigned* __restrict__ maxb){
  __shared__ __align__(16) short smem[33792];   // 67,584 B (headsdec needs 2x16896)
  const int bx = blockIdx.x, b = blockIdx.z;
  if (bx < 32){
    headsdec_body(smem, bx, b, ahh, ahl, fthi, ftlo, bh, hout,
                  boxes, scores, labels, maxb);
  } else {
    const int lx = bx - 32;
    cgemm_row_body<256,2304,256,2,4,1,34,66,1,false,false,true,2,1,1>(
        smem, lx & 31, lx >> 5, b, ap1h, ap1h, fthi, fthi, pb1, p1, nullptr, nullptr);
  }
}

// ---------------- pw2 + sortk co-dispatch (1024 threads; disjoint CUs) ----------------
// grid (24): bx<16 -> pw2 (b=bx>>1, sp=(bx&1)*1024+t); bx>=16 -> sortk (b=bx-16)
__global__ void __launch_bounds__(1024) pw2sortk(
    const float* __restrict__ p1, const float* __restrict__ wT,
    const float* __restrict__ biasp, float* __restrict__ proto,
    const float* __restrict__ scores, const float* __restrict__ boxes,
    const int* __restrict__ labels, const unsigned* __restrict__ maxb,
    int* __restrict__ order, float* __restrict__ sb){
  __shared__ float sc[NANCH];
  __shared__ int   id[NANCH];
  const int bx = blockIdx.x, t = threadIdx.x;
  if (bx < 16){
    // ---- pw2 role (identical arithmetic to pw2k2, 1024-thread mapping) ----
    const int b  = bx >> 1;
    const int sp = (bx & 1)*1024 + t;
    float acc[32];
#pragma unroll
    for (int c=0;c<32;c++) acc[c] = biasp[c];
    const float* pb = p1 + (size_t)b*256*NANCH + sp;
    for (int ci=0;ci<256;ci++){
      float v = pb[(size_t)ci*NANCH];
      const float* wq = wT + ci*32;
#pragma unroll
      for (int c=0;c<32;c++) acc[c] = fmaf(v, wq[c], acc[c]);
    }
#pragma unroll
    for (int c=0;c<32;c++)
      proto[((size_t)b*32 + c)*NANCH + sp] = acc[c];
    return;
  }
  // ---- sortk role (identical to standalone) ----
  const int b = bx - 16;
  for (int i=t;i<NANCH;i+=1024){ sc[i]=scores[(size_t)b*NANCH+i]; id[i]=i; }
  __syncthreads();
  for (int k=2;k<=NANCH;k<<=1){
    for (int j=k>>1;j>0;j>>=1){
      for (int i=t;i<NANCH;i+=1024){
        int ixj = i ^ j;
        if (ixj > i){
          float sa=sc[i], sb_=sc[ixj]; int ia=id[i], ib=id[ixj];
          bool dir = ((i & k) == 0);
          bool before_ba = (sb_ > sa) || (sb_ == sa && ib < ia);
          if (before_ba == dir){ sc[i]=sb_; sc[ixj]=sa; id[i]=ib; id[ixj]=ia; }
        }
      }
      __syncthreads();
    }
  }
  float mboff = decf(maxb[b]) + 1.0f;
  for (int r=t;r<NANCH;r+=1024){
    int o = id[r];
    order[(size_t)b*NANCH + r] = o;
    float off = (float)labels[(size_t)b*NANCH + o] * mboff;
    const float* bo = boxes + ((size_t)b*NANCH + o)*4;
    float* sp = sb + ((size_t)b*NANCH + r)*4;
    sp[0]=bo[0]+off; sp[1]=bo[1]+off; sp[2]=bo[2]+off; sp[3]=bo[3]+off;
  }
}

// ---------------- IoU>thr bitmask ----------------
__global__ void ioumask(const float* __restrict__ sb, unsigned long long* __restrict__ iou){
  const int b = blockIdx.y;
  const int gid = blockIdx.x*blockDim.x + threadIdx.x;
  const int i = gid >> 5, w = gid & 31;
  const float* base = sb + (size_t)b*NANCH*4;
  unsigned long long bits = 0ull;
  const int j0 = w << 6;
  if (j0 + 63 > i){
    float x1=base[i*4], y1=base[i*4+1], x2=base[i*4+2], y2=base[i*4+3];
    float ai = (x2-x1)*(y2-y1);
    for (int jj=0;jj<64;jj++){
      int j = j0 + jj;
      if (j > i){
        float bx1=base[j*4], by1=base[j*4+1], bx2=base[j*4+2], by2=base[j*4+3];
        float lx=fmaxf(x1,bx1), ly=fmaxf(y1,by1);
        float rx=fminf(x2,bx2), ry=fminf(y2,by2);
        float ww=fmaxf(rx-lx,0.f), hh=fmaxf(ry-ly,0.f);
        float inter = ww*hh;
        float aj = (bx2-bx1)*(by2-by1);
        float v = inter/(ai + aj - inter + 1e-9f);
        if (v > 0.5f) bits |= (1ull << jj);
      }
    }
  }
  iou[((size_t)b*NANCH + i)*32 + w] = bits;
}

// ---------------- greedy NMS skip-scan + gather (one wave per batch) ----------------
__global__ void nmsgather(const unsigned long long* __restrict__ iou,
                          const int* __restrict__ order,
                          const float* __restrict__ boxes, const float* __restrict__ scores,
                          const int* __restrict__ labels,
                          int* __restrict__ keep, float* __restrict__ out){
  const int b = blockIdx.x, lane = threadIdx.x;
  __shared__ int s_keep[TOPK_N];
  unsigned long long sup = 0ull;
  int k = 0, i = 0;
  while (k < TOPK_N){
    unsigned long long avail = (lane < 32) ? ~sup : 0ull;
    const int wi = i >> 6;
    if (lane < wi) avail = 0ull;
    else if (lane == wi) avail &= (~0ull) << (i & 63);
    unsigned long long ball = __ballot(avail != 0ull);
    if (!ball) break;
    int w0 = (int)__builtin_ctzll(ball);
    unsigned long long aw = __shfl(avail, w0);
    int b0 = (int)__builtin_ctzll(aw);
    i = (w0 << 6) + b0;
    int ov = order[(size_t)b*NANCH + i];
    if (lane == 0) s_keep[k] = ov;
    k++;
    unsigned long long row = (lane < 32) ? iou[((size_t)b*NANCH + i)*32 + lane] : 0ull;
    sup |= row;
    i++;
    if (i >= NANCH) break;
  }
  __syncthreads();
  for (int r = lane; r < TOPK_N; r += 64){
    int kv = (r < k) ? s_keep[r] : -1;
    keep[b*TOPK_N + r] = kv;
    float valid = (kv >= 0) ? 1.f : 0.f;
    int kc = (kv < 0) ? 0 : kv;
    const float* bo = boxes + ((size_t)b*NANCH + kc)*4;
#pragma unroll
    for (int c=0;c<4;c++) out[OUT_BOXES + ((size_t)b*TOPK_N + r)*4 + c] = bo[c]*valid;
    out[OUT_SCORES + b*TOPK_N + r] = scores[(size_t)b*NANCH + kc]*valid;
    out[OUT_LABELS + b*TOPK_N + r] = (kv >= 0) ? (float)labels[(size_t)b*NANCH + kc] : 0.f;
    out[OUT_VALID  + b*TOPK_N + r] = valid;
  }
}

// ---------------- fused mask logits + sigmoid + bilinear resize + threshold ----------------
__global__ __launch_bounds__(256) void maskresize(const int* __restrict__ keep,
    const float* __restrict__ hout, const float* __restrict__ proto,
    float* __restrict__ out){
  const int b = blockIdx.y, r = blockIdx.x;
  float* obase = out + OUT_MASKS + ((size_t)b*TOPK_N + r)*131072;
  int ki = keep[b*TOPK_N + r];
  if (ki < 0){
    float4 z = make_float4(0.f,0.f,0.f,0.f);
    for (int idx = threadIdx.x; idx < 32768; idx += 256)
      ((float4*)obase)[idx] = z;
    return;
  }
  __shared__ float cf[32];
  __shared__ float sm[NANCH];
  if (threadIdx.x < 32)
    cf[threadIdx.x] = hout[((size_t)b*64 + 25 + threadIdx.x)*NANCH + ki];
  __syncthreads();
  for (int s = threadIdx.x; s < NANCH; s += 256){
    float acc = 0.f;
#pragma unroll
    for (int p=0;p<32;p++) acc = fmaf(cf[p], proto[((size_t)b*32 + p)*NANCH + s], acc);
    sm[s] = 1.f/(1.f + expf(-acc));
  }
  __syncthreads();
  for (int pid = threadIdx.x; pid < 32768; pid += 256){
    const int y  = pid >> 7;
    const int x4 = (pid & 127) << 2;
    float sy = (y + 0.5f)*0.125f - 0.5f;
    sy = fminf(fmaxf(sy, 0.f), 31.f);
    int y0 = (int)floorf(sy);
    int y1 = min(y0+1, 31);
    float wy = sy - (float)y0;
    const float* r0 = sm + y0*64;
    const float* r1 = sm + y1*64;
    float res[4];
#pragma unroll
    for (int kk=0;kk<4;kk++){
      int x = x4 + kk;
      float sx = (x + 0.5f)*0.125f - 0.5f;
      sx = fminf(fmaxf(sx, 0.f), 63.f);
      int x0 = (int)floorf(sx);
      int x1 = min(x0+1, 63);
      float wx = sx - (float)x0;
      float t0 = r0[x0]*(1.f-wy) + r1[x0]*wy;
      float t1 = r0[x1]*(1.f-wy) + r1[x1]*wy;
      float v  = t0*(1.f-wx) + t1*wx;
      res[kk] = (v > 0.5f) ? 1.f : 0.f;
    }
    *(float4*)(obase + y*512 + x4) = make_float4(res[0], res[1], res[2], res[3]);
  }
}

extern "C" void kernel_launch(void* const* d_in, const int* in_sizes, int n_in,
                              void* d_out, int out_size, void* d_ws, size_t ws_size,
                              hipStream_t stream) {
  const float* images=(const float*)d_in[0];
  const float* w1=(const float*)d_in[1];  const float* b1=(const float*)d_in[2];
  const float* w2=(const float*)d_in[3];  const float* b2=(const float*)d_in[4];
  const float* w3=(const float*)d_in[5];  const float* b3=(const float*)d_in[6];
  const float* pw1=(const float*)d_in[7]; const float* pb1=(const float*)d_in[8];
  const float* pw2=(const float*)d_in[9]; const float* pb2=(const float*)d_in[10];
  const float* cw=(const float*)d_in[11]; const float* cb=(const float*)d_in[12];
  const float* bw=(const float*)d_in[13]; const float* bb=(const float*)d_in[14];
  const float* kw=(const float*)d_in[15]; const float* kb=(const float*)d_in[16];
  float* out = (float*)d_out;
  char* ws = (char*)d_ws;

  short* x1hi = (short*)(ws + OFF_X1HI);
  short* x1lo = (short*)(ws + OFF_X1LO);
  short* x2hi = (short*)(ws + OFF_X2HI);
  short* x2lo = (short*)(ws + OFF_X2LO);
  short* fthi = (short*)(ws + OFF_FTHI);
  short* ftlo = (short*)(ws + OFF_FTLO);
  short* a2h  = (short*)(ws + OFF_A2H);
  short* a2l  = (short*)(ws + OFF_A2L);
  short* a3h  = (short*)(ws + OFF_A3H);
  short* a3l  = (short*)(ws + OFF_A3L);
  short* ahh  = (short*)(ws + OFF_AHH);
  short* ahl  = (short*)(ws + OFF_AHL);
  short* ap1h = (short*)(ws + OFF_AP1H);
  short* ap1l = (short*)(ws + OFF_AP1L);
  float* wTp2 = (float*)(ws + OFF_WTP2);
  float* bh   = (float*)(ws + OFF_BH);
  float* hout = (float*)(ws + OFF_HOUT);
  float* p1   = (float*)(ws + OFF_P1);
  float* proto= (float*)(ws + OFF_PROTO);
  float* boxes= (float*)(ws + OFF_BOXES);
  float* scores=(float*)(ws + OFF_SCORES);
  int*   labels=(int*)  (ws + OFF_LABELS);
  int*   order =(int*)  (ws + OFF_ORDER);
  float* sb   = (float*)(ws + OFF_SB);
  unsigned long long* iou = (unsigned long long*)(ws + OFF_IOU);
  int*   keep = (int*)  (ws + OFF_KEEP);
  unsigned* maxb = (unsigned*)(ws + OFF_MAXB);

  // halo zero + all packing + conv1 in one dispatch
  megaprep<<<dim3(6983), 256, 0, stream>>>(
      images, w1, b1, w2, a2h, a2l, w3, a3h, a3l, pw1, ap1h, ap1l,
      cw, bw, kw, cb, bb, kb, ahh, ahl, bh, pw2, wTp2,
      x1hi, x1lo, x2hi, x2lo, fthi, ftlo, maxb);

  // conv2: split-bf16, now T14 reg-staged (4 blocks/CU)
  cgemm_row<64,576,128,2,4,2,130,258,2,true,true,true,0,66,130>
      <<<dim3(128,1,BB), 256, 0, stream>>>(a2h, a2l, x1hi, x1lo, b2, nullptr, x2hi, x2lo);

  // conv3: split-bf16, T14 reg-staged (2 blocks/CU)
  cgemm_row<128,1152,256,2,4,2,66,130,1,true,true,true,0,34,66>
      <<<dim3(32,2,BB), 256, 0, stream>>>(a3h, a3l, x2hi, x2lo, b3, nullptr, fthi, ftlo);

  // heads(+decode) and pw1 co-dispatched as separate blocks in one grid
  headpw1k<<<dim3(96,1,BB), 256, 0, stream>>>(ahh, ahl, ap1h, fthi, ftlo,
                                              bh, pb1, hout, p1,
                                              boxes, scores, labels, maxb);

  // pw2 and sortk co-dispatched (independent; disjoint CUs)
  pw2sortk<<<dim3(24), 1024, 0, stream>>>(p1, wTp2, pb2, proto,
                                          scores, boxes, labels, maxb, order, sb);

  ioumask<<<dim3(256,BB), 256, 0, stream>>>(sb, iou);
  nmsgather<<<dim3(BB), 64, 0, stream>>>(iou, order, boxes, scores, labels, keep, out);

  // fused masks
  maskresize<<<dim3(TOPK_N,BB), 256, 0, stream>>>(keep, hout, proto, out);
}

// Round 7
// 834.976 us; speedup vs baseline: 1.1895x; 1.0652x over previous
//
#include <hip/hip_runtime.h>
#include <hip/hip_bf16.h>
#include <math.h>

#define BB 8
#define NCLS 21
#define NANCH 2048
#define TOPK_N 100

// ---------------- workspace layout (bytes) ----------------
static const size_t OFF_X1HI = 0;           // 8*8*130*258*8*2 = 34,344,960
static const size_t OFF_X1LO = 34344960;
static const size_t OFF_X2HI = 68689920;    // 8*16*66*130*8*2
static const size_t OFF_X2LO = 86261760;
static const size_t OFF_FTHI = 103833600;   // 8*32*34*66*8*2
static const size_t OFF_FTLO = 113025024;
static const size_t OFF_A2H  = 122223616;
static const size_t OFF_A2L  = 122371072;
static const size_t OFF_A3H  = 122518528;
static const size_t OFF_A3L  = 123108352;
static const size_t OFF_AHH  = 123698176;
static const size_t OFF_AHL  = 123993088;
static const size_t OFF_AP1H = 124288000;
static const size_t OFF_AP1L = 125467648;
static const size_t OFF_WTP2 = 126647296;
static const size_t OFF_BH   = 126680064;
static const size_t OFF_HOUT = 126680576;
static const size_t OFF_P1   = 130874880;
static const size_t OFF_PROTO= 147652096;
static const size_t OFF_BOXES= 149749248;
static const size_t OFF_SCORES=150011392;
static const size_t OFF_LABELS=150076928;
static const size_t OFF_KEEP = 154664448;
static const size_t OFF_MAXB = 154668032;

// ---------------- output layout (float elements) ----------------
static const size_t OUT_BOXES  = 0;
static const size_t OUT_SCORES = 3200;
static const size_t OUT_LABELS = 4000;
static const size_t OUT_MASKS  = 4800;
static const size_t OUT_VALID  = 104862400;

typedef __attribute__((ext_vector_type(8))) short bf16x8;
typedef __attribute__((ext_vector_type(4))) float f32x4;

__device__ __forceinline__ unsigned encf(float f){
  unsigned u = __float_as_uint(f);
  return (u & 0x80000000u) ? ~u : (u | 0x80000000u);
}
__device__ __forceinline__ float decf(unsigned u){
  unsigned b = (u & 0x80000000u) ? (u & 0x7fffffffu) : ~u;
  return __uint_as_float(b);
}
__device__ __forceinline__ short f2bf(float f){
  __hip_bfloat16 h = __float2bfloat16(f);
  return *(short*)&h;
}
__device__ __forceinline__ float bf2f(short h){
  return __uint_as_float(((unsigned)(unsigned short)h) << 16);
}

// ---------------- pack device bodies ----------------
template<int CIN,int COUT,int KK>
__device__ __forceinline__ void packw_body(int i, const float* __restrict__ w,
                                           float* __restrict__ wT){
  if (i >= CIN*KK*COUT) return;
  int co = i % COUT; int r = i / COUT;
  int ci = r / KK,  k = r % KK;
  wT[i] = w[(co*CIN + ci)*KK + k];
}

template<int CIN,int COUT>
__device__ __forceinline__ void packA_body(int i, const float* __restrict__ w,
                                           short* __restrict__ Ahi, short* __restrict__ Alo){
  constexpr int K = CIN*9;
  constexpr int KS = K/32;
  if (i >= COUT*K) return;
  int sub  = i & 7;
  int lane = (i >> 3) & 63;
  int rest = i >> 9;
  int ks = rest % KS;
  int mt = rest / KS;
  int m = mt*16 + (lane & 15);
  int k = ks*32 + (lane >> 4)*8 + sub;
  int tap = k / CIN, ci = k - tap*CIN;
  float v = w[(m*CIN + ci)*9 + tap];
  short h = f2bf(v);
  Ahi[i] = h;
  Alo[i] = f2bf(v - bf2f(h));
}

__device__ __forceinline__ void packAh_body(int i,
    const float* __restrict__ cw, const float* __restrict__ bw,
    const float* __restrict__ kw, const float* __restrict__ cb,
    const float* __restrict__ bb, const float* __restrict__ kb,
    short* __restrict__ Ahi, short* __restrict__ Alo, float* __restrict__ bh){
  if (i < 64){
    float v = 0.f;
    if (i < 21) v = cb[i]; else if (i < 25) v = bb[i-21]; else if (i < 57) v = kb[i-25];
    bh[i] = v;
  }
  if (i >= 64*2304) return;
  constexpr int KS = 72;
  int sub  = i & 7;
  int lane = (i >> 3) & 63;
  int rest = i >> 9;
  int ks = rest % KS;
  int mt = rest / KS;
  int m = mt*16 + (lane & 15);
  int k = ks*32 + (lane >> 4)*8 + sub;
  int tap = k >> 8, ci = k & 255;
  float v = 0.f;
  if (m < 21)      v = cw[(m*256 + ci)*9 + tap];
  else if (m < 25) v = bw[((m-21)*256 + ci)*9 + tap];
  else if (m < 57) v = kw[((m-25)*256 + ci)*9 + tap];
  short h = f2bf(v);
  Ahi[i] = h;
  Alo[i] = f2bf(v - bf2f(h));
}

// ---------------- megaprep: halo-zero + all packing + conv1 in one dispatch ----------------
// block ranges: [0,583) halo; [583,4935) packs; [4935,6983) conv1 (self-transposes w1)
__global__ __launch_bounds__(256) void megaprep(
    const float* __restrict__ images, const float* __restrict__ w1, const float* __restrict__ b1,
    const float* __restrict__ w2, short* __restrict__ a2h, short* __restrict__ a2l,
    const float* __restrict__ w3, short* __restrict__ a3h, short* __restrict__ a3l,
    const float* __restrict__ pw1, short* __restrict__ ap1h, short* __restrict__ ap1l,
    const float* __restrict__ cw, const float* __restrict__ bw, const float* __restrict__ kw,
    const float* __restrict__ cb, const float* __restrict__ bb, const float* __restrict__ kb,
    short* __restrict__ ahh, short* __restrict__ ahl, float* __restrict__ bh,
    const float* __restrict__ pw2, float* __restrict__ wTp2,
    short* __restrict__ x1hi, short* __restrict__ x1lo,
    short* __restrict__ x2hi, short* __restrict__ x2lo,
    short* __restrict__ fthi, short* __restrict__ ftlo,
    unsigned* __restrict__ maxb){
  __shared__ float sw[27*64];
  const int blk = blockIdx.x, tid = threadIdx.x;

  if (blk < 583){
    int i = blk*256 + tid;
    if (i < BB) maxb[i] = 0u;
    short *hi, *lo; int Hp, Wp, cell, bg;
    if (i < 49408){
      hi=x1hi; lo=x1lo; Hp=130; Wp=258; cell = i % 772; bg = i / 772;
    } else if (i < 99072){
      int j = i - 49408; hi=x2hi; lo=x2lo; Hp=66; Wp=130; cell = j % 388; bg = j / 388;
    } else if (i < 149248){
      int j = i - 99072; hi=fthi; lo=ftlo; Hp=34; Wp=66; cell = j % 196; bg = j / 196;
    } else return;
    int y, x;
    if (cell < Wp)        { y = 0;      x = cell; }
    else if (cell < 2*Wp) { y = Hp-1;   x = cell - Wp; }
    else { int r = cell - 2*Wp; y = 1 + (r>>1); x = (r&1) ? (Wp-1) : 0; }
    size_t ad = (((size_t)bg*Hp + y)*Wp + x)*8;
    bf16x8 z = (bf16x8){0,0,0,0,0,0,0,0};
    *(bf16x8*)(hi + ad) = z;
    *(bf16x8*)(lo + ad) = z;
    return;
  }
  if (blk < 4935){
    int lb = blk - 583;
    if (lb < 288)        packA_body<64,128>(lb*256+tid, w2, a2h, a2l);
    else if (lb < 1440)  packA_body<128,256>((lb-288)*256+tid, w3, a3h, a3l);
    else if (lb < 3744)  packA_body<256,256>((lb-1440)*256+tid, pw1, ap1h, ap1l);
    else if (lb < 4320)  packAh_body((lb-3744)*256+tid, cw,bw,kw,cb,bb,kb, ahh,ahl,bh);
    else                 packw_body<256,32,1>((lb-4320)*256+tid, pw2, wTp2);
    return;
  }

  // ---- conv1 role ----
  const int cblk = blk - 4935;
  const int bxc = cblk & 63;
  const int co0 = ((cblk >> 6) & 3) * 16;
  const int b   = cblk >> 8;
  for (int idx = tid; idx < 1728; idx += 256){
    int r = idx >> 6, co = idx & 63;
    sw[idx] = w1[co*27 + r];
  }
  __syncthreads();

  const int g  = bxc*256 + tid;
  const int y  = g >> 7;
  const int x0 = (g & 127) << 1;

  float acc[16][2];
#pragma unroll
  for (int c=0;c<16;c++){
    float bv = b1[co0+c];
    acc[c][0] = bv; acc[c][1] = bv;
  }
  int   off[3][5];
  float msk[3][5];
#pragma unroll
  for (int kh=0;kh<3;kh++){
    int iy = y*2 - 1 + kh;
    bool okr = (iy >= 0) && (iy < 256);
    int ro = okr ? iy*512 : 0;
#pragma unroll
    for (int t=0;t<5;t++){
      int col = x0*2 - 1 + t;
      bool ok = okr && (col >= 0) && (col < 512);
      off[kh][t] = ok ? (ro + col) : 0;
      msk[kh][t] = ok ? 1.f : 0.f;
    }
  }
  const float* inb = images + (size_t)b*3*256*512;
  for (int ci=0; ci<3; ci++){
    const float* inc = inb + (size_t)ci*256*512;
    float v[3][5];
#pragma unroll
    for (int kh=0;kh<3;kh++)
#pragma unroll
      for (int t=0;t<5;t++)
        v[kh][t] = inc[off[kh][t]] * msk[kh][t];
    const float* wp = sw + ci*9*64 + co0;
#pragma unroll
    for (int kh=0;kh<3;kh++)
#pragma unroll
    for (int kw2=0;kw2<3;kw2++){
      const float* wq = wp + (kh*3+kw2)*64;
#pragma unroll
      for (int c=0;c<16;c++){
        float wv = wq[c];
        acc[c][0] = fmaf(wv, v[kh][2*0+kw2], acc[c][0]);
        acc[c][1] = fmaf(wv, v[kh][2*1+kw2], acc[c][1]);
      }
    }
  }
#pragma unroll
  for (int s=0;s<2;s++){
    short hv[16] __attribute__((aligned(16)));
    short lv[16] __attribute__((aligned(16)));
#pragma unroll
    for (int c=0;c<16;c++){
      float r = fmaxf(acc[c][s], 0.f);
      short h = f2bf(r);
      hv[c] = h;
      lv[c] = f2bf(r - bf2f(h));
    }
#pragma unroll
    for (int g2=0; g2<2; g2++){
      size_t ad = (((size_t)(b*8 + (co0>>3) + g2)*130 + (y+1))*258 + (x0+s+1))*8;
      *(bf16x8*)(x1hi + ad) = *(bf16x8*)(hv + g2*8);
      *(bf16x8*)(x1lo + ad) = *(bf16x8*)(lv + g2*8);
    }
  }
}

// ---------------- cgemm_row body (T14 reg-staged option), shared-mem passed in ----------------
template<int CIN,int K,int M,int MW,int NW,int S,int IPH,int IPW,int NXB,
         bool SPLIT,bool STAGELO,bool STAGEREG,int EMODE,int OPH,int OPW>
__device__ __forceinline__ void cgemm_row_body(
    short* sB, int bxi, int byi, int bzi,
    const short* __restrict__ Ahi, const short* __restrict__ Alo,
    const short* __restrict__ Bhi, const short* __restrict__ Blo,
    const float* __restrict__ bias, float* __restrict__ outf,
    short* __restrict__ outhi, short* __restrict__ outlo){
  static_assert(CIN % 32 == 0, "CIN must be multiple of 32");
  constexpr int NT = 64*32;
  constexpr int KS = K/32;
  constexpr int CG = CIN/8;
  constexpr int SW  = 64*S + 2;
  constexpr int SWP = (S==2) ? (SW/2 + 1) : SW;
  constexpr int LOOFF = CG*((S==2)?2:1)*SWP*8;
  constexpr int NTH = NW*64;
  constexpr int NLD = (CG*SW + NTH - 1)/NTH;

  const int b    = bzi;
  const int oy   = bxi / NXB;
  const int xb   = (bxi % NXB) * 64;
  const int wave = threadIdx.x >> 6;
  const int lane = threadIdx.x & 63;
  const int lm = lane & 15, lq = lane >> 4;
  const int m0 = (byi * NW + wave) * (MW*16);
  const int tid = threadIdx.x;

  f32x4 acc[MW][4];
#pragma unroll
  for (int i=0;i<MW;i++)
#pragma unroll
    for (int j=0;j<4;j++) acc[i][j] = (f32x4){0.f,0.f,0.f,0.f};

  const short* Ah_l = Ahi + (size_t)lane*8;
  const short* Al_l = Alo + (size_t)lane*8;
  const int mt0 = m0 >> 4;
  const size_t plane = (size_t)IPH*IPW;
  const short* Bl0 = Blo + ((size_t)b*CG + lq)*plane*8;

  bf16x8 rh[STAGEREG ? NLD : 1];
  bf16x8 rl[(STAGEREG && SPLIT && STAGELO) ? NLD : 1];

  auto LOADS = [&](int iyv){
    const short* srch = Bhi + (((size_t)b*CG*IPH + iyv)*IPW + (size_t)(xb*S))*8;
#pragma unroll
    for (int t=0;t<NLD;t++){
      int c = tid + t*NTH;
      if (c < CG*SW){
        int g = c / SW, p = c - g*SW;
        rh[t] = *(const bf16x8*)(srch + ((size_t)g*plane + p)*8);
      }
    }
    if constexpr (SPLIT && STAGELO){
      const short* srcl = Blo + (((size_t)b*CG*IPH + iyv)*IPW + (size_t)(xb*S))*8;
#pragma unroll
      for (int t=0;t<NLD;t++){
        int c = tid + t*NTH;
        if (c < CG*SW){
          int g = c / SW, p = c - g*SW;
          rl[t] = *(const bf16x8*)(srcl + ((size_t)g*plane + p)*8);
        }
      }
    }
  };
  auto WRITES = [&](){
#pragma unroll
    for (int t=0;t<NLD;t++){
      int c = tid + t*NTH;
      if (c < CG*SW){
        int g = c / SW, p = c - g*SW;
        int dst = (S==2) ? ((g*2 + (p&1))*SWP + (p>>1)) : (g*SW + p);
        *(bf16x8*)(&sB[(size_t)dst*8]) = rh[t];
        if constexpr (SPLIT && STAGELO)
          *(bf16x8*)(&sB[LOOFF + (size_t)dst*8]) = rl[t];
      }
    }
  };

  if constexpr (STAGEREG){
    LOADS(oy*S);
    WRITES();
    __syncthreads();
  }

#pragma unroll 1
  for (int dy=0; dy<3; dy++){
    const int iy = oy*S + dy;
    if constexpr (STAGEREG){
      if (dy < 2) LOADS(oy*S + dy + 1);     // in flight during compute
    } else {
      __syncthreads();
      {
        const short* srch = Bhi + (((size_t)b*CG*IPH + iy)*IPW + (size_t)(xb*S))*8;
        for (int c = tid; c < CG*SW; c += NTH){
          int g = c / SW, p = c - g*SW;
          int dst = (S==2) ? ((g*2 + (p&1))*SWP + (p>>1)) : (g*SW + p);
          *(bf16x8*)(&sB[(size_t)dst*8]) =
            *(const bf16x8*)(srch + ((size_t)g*plane + p)*8);
        }
        if constexpr (SPLIT && STAGELO){
          const short* srcl = Blo + (((size_t)b*CG*IPH + iy)*IPW + (size_t)(xb*S))*8;
          for (int c = tid; c < CG*SW; c += NTH){
            int g = c / SW, p = c - g*SW;
            int dst = (S==2) ? ((g*2 + (p&1))*SWP + (p>>1)) : (g*SW + p);
            *(bf16x8*)(&sB[LOOFF + (size_t)dst*8]) =
              *(const bf16x8*)(srcl + ((size_t)g*plane + p)*8);
          }
        }
      }
      __syncthreads();
    }
#pragma unroll
    for (int dx=0; dx<3; dx++){
      const int tap = dy*3 + dx;
      const int ksb = tap*(CIN/32);
#pragma unroll
      for (int kc=0; kc<CIN; kc+=32){
        const int ks = ksb + (kc>>5);
        int ra[4];
#pragma unroll
        for (int j=0;j<4;j++){
          int pc = (j*16 + lm)*S + dx;
          ra[j] = (S==2) ? ((((kc>>3) + lq)*2 + (pc&1))*SWP + (pc>>1))
                         : (((kc>>3) + lq)*SW + pc);
        }
        bf16x8 ah[MW], bh_[4];
#pragma unroll
        for (int i=0;i<MW;i++)
          ah[i] = *(const bf16x8*)(Ah_l + ((size_t)(mt0+i)*KS + ks)*512);
#pragma unroll
        for (int j=0;j<4;j++)
          bh_[j] = *(const bf16x8*)(&sB[(size_t)ra[j]*8]);
        if constexpr (SPLIT){
          bf16x8 al[MW], bl_[4];
#pragma unroll
          for (int i=0;i<MW;i++)
            al[i] = *(const bf16x8*)(Al_l + ((size_t)(mt0+i)*KS + ks)*512);
          if constexpr (STAGELO){
#pragma unroll
            for (int j=0;j<4;j++)
              bl_[j] = *(const bf16x8*)(&sB[LOOFF + (size_t)ra[j]*8]);
          } else {
#pragma unroll
            for (int j=0;j<4;j++){
              size_t pix = (size_t)iy*IPW + (size_t)((xb + j*16 + lm)*S + dx);
              bl_[j] = *(const bf16x8*)(Bl0 + ((size_t)(kc>>3)*plane + pix)*8);
            }
          }
#pragma unroll
          for (int j=0;j<4;j++)
#pragma unroll
            for (int i=0;i<MW;i++)
              acc[i][j] = __builtin_amdgcn_mfma_f32_16x16x32_bf16(ah[i], bh_[j], acc[i][j], 0,0,0);
#pragma unroll
          for (int j=0;j<4;j++)
#pragma unroll
            for (int i=0;i<MW;i++)
              acc[i][j] = __builtin_amdgcn_mfma_f32_16x16x32_bf16(ah[i], bl_[j], acc[i][j], 0,0,0);
#pragma unroll
          for (int j=0;j<4;j++)
#pragma unroll
            for (int i=0;i<MW;i++)
              acc[i][j] = __builtin_amdgcn_mfma_f32_16x16x32_bf16(al[i], bh_[j], acc[i][j], 0,0,0);
        } else {
#pragma unroll
          for (int j=0;j<4;j++)
#pragma unroll
            for (int i=0;i<MW;i++)
              acc[i][j] = __builtin_amdgcn_mfma_f32_16x16x32_bf16(ah[i], bh_[j], acc[i][j], 0,0,0);
        }
      }
    }
    if constexpr (STAGEREG){
      if (dy < 2){
        __syncthreads();      // all reads of sB done
        WRITES();             // data already arrived (hidden under compute)
        __syncthreads();      // staged for next dy
      }
    }
  }

#pragma unroll
  for (int i=0;i<MW;i++){
#pragma unroll
    for (int r=0;r<4;r++){
      const int m = m0 + i*16 + lq*4 + r;
      const float bv = bias[m];
      if constexpr (EMODE == 0){
#pragma unroll
        for (int j=0;j<4;j++){
          const int ox = xb + j*16 + lm;
          float v = fmaxf(acc[i][j][r] + bv, 0.f);
          short h = f2bf(v);
          short l = f2bf(v - bf2f(h));
          size_t ad = ((((size_t)(b*(M/8) + (m>>3))*OPH + (oy+1))*OPW + (ox+1)))*8 + (m&7);
          outhi[ad] = h;
          outlo[ad] = l;
        }
      } else {
        float* cp = outf + ((size_t)b*M + m)*NT + oy*64 + lm;
#pragma unroll
        for (int j=0;j<4;j++){
          float v = acc[i][j][r] + bv;
          if constexpr (EMODE == 2) v = fmaxf(v, 0.f);
          cp[j*16] = v;
        }
      }
    }
  }
}

template<int CIN,int K,int M,int MW,int NW,int S,int IPH,int IPW,int NXB,
         bool SPLIT,bool STAGELO,bool STAGEREG,int EMODE,int OPH,int OPW>
__global__ __launch_bounds__(NW*64) void cgemm_row(
    const short* __restrict__ Ahi, const short* __restrict__ Alo,
    const short* __restrict__ Bhi, const short* __restrict__ Blo,
    const float* __restrict__ bias, float* __restrict__ outf,
    short* __restrict__ outhi, short* __restrict__ outlo){
  constexpr int CG = CIN/8;
  constexpr int SW  = 64*S + 2;
  constexpr int SWP = (S==2) ? (SW/2 + 1) : SW;
  constexpr int LOOFF = CG*((S==2)?2:1)*SWP*8;
  constexpr int BUFS = (SPLIT && STAGELO) ? 2 : 1;
  __shared__ __align__(16) short sB[BUFS*LOOFF];
  cgemm_row_body<CIN,K,M,MW,NW,S,IPH,IPW,NXB,SPLIT,STAGELO,STAGEREG,EMODE,OPH,OPW>(
      sB, blockIdx.x, blockIdx.y, blockIdx.z,
      Ahi, Alo, Bhi, Blo, bias, outf, outhi, outlo);
}

// ---------------- headsdec body (T14 reg-staged + fused decode) ----------------
__device__ __forceinline__ void headsdec_body(
    short* sB, int oy, int b,
    const short* __restrict__ Ahi, const short* __restrict__ Alo,
    const short* __restrict__ Bhi, const short* __restrict__ Blo,
    const float* __restrict__ bias, float* __restrict__ hout,
    float* __restrict__ boxes, float* __restrict__ scores,
    int* __restrict__ labels, unsigned* __restrict__ maxb){
  constexpr int KS = 72;           // 2304/32
  constexpr int CG = 32;           // 256/8
  constexpr int SW = 66;
  constexpr int IPH = 34, IPW = 66;
  constexpr int LOOFF = CG*SW*8;   // 16896 shorts per buffer
  constexpr int NLD = (CG*SW + 255)/256;   // 9

  const int wave = threadIdx.x >> 6;
  const int lane = threadIdx.x & 63;
  const int lm = lane & 15, lq = lane >> 4;
  const int tid = threadIdx.x;

  f32x4 acc[4];
#pragma unroll
  for (int j=0;j<4;j++) acc[j] = (f32x4){0.f,0.f,0.f,0.f};

  const short* Ah_l = Ahi + (size_t)lane*8;
  const short* Al_l = Alo + (size_t)lane*8;
  const size_t plane = (size_t)IPH*IPW;

  bf16x8 rh[NLD], rl[NLD];
  auto HLOADS = [&](int iyv){
    const short* srch = Bhi + ((size_t)b*CG*IPH + iyv)*IPW*8;
    const short* srcl = Blo + ((size_t)b*CG*IPH + iyv)*IPW*8;
#pragma unroll
    for (int t=0;t<NLD;t++){
      int c = tid + t*256;
      if (c < CG*SW){
        int g = c / SW, p = c - g*SW;
        rh[t] = *(const bf16x8*)(srch + ((size_t)g*plane + p)*8);
        rl[t] = *(const bf16x8*)(srcl + ((size_t)g*plane + p)*8);
      }
    }
  };
  auto HWRITES = [&](){
#pragma unroll
    for (int t=0;t<NLD;t++){
      int c = tid + t*256;
      if (c < CG*SW){
        *(bf16x8*)(&sB[(size_t)c*8]) = rh[t];
        *(bf16x8*)(&sB[LOOFF + (size_t)c*8]) = rl[t];
      }
    }
  };

  HLOADS(oy);
  HWRITES();
  __syncthreads();

#pragma unroll 1
  for (int dy=0; dy<3; dy++){
    if (dy < 2) HLOADS(oy + dy + 1);
#pragma unroll
    for (int dx=0; dx<3; dx++){
      const int tap = dy*3 + dx;
      const int ksb = tap*8;
#pragma unroll
      for (int kc=0; kc<256; kc+=32){
        const int ks = ksb + (kc>>5);
        int ra[4];
#pragma unroll
        for (int j=0;j<4;j++) ra[j] = ((kc>>3) + lq)*SW + (j*16 + lm) + dx;
        bf16x8 bh_[4], bl_[4];
#pragma unroll
        for (int j=0;j<4;j++){
          bh_[j] = *(const bf16x8*)(&sB[(size_t)ra[j]*8]);
          bl_[j] = *(const bf16x8*)(&sB[LOOFF + (size_t)ra[j]*8]);
        }
        bf16x8 ah = *(const bf16x8*)(Ah_l + ((size_t)wave*KS + ks)*512);
        bf16x8 al = *(const bf16x8*)(Al_l + ((size_t)wave*KS + ks)*512);
#pragma unroll
        for (int j=0;j<4;j++)
          acc[j] = __builtin_amdgcn_mfma_f32_16x16x32_bf16(ah, bh_[j], acc[j], 0,0,0);
#pragma unroll
        for (int j=0;j<4;j++)
          acc[j] = __builtin_amdgcn_mfma_f32_16x16x32_bf16(ah, bl_[j], acc[j], 0,0,0);
#pragma unroll
        for (int j=0;j<4;j++)
          acc[j] = __builtin_amdgcn_mfma_f32_16x16x32_bf16(al, bh_[j], acc[j], 0,0,0);
      }
    }
    if (dy < 2){
      __syncthreads();
      HWRITES();
      __syncthreads();
    }
  }

  // epilogue: hout write + LDS f32 stage [64 rows][68 stride]
  __syncthreads();                  // all k-loop LDS reads done before reuse
  float* sF = (float*)sB;
#pragma unroll
  for (int r=0;r<4;r++){
    const int m = wave*16 + lq*4 + r;
    const float bv = bias[m];
    float* cp = hout + ((size_t)b*64 + m)*NANCH + oy*64 + lm;
#pragma unroll
    for (int j=0;j<4;j++){
      float v = acc[j][r] + bv;
      cp[j*16] = v;
      sF[m*68 + j*16 + lm] = v;
    }
  }
  __syncthreads();

  // decode (exact decodek sequence) for anchors n = oy*64 + 0..63
  if (tid < 64){
    const int n = oy*64 + tid;
    float l[NCLS];
    float M = -1e30f;
#pragma unroll
    for (int c=0;c<NCLS;c++){ l[c] = sF[c*68 + tid]; M = fmaxf(M, l[c]); }
    float denom = 0.f;
#pragma unroll
    for (int c=0;c<NCLS;c++) denom += expf(l[c]-M);
    float best = -1.f; int bi = 0;
#pragma unroll
    for (int c=0;c<NCLS-1;c++){
      float e = expf(l[c]-M);
      if (e > best){ best = e; bi = c; }
    }
    scores[(size_t)b*NANCH + n] = best/denom;
    labels[(size_t)b*NANCH + n] = bi;

    float dxv = sF[21*68 + tid], dyv = sF[22*68 + tid];
    float dwv = sF[23*68 + tid], dhv = sF[24*68 + tid];
    const int yy = n >> 6, xx = n & 63;
    float cx = (xx+0.5f)*8.f, cy = (yy+0.5f)*8.f;
    float px = cx + dxv*32.f, py = cy + dyv*32.f;
    float pw = 32.f*expf(dwv), ph = 32.f*expf(dhv);
    float x1 = px - 0.5f*pw, y1 = py - 0.5f*ph;
    float x2 = px + 0.5f*pw, y2 = py + 0.5f*ph;
    float* bo = boxes + ((size_t)b*NANCH + n)*4;
    bo[0]=x1; bo[1]=y1; bo[2]=x2; bo[3]=y2;
    float mx = fmaxf(fmaxf(x1,y1), fmaxf(x2,y2));
#pragma unroll
    for (int off=32; off>0; off>>=1) mx = fmaxf(mx, __shfl_down(mx, off));
    if (tid == 0) atomicMax(maxb + b, encf(mx));
  }
}

// ---------------- heads + pw1 co-dispatch ----------------
__global__ __launch_bounds__(256) void headpw1k(
    const short* __restrict__ ahh, const short* __restrict__ ahl,
    const short* __restrict__ ap1h,
    const short* __restrict__ fthi, const short* __restrict__ ftlo,
    const float* __restrict__ bh, const float* __restrict__ pb1,
    float* __restrict__ hout, float* __restrict__ p1,
    float* __restrict__ boxes, float* __restrict__ scores,
    int* __restrict__ labels, unsigned* __restrict__ maxb){
  __shared__ __align__(16) short smem[33792];   // 67,584 B (headsdec needs 2x16896)
  const int bx = blockIdx.x, b = blockIdx.z;
  if (bx < 32){
    headsdec_body(smem, bx, b, ahh, ahl, fthi, ftlo, bh, hout,
                  boxes, scores, labels, maxb);
  } else {
    const int lx = bx - 32;
    cgemm_row_body<256,2304,256,2,4,1,34,66,1,false,false,true,2,1,1>(
        smem, lx & 31, lx >> 5, b, ap1h, ap1h, fthi, fthi, pb1, p1, nullptr, nullptr);
  }
}

// ---------------- pw2 + fused sort/NMS/gather co-dispatch ----------------
// grid (24), 1024 threads: bx<16 -> pw2 role; bx>=16 -> sortnms role (b=bx-16):
//   bitonic sort -> offset boxes in LDS -> greedy NMS with on-demand IoU rows
//   (only kept boxes' rows are ever OR'd — identical keep list to full-matrix
//   ioumask+nmsgather: same IoU expression, same sb values, boolean OR) -> gather.
__global__ void __launch_bounds__(1024) pw2nms(
    const float* __restrict__ p1, const float* __restrict__ wT,
    const float* __restrict__ biasp, float* __restrict__ proto,
    const float* __restrict__ scores, const float* __restrict__ boxes,
    const int* __restrict__ labels, const unsigned* __restrict__ maxb,
    int* __restrict__ keep, float* __restrict__ out){
  __shared__ float sc[NANCH];
  __shared__ int   id[NANCH];
  __shared__ float sbL[NANCH*4];
  __shared__ unsigned long long sup[32];
  __shared__ int s_keep[TOPK_N];
  __shared__ int s_next;
  const int bx = blockIdx.x, t = threadIdx.x;
  if (bx < 16){
    // ---- pw2 role (identical arithmetic to pw2k2, 1024-thread mapping) ----
    const int b  = bx >> 1;
    const int sp = (bx & 1)*1024 + t;
    float acc[32];
#pragma unroll
    for (int c=0;c<32;c++) acc[c] = biasp[c];
    const float* pb = p1 + (size_t)b*256*NANCH + sp;
    for (int ci=0;ci<256;ci++){
      float v = pb[(size_t)ci*NANCH];
      const float* wq = wT + ci*32;
#pragma unroll
      for (int c=0;c<32;c++) acc[c] = fmaf(v, wq[c], acc[c]);
    }
#pragma unroll
    for (int c=0;c<32;c++)
      proto[((size_t)b*32 + c)*NANCH + sp] = acc[c];
    return;
  }
  // ---- sortnms role ----
  const int b = bx - 16;
  for (int i=t;i<NANCH;i+=1024){ sc[i]=scores[(size_t)b*NANCH+i]; id[i]=i; }
  if (t < 32) sup[t] = 0ull;
  __syncthreads();
  for (int k=2;k<=NANCH;k<<=1){
    for (int j=k>>1;j>0;j>>=1){
      for (int i=t;i<NANCH;i+=1024){
        int ixj = i ^ j;
        if (ixj > i){
          float sa=sc[i], sb_=sc[ixj]; int ia=id[i], ib=id[ixj];
          bool dir = ((i & k) == 0);
          bool before_ba = (sb_ > sa) || (sb_ == sa && ib < ia);
          if (before_ba == dir){ sc[i]=sb_; sc[ixj]=sa; id[i]=ib; id[ixj]=ia; }
        }
      }
      __syncthreads();
    }
  }
  // offset boxes into LDS (identical values to old sb)
  float mboff = decf(maxb[b]) + 1.0f;
  for (int r=t;r<NANCH;r+=1024){
    int o = id[r];
    float off = (float)labels[(size_t)b*NANCH + o] * mboff;
    const float* bo = boxes + ((size_t)b*NANCH + o)*4;
    sbL[r*4]   = bo[0]+off; sbL[r*4+1] = bo[1]+off;
    sbL[r*4+2] = bo[2]+off; sbL[r*4+3] = bo[3]+off;
  }
  __syncthreads();
  // greedy NMS with on-demand IoU rows
  int k = 0, i = 0;
  while (true){
    if (k >= TOPK_N) break;
    if (t < 64){
      unsigned long long avail = (t < 32) ? ~sup[t] : 0ull;
      const int wi = i >> 6;
      if ((int)t < wi) avail = 0ull;
      else if ((int)t == wi) avail &= (~0ull) << (i & 63);
      unsigned long long ball = __ballot(avail != 0ull);
      int nxt = -1;
      if (ball){
        int w0 = (int)__builtin_ctzll(ball);
        unsigned long long aw = __shfl(avail, w0);
        int b0 = (int)__builtin_ctzll(aw);
        nxt = (w0 << 6) + b0;
      }
      if (t == 0) s_next = nxt;
    }
    __syncthreads();
    i = s_next;
    if (i < 0) break;
    if (t == 0) s_keep[k] = id[i];
    k++;
    // IoU of kept box i vs j = t and j = t+1024 (exact ioumask expression)
    float x1 = sbL[i*4], y1 = sbL[i*4+1], x2 = sbL[i*4+2], y2 = sbL[i*4+3];
    float ai = (x2-x1)*(y2-y1);
    bool f0 = false, f1 = false;
    {
      int j = t;
      if (j > i){
        float bx1=sbL[j*4], by1=sbL[j*4+1], bx2=sbL[j*4+2], by2=sbL[j*4+3];
        float lx=fmaxf(x1,bx1), ly=fmaxf(y1,by1);
        float rx=fminf(x2,bx2), ry=fminf(y2,by2);
        float ww=fmaxf(rx-lx,0.f), hh=fmaxf(ry-ly,0.f);
        float inter = ww*hh;
        float aj = (bx2-bx1)*(by2-by1);
        f0 = (inter/(ai + aj - inter + 1e-9f)) > 0.5f;
      }
      j = t + 1024;
      if (j > i){
        float bx1=sbL[j*4], by1=sbL[j*4+1], bx2=sbL[j*4+2], by2=sbL[j*4+3];
        float lx=fmaxf(x1,bx1), ly=fmaxf(y1,by1);
        float rx=fminf(x2,bx2), ry=fminf(y2,by2);
        float ww=fmaxf(rx-lx,0.f), hh=fmaxf(ry-ly,0.f);
        float inter = ww*hh;
        float aj = (bx2-bx1)*(by2-by1);
        f1 = (inter/(ai + aj - inter + 1e-9f)) > 0.5f;
      }
    }
    // wave w (threads 64w..64w+63) covers word w (j=t) and word 16+w (j=t+1024)
    unsigned long long b0m = __ballot(f0);
    unsigned long long b1m = __ballot(f1);
    if ((t & 63) == 0){
      sup[t >> 6]        |= b0m;
      sup[16 + (t >> 6)] |= b1m;
    }
    i++;
    __syncthreads();
  }
  __syncthreads();
  // gather (identical to old nmsgather epilogue)
  for (int r = t; r < TOPK_N; r += 1024){
    int kv = (r < k) ? s_keep[r] : -1;
    keep[b*TOPK_N + r] = kv;
    float valid = (kv >= 0) ? 1.f : 0.f;
    int kc = (kv < 0) ? 0 : kv;
    const float* bo = boxes + ((size_t)b*NANCH + kc)*4;
#pragma unroll
    for (int c=0;c<4;c++) out[OUT_BOXES + ((size_t)b*TOPK_N + r)*4 + c] = bo[c]*valid;
    out[OUT_SCORES + b*TOPK_N + r] = scores[(size_t)b*NANCH + kc]*valid;
    out[OUT_LABELS + b*TOPK_N + r] = (kv >= 0) ? (float)labels[(size_t)b*NANCH + kc] : 0.f;
    out[OUT_VALID  + b*TOPK_N + r] = valid;
  }
}

// ---------------- fused mask logits + sigmoid + bilinear resize + threshold ----------------
// 1D grid 800: b = bid&7 so each XCD (round-robin) keeps one batch's proto in L2.
__global__ __launch_bounds__(256) void maskresize(const int* __restrict__ keep,
    const float* __restrict__ hout, const float* __restrict__ proto,
    float* __restrict__ out){
  const int b = blockIdx.x & 7, r = blockIdx.x >> 3;
  float* obase = out + OUT_MASKS + ((size_t)b*TOPK_N + r)*131072;
  int ki = keep[b*TOPK_N + r];
  if (ki < 0){
    float4 z = make_float4(0.f,0.f,0.f,0.f);
    for (int idx = threadIdx.x; idx < 32768; idx += 256)
      ((float4*)obase)[idx] = z;
    return;
  }
  __shared__ float cf[32];
  __shared__ float sm[NANCH];
  if (threadIdx.x < 32)
    cf[threadIdx.x] = hout[((size_t)b*64 + 25 + threadIdx.x)*NANCH + ki];
  __syncthreads();
  for (int s = threadIdx.x; s < NANCH; s += 256){
    float acc = 0.f;
#pragma unroll
    for (int p=0;p<32;p++) acc = fmaf(cf[p], proto[((size_t)b*32 + p)*NANCH + s], acc);
    sm[s] = 1.f/(1.f + expf(-acc));
  }
  __syncthreads();
  for (int pid = threadIdx.x; pid < 32768; pid += 256){
    const int y  = pid >> 7;
    const int x4 = (pid & 127) << 2;
    float sy = (y + 0.5f)*0.125f - 0.5f;
    sy = fminf(fmaxf(sy, 0.f), 31.f);
    int y0 = (int)floorf(sy);
    int y1 = min(y0+1, 31);
    float wy = sy - (float)y0;
    const float* r0 = sm + y0*64;
    const float* r1 = sm + y1*64;
    float res[4];
#pragma unroll
    for (int kk=0;kk<4;kk++){
      int x = x4 + kk;
      float sx = (x + 0.5f)*0.125f - 0.5f;
      sx = fminf(fmaxf(sx, 0.f), 63.f);
      int x0 = (int)floorf(sx);
      int x1 = min(x0+1, 63);
      float wx = sx - (float)x0;
      float t0 = r0[x0]*(1.f-wy) + r1[x0]*wy;
      float t1 = r0[x1]*(1.f-wy) + r1[x1]*wy;
      float v  = t0*(1.f-wx) + t1*wx;
      res[kk] = (v > 0.5f) ? 1.f : 0.f;
    }
    *(float4*)(obase + y*512 + x4) = make_float4(res[0], res[1], res[2], res[3]);
  }
}

extern "C" void kernel_launch(void* const* d_in, const int* in_sizes, int n_in,
                              void* d_out, int out_size, void* d_ws, size_t ws_size,
                              hipStream_t stream) {
  const float* images=(const float*)d_in[0];
  const float* w1=(const float*)d_in[1];  const float* b1=(const float*)d_in[2];
  const float* w2=(const float*)d_in[3];  const float* b2=(const float*)d_in[4];
  const float* w3=(const float*)d_in[5];  const float* b3=(const float*)d_in[6];
  const float* pw1=(const float*)d_in[7]; const float* pb1=(const float*)d_in[8];
  const float* pw2=(const float*)d_in[9]; const float* pb2=(const float*)d_in[10];
  const float* cw=(const float*)d_in[11]; const float* cb=(const float*)d_in[12];
  const float* bw=(const float*)d_in[13]; const float* bb=(const float*)d_in[14];
  const float* kw=(const float*)d_in[15]; const float* kb=(const float*)d_in[16];
  float* out = (float*)d_out;
  char* ws = (char*)d_ws;

  short* x1hi = (short*)(ws + OFF_X1HI);
  short* x1lo = (short*)(ws + OFF_X1LO);
  short* x2hi = (short*)(ws + OFF_X2HI);
  short* x2lo = (short*)(ws + OFF_X2LO);
  short* fthi = (short*)(ws + OFF_FTHI);
  short* ftlo = (short*)(ws + OFF_FTLO);
  short* a2h  = (short*)(ws + OFF_A2H);
  short* a2l  = (short*)(ws + OFF_A2L);
  short* a3h  = (short*)(ws + OFF_A3H);
  short* a3l  = (short*)(ws + OFF_A3L);
  short* ahh  = (short*)(ws + OFF_AHH);
  short* ahl  = (short*)(ws + OFF_AHL);
  short* ap1h = (short*)(ws + OFF_AP1H);
  short* ap1l = (short*)(ws + OFF_AP1L);
  float* wTp2 = (float*)(ws + OFF_WTP2);
  float* bh   = (float*)(ws + OFF_BH);
  float* hout = (float*)(ws + OFF_HOUT);
  float* p1   = (float*)(ws + OFF_P1);
  float* proto= (float*)(ws + OFF_PROTO);
  float* boxes= (float*)(ws + OFF_BOXES);
  float* scores=(float*)(ws + OFF_SCORES);
  int*   labels=(int*)  (ws + OFF_LABELS);
  int*   keep = (int*)  (ws + OFF_KEEP);
  unsigned* maxb = (unsigned*)(ws + OFF_MAXB);

  // halo zero + all packing + conv1 in one dispatch
  megaprep<<<dim3(6983), 256, 0, stream>>>(
      images, w1, b1, w2, a2h, a2l, w3, a3h, a3l, pw1, ap1h, ap1l,
      cw, bw, kw, cb, bb, kb, ahh, ahl, bh, pw2, wTp2,
      x1hi, x1lo, x2hi, x2lo, fthi, ftlo, maxb);

  // conv2: split-bf16, T14 reg-staged (4 blocks/CU)
  cgemm_row<64,576,128,2,4,2,130,258,2,true,true,true,0,66,130>
      <<<dim3(128,1,BB), 256, 0, stream>>>(a2h, a2l, x1hi, x1lo, b2, nullptr, x2hi, x2lo);

  // conv3: split-bf16, T14 reg-staged (2 blocks/CU)
  cgemm_row<128,1152,256,2,4,2,66,130,1,true,true,true,0,34,66>
      <<<dim3(32,2,BB), 256, 0, stream>>>(a3h, a3l, x2hi, x2lo, b3, nullptr, fthi, ftlo);

  // heads(+decode) and pw1 co-dispatched as separate blocks in one grid
  headpw1k<<<dim3(96,1,BB), 256, 0, stream>>>(ahh, ahl, ap1h, fthi, ftlo,
                                              bh, pb1, hout, p1,
                                              boxes, scores, labels, maxb);

  // pw2 + fused sort/NMS/gather co-dispatched
  pw2nms<<<dim3(24), 1024, 0, stream>>>(p1, wTp2, pb2, proto,
                                        scores, boxes, labels, maxb, keep, out);

  // fused masks
  maskresize<<<dim3(800), 256, 0, stream>>>(keep, hout, proto, out);
}